// Round 8
// baseline (370.747 us; speedup 1.0000x reference)
//
#include <hip/hip_runtime.h>

typedef unsigned int u32;

// ---------------------------------------------------------------------------
// LiBNet forward, bit-packed ternary arithmetic + integer intermediates.
// dot over taps = popc(nzA & nzW) - 2*popc((sA ^ sW) & nzA & nzW)
// nz masks preserve sign(0)=0 semantics exactly (padding AND exact zeros).
// conv1: ONE pass; 48-tap window PINNED into VGPRs via empty asm "+v"
// (compiler otherwise rematerializes LDS reads every oc iteration).
// Grouped convs fuse their own (exact integer) bn stats.
// ---------------------------------------------------------------------------

static __device__ __forceinline__ float fsign(float x) {
    return (x > 0.f) ? 1.f : ((x < 0.f) ? -1.f : 0.f);
}
static __device__ __forceinline__ u32 pack4(int a, int b, int c, int d) {
    return (a & 0xff) | ((b & 0xff) << 8) | ((c & 0xff) << 16) | ((u32)(d & 0xff) << 24);
}

// --- merged weight prep: conv1 sign-f32, grouped packs, 1x1 packs ---
__global__ __launch_bounds__(256) void k_wprep(const float* __restrict__ w1, float* __restrict__ sw1f,
                                               const float* __restrict__ w2_1, u32* __restrict__ wpk21,
                                               const float* __restrict__ w3_1, u32* __restrict__ wpk31,
                                               const float* __restrict__ w2_2, u32* __restrict__ wp22,
                                               const float* __restrict__ w3_2, u32* __restrict__ wp32)
{
    int blk = blockIdx.x, tid = threadIdx.x;
    if (blk < 12) {
        int i = blk * 256 + tid;
        if (i < 3072) sw1f[i] = fsign(w1[i]);
        return;
    }
    if (blk == 12) {
        if (tid < 64) {   // grouped 4x4 weights, C=64
            const float* p = w2_1 + tid * 32;
            for (int r = 0; r < 8; ++r) {
                u32 sn = 0, nz = 0;
                for (int kw = 0; kw < 4; ++kw) {
                    float v = p[r * 4 + kw];
                    sn |= (u32)(v > 0.f) << kw;
                    nz |= (u32)(v != 0.f) << kw;
                }
                wpk21[tid * 8 + r] = sn | (nz << 8);
            }
        }
        {                 // 1x1 weights 256x64
            const float* p = w2_2 + (size_t)tid * 64;
            for (int j = 0; j < 2; ++j) {
                u32 sv = 0, nv = 0;
                for (int k = 0; k < 32; ++k) {
                    float v = p[j * 32 + k];
                    sv |= (u32)(v > 0.f) << k;
                    nv |= (u32)(v != 0.f) << k;
                }
                wp22[tid * 4 + j] = sv;
                wp22[tid * 4 + 2 + j] = nv;
            }
        }
        return;
    }
    {                     // blk == 13
        {                 // grouped 4x4 weights, C=256
            const float* p = w3_1 + tid * 32;
            for (int r = 0; r < 8; ++r) {
                u32 sn = 0, nz = 0;
                for (int kw = 0; kw < 4; ++kw) {
                    float v = p[r * 4 + kw];
                    sn |= (u32)(v > 0.f) << kw;
                    nz |= (u32)(v != 0.f) << kw;
                }
                wpk31[tid * 8 + r] = sn | (nz << 8);
            }
        }
        {                 // 1x1 weights 256x256
            const float* p = w3_2 + (size_t)tid * 256;
            for (int j = 0; j < 8; ++j) {
                u32 sv = 0, nv = 0;
                for (int k = 0; k < 32; ++k) {
                    float v = p[j * 32 + k];
                    sv |= (u32)(v > 0.f) << k;
                    nv |= (u32)(v != 0.f) << k;
                }
                wp32[tid * 16 + j] = sv;
                wp32[tid * 16 + 8 + j] = nv;
            }
        }
    }
}

// --- conv1 fused: conv + pooled max/min stores + per-channel stats ---
__global__ __launch_bounds__(256, 4) void k_conv1f(const float* __restrict__ x,
                                                   const float* __restrict__ swf,
                                                   float* __restrict__ pmax,
                                                   float* __restrict__ pmin,
                                                   double* __restrict__ part)
{
    __shared__ float sx[3 * 35 * 35];
    __shared__ float sacc_s[64 * 33];   // [oc][32 s8-partials], pad 33
    __shared__ float sacc_q[64 * 33];
    int b = blockIdx.x >> 2, q = blockIdx.x & 3;
    for (int i = threadIdx.x; i < 3 * 35 * 35; i += 256) sx[i] = 0.f;
    __syncthreads();
    const float* xb = x + (size_t)b * 3072;
    for (int i = threadIdx.x; i < 3072; i += 256) {
        int w = i & 31, h = (i >> 5) & 31, ic = i >> 10;
        sx[(ic * 35 + h + 1) * 35 + w + 1] = xb[i];
    }
    __syncthreads();
    int pos = q * 256 + threadIdx.x;
    int h = pos >> 5, w = pos & 31;
    int lane = threadIdx.x & 63, wv = threadIdx.x >> 6;
    int oh = q * 4 + wv;
    bool statw = ((lane & 7) == 0);
    bool owner = ((lane & 33) == 0);   // even lane, lane<32
    float in[48];
#pragma unroll
    for (int ic = 0; ic < 3; ++ic)
#pragma unroll
        for (int kh = 0; kh < 4; ++kh)
#pragma unroll
            for (int kw = 0; kw < 4; ++kw)
                in[ic * 16 + kh * 4 + kw] = sx[(ic * 35 + h + kh) * 35 + w + kw];
    // Pin the 48-tap window into VGPRs: empty asm makes each tap a
    // non-rematerializable def, so the oc loop reads registers, not LDS.
#pragma unroll
    for (int k = 0; k < 48; ++k) asm volatile("" : "+v"(in[k]));
    float* pmaxb = pmax + ((size_t)(b * 64) * 16 + oh) * 16 + (lane >> 1);
    float* pminb = pmin + ((size_t)(b * 64) * 16 + oh) * 16 + (lane >> 1);
#pragma unroll 8
    for (int oc = 0; oc < 64; ++oc) {
        const float* wp = swf + oc * 48;   // wave-uniform -> s_load
        float a0 = 0.f, a1 = 0.f, a2 = 0.f, a3 = 0.f;
#pragma unroll
        for (int k = 0; k < 48; k += 4) {
            a0 += in[k]     * wp[k];
            a1 += in[k + 1] * wp[k + 1];
            a2 += in[k + 2] * wp[k + 2];
            a3 += in[k + 3] * wp[k + 3];
        }
        float v = (a0 + a1) + (a2 + a3);
        float p1 = __shfl_xor(v, 1);                 // horizontal neighbor
        float s2 = v + p1;
        float sq2 = v * v + p1 * p1;
        float mx = fmaxf(v, p1), mn = fminf(v, p1);
        float s4  = s2  + __shfl_xor(s2, 2);
        float sq4 = sq2 + __shfl_xor(sq2, 2);
        float s8  = s4  + __shfl_xor(s4, 4);
        float sq8 = sq4 + __shfl_xor(sq4, 4);
        float mx2 = fmaxf(mx, __shfl_xor(mx, 32));   // vertical neighbor
        float mn2 = fminf(mn, __shfl_xor(mn, 32));
        if (statw) {
            int idx = oc * 33 + wv * 8 + (lane >> 3);
            sacc_s[idx] = s8;
            sacc_q[idx] = sq8;
        }
        if (owner) {
            pmaxb[oc * 256] = mx2;
            pminb[oc * 256] = mn2;
        }
    }
    __syncthreads();
    if (threadIdx.x < 128) {
        int oc = threadIdx.x >> 1, half = threadIdx.x & 1;
        const float* sp = (half ? sacc_q : sacc_s) + oc * 33;
        double acc = 0.0;
        for (int j = 0; j < 32; ++j) acc += (double)sp[j];
        part[((size_t)oc * 2048 + blockIdx.x) * 2 + half] = acc;
    }
}

// --- bn pick (max if scale>0 else min) + binarize + row-bitpack ---
__global__ __launch_bounds__(256) void k_bnpick(const float* __restrict__ pmax,
                                                const float* __restrict__ pmin,
                                                const float4* __restrict__ st,
                                                u32* __restrict__ spk,
                                                u32* __restrict__ npk)
{
    int bc = blockIdx.x;              // b*64 + c
    int c = bc & 63;
    int t = threadIdx.x;
    int lane = t & 63, wv = t >> 6;
    float4 s = st[c];
    float mx = pmax[(size_t)bc * 256 + t];
    float mn = pmin[(size_t)bc * 256 + t];
    float raw = (s.y > 0.f) ? mx : mn;
    float v = (raw - s.x) * s.y + s.z;
    unsigned long long bs = __ballot(v > 0.f);
    unsigned long long bn = __ballot(v != 0.f);
    int r = lane >> 4;                // row within wave (4 rows x 16 cols)
    int oh = wv * 4 + r;
    size_t base = (size_t)bc * 20;
    if ((lane & 15) == 0) {
        spk[base + 1 + oh] = (((u32)(bs >> (16 * r))) & 0xffffu) << 1;
        npk[base + 1 + oh] = (((u32)(bn >> (16 * r))) & 0xffffu) << 1;
    }
    if (t < 4) {                      // zero margin slots 0,17,18,19
        int zs = (t == 0) ? 0 : (16 + t);
        spk[base + zs] = 0; npk[base + zs] = 0;
    }
}

// --- int8 stats: exact int32 block sums -> double partials ---
__global__ __launch_bounds__(256) void k_stats_i8(const signed char* __restrict__ in,
                                                  double* __restrict__ part,
                                                  int C, int HW, int bPerChunk)
{
    int c = blockIdx.x, chunk = blockIdx.y, b0 = chunk * bPerChunk;
    int q4 = HW >> 2;
    int s = 0, sq = 0;
    for (int b = b0; b < b0 + bPerChunk; ++b) {
        const u32* p = (const u32*)(in + (size_t)(b * C + c) * HW);
        for (int i = threadIdx.x; i < q4; i += 256) {
            u32 v = p[i];
            int x0 = (int)(v << 24) >> 24, x1 = (int)(v << 16) >> 24;
            int x2 = (int)(v << 8) >> 24,  x3 = (int)v >> 24;
            s += x0 + x1 + x2 + x3;
            sq += x0 * x0 + x1 * x1 + x2 * x2 + x3 * x3;
        }
    }
    __shared__ int ss[256];
    __shared__ int sb[256];
    ss[threadIdx.x] = s; sb[threadIdx.x] = sq;
    __syncthreads();
    for (int st = 128; st > 0; st >>= 1) {
        if (threadIdx.x < st) {
            ss[threadIdx.x] += ss[threadIdx.x + st];
            sb[threadIdx.x] += sb[threadIdx.x + st];
        }
        __syncthreads();
    }
    if (threadIdx.x == 0) {
        int nch = gridDim.y;
        part[(size_t)(c * nch + chunk) * 2]     = (double)ss[0];
        part[(size_t)(c * nch + chunk) * 2 + 1] = (double)sb[0];
    }
}

// --- int16 stats ---
__global__ __launch_bounds__(256) void k_stats_i16(const short* __restrict__ in,
                                                   double* __restrict__ part,
                                                   int C, int HW, int bPerChunk)
{
    int c = blockIdx.x, chunk = blockIdx.y, b0 = chunk * bPerChunk;
    int q2 = HW >> 1;
    int s = 0, sq = 0;
    for (int b = b0; b < b0 + bPerChunk; ++b) {
        const u32* p = (const u32*)(in + (size_t)(b * C + c) * HW);
        for (int i = threadIdx.x; i < q2; i += 256) {
            u32 v = p[i];
            int x0 = (int)(v << 16) >> 16, x1 = (int)v >> 16;
            s += x0 + x1;
            sq += x0 * x0 + x1 * x1;
        }
    }
    __shared__ int ss[256];
    __shared__ int sb[256];
    ss[threadIdx.x] = s; sb[threadIdx.x] = sq;
    __syncthreads();
    for (int st = 128; st > 0; st >>= 1) {
        if (threadIdx.x < st) {
            ss[threadIdx.x] += ss[threadIdx.x + st];
            sb[threadIdx.x] += sb[threadIdx.x + st];
        }
        __syncthreads();
    }
    if (threadIdx.x == 0) {
        int nch = gridDim.y;
        part[(size_t)(c * nch + chunk) * 2]     = (double)ss[0];
        part[(size_t)(c * nch + chunk) * 2 + 1] = (double)sb[0];
    }
}

// --- finalize: block per channel; mean/var -> power-of-two shift scale ---
__global__ __launch_bounds__(256) void k_finalize2(const double* __restrict__ part,
                                                   int nch, int N,
                                                   const float* __restrict__ gamma,
                                                   const float* __restrict__ beta,
                                                   float4* __restrict__ st)
{
    int c = blockIdx.x;
    double s = 0.0, sq = 0.0;
    for (int i = threadIdx.x; i < nch; i += 256) {
        s  += part[((size_t)c * nch + i) * 2];
        sq += part[((size_t)c * nch + i) * 2 + 1];
    }
    __shared__ double ss[256];
    __shared__ double sb[256];
    ss[threadIdx.x] = s; sb[threadIdx.x] = sq;
    __syncthreads();
    for (int stp = 128; stp > 0; stp >>= 1) {
        if (threadIdx.x < stp) {
            ss[threadIdx.x] += ss[threadIdx.x + stp];
            sb[threadIdx.x] += sb[threadIdx.x + stp];
        }
        __syncthreads();
    }
    if (threadIdx.x == 0) {
        double mean = ss[0] / (double)N;
        double var = sb[0] / (double)N - mean * mean;
        float inv = gamma[c] / sqrtf((float)var + 1e-5f);
        float sh = rintf(log2f(fabsf(inv) + 1e-12f));
        sh = fminf(fmaxf(sh, -4.f), 4.f);
        float scale = copysignf(exp2f(sh), inv);
        st[c] = make_float4((float)mean, scale, beta[c], 0.f);
    }
}

// --- layer2->3 bn+pool+pack: int8 in [512,256,16,16], wave per channel ---
__global__ __launch_bounds__(256) void k_poolpack3(const signed char* __restrict__ in,
                                                   const float4* __restrict__ st,
                                                   u32* __restrict__ spk,
                                                   u32* __restrict__ npk)
{
    int wv = threadIdx.x >> 6, lane = threadIdx.x & 63;
    int bc = blockIdx.x * 4 + wv;     // b*256 + c
    int c = bc & 255;
    int oh = lane >> 3, ow = lane & 7;
    float4 s = st[c];
    const signed char* p = in + (size_t)bc * 256 + (2 * oh) * 16 + 2 * ow;
    short s01 = *(const short*)p;
    short s23 = *(const short*)(p + 16);
    int a0 = (int)(signed char)(s01 & 0xff), a1 = (int)(s01 >> 8);
    int a2 = (int)(signed char)(s23 & 0xff), a3 = (int)(s23 >> 8);
    bool pos = (s.y > 0.f);
    int raw = pos ? max(max(a0, a1), max(a2, a3)) : min(min(a0, a1), min(a2, a3));
    float v = ((float)raw - s.x) * s.y + s.z;
    unsigned long long bs = __ballot(v > 0.f);
    unsigned long long bn = __ballot(v != 0.f);
    size_t base = (size_t)bc * 12;
    if (ow == 0) {
        spk[base + 1 + oh] = (((u32)(bs >> (8 * oh))) & 0xffu) << 1;
        npk[base + 1 + oh] = (((u32)(bn >> (8 * oh))) & 0xffu) << 1;
    }
    if (lane < 4) {                   // zero margin slots 0,9,10,11
        int zs = (lane == 0) ? 0 : (8 + lane);
        spk[base + zs] = 0; npk[base + zs] = 0;
    }
}

// --- grouped 4x4 binary conv, bit-packed in, int8 out, FUSED bn stats. ---
template <int C, int H>
__global__ __launch_bounds__(256) void k_convg_bp(const u32* __restrict__ spk,
                                                  const u32* __restrict__ npk,
                                                  const u32* __restrict__ wpk,
                                                  signed char* __restrict__ out,
                                                  double* __restrict__ part)
{
    constexpr int SLOTS = (H == 16) ? 20 : 12;
    int t = blockIdx.x * 256 + threadIdx.x;
    int h = t % H; int r0 = t / H;
    int g = r0 % (C / 2); int b = r0 / (C / 2);
    int lane = threadIdx.x & 63;
    const u32* sp = spk + (size_t)(b * C + 2 * g) * SLOTS + h;
    const u32* np = npk + (size_t)(b * C + 2 * g) * SLOTS + h;
    u32 S[8], N[8];
#pragma unroll
    for (int jc = 0; jc < 2; ++jc)
#pragma unroll
        for (int jj = 0; jj < 4; ++jj) {    // slot h+jj = input row h-1+jj
            S[jc * 4 + jj] = sp[jc * SLOTS + jj];
            N[jc * 4 + jj] = np[jc * SLOTS + jj];
        }
    const u32* wq = wpk + (size_t)(2 * g) * 8;
    u32 Ws0[8], Wn0[8], Ws1[8], Wn1[8];
#pragma unroll
    for (int r = 0; r < 8; ++r) {
        u32 a = wq[r];      Ws0[r] = a & 15u;  Wn0[r] = (a >> 8) & 15u;
        u32 bb = wq[8 + r]; Ws1[r] = bb & 15u; Wn1[r] = (bb >> 8) & 15u;
    }
    int v0[H], v1[H];
    int s0 = 0, q0 = 0, s1 = 0, q1 = 0;
#pragma unroll
    for (int w = 0; w < H; ++w) {
        int snz0 = 0, smis0 = 0, snz1 = 0, smis1 = 0;
#pragma unroll
        for (int r = 0; r < 8; ++r) {
            u32 ss = (S[r] >> w) & 15u;
            u32 nn = (N[r] >> w) & 15u;
            u32 nz0 = nn & Wn0[r]; u32 m0 = (ss ^ Ws0[r]) & nz0;
            snz0 += __popc(nz0); smis0 += __popc(m0);
            u32 nz1 = nn & Wn1[r]; u32 m1 = (ss ^ Ws1[r]) & nz1;
            snz1 += __popc(nz1); smis1 += __popc(m1);
        }
        v0[w] = snz0 - 2 * smis0;
        v1[w] = snz1 - 2 * smis1;
        s0 += v0[w]; q0 += v0[w] * v0[w];
        s1 += v1[w]; q1 += v1[w] * v1[w];
    }
    // group-of-H lanes (aligned) hold one (b, g): butterfly int reduce
#pragma unroll
    for (int m = 1; m < H; m <<= 1) {
        s0 += __shfl_xor(s0, m); q0 += __shfl_xor(q0, m);
        s1 += __shfl_xor(s1, m); q1 += __shfl_xor(q1, m);
    }
    if ((lane & (H - 1)) == 0) {
        part[((size_t)(2 * g) * 512 + b) * 2]         = (double)s0;
        part[((size_t)(2 * g) * 512 + b) * 2 + 1]     = (double)q0;
        part[((size_t)(2 * g + 1) * 512 + b) * 2]     = (double)s1;
        part[((size_t)(2 * g + 1) * 512 + b) * 2 + 1] = (double)q1;
    }
    signed char* o0 = out + ((size_t)((b * C + 2 * g) * H + h)) * H;
    signed char* o1 = o0 + (size_t)H * H;
    u32 wb0[H / 4], wb1[H / 4];
#pragma unroll
    for (int j = 0; j < H / 4; ++j) {
        wb0[j] = pack4(v0[4*j], v0[4*j+1], v0[4*j+2], v0[4*j+3]);
        wb1[j] = pack4(v1[4*j], v1[4*j+1], v1[4*j+2], v1[4*j+3]);
    }
    if constexpr (H == 16) {
        *(uint4*)o0 = make_uint4(wb0[0], wb0[1], wb0[2], wb0[3]);
        *(uint4*)o1 = make_uint4(wb1[0], wb1[1], wb1[2], wb1[3]);
    } else {
        *(uint2*)o0 = make_uint2(wb0[0], wb0[1]);
        *(uint2*)o1 = make_uint2(wb1[0], wb1[1]);
    }
}

// --- bn + binarize + channel-bitpack from int8: act[t] = {signs..., nz...} ---
template <int C, int HW>
__global__ __launch_bounds__(256) void k_bnpackC(const signed char* __restrict__ q,
                                                 const float4* __restrict__ st,
                                                 u32* __restrict__ act)
{
    constexpr int W = C / 32;
    int t = blockIdx.x * 256 + threadIdx.x;   // t = b*HW + hw
    int hw = t % HW; int b = t / HW;
    const signed char* qp = q + (size_t)b * C * HW + hw;
    u32* ap = act + (size_t)t * 2 * W;
#pragma unroll
    for (int j = 0; j < W; ++j) {
        u32 sv = 0, nv = 0;
#pragma unroll
        for (int k = 0; k < 32; ++k) {
            int c = j * 32 + k;
            float4 s = st[c];
            float v = ((float)qp[(size_t)c * HW] - s.x) * s.y + s.z;
            sv |= (u32)(v > 0.f) << k;
            nv |= (u32)(v != 0.f) << k;
        }
        ap[j] = sv; ap[W + j] = nv;
    }
}

// --- 1x1 conv, Cin=64, Cout=256, HW=256, int8 out. Thread=(b,hw). ---
__global__ __launch_bounds__(256) void k_conv1x1_bp2(const u32* __restrict__ act,
                                                     const u32* __restrict__ wp,
                                                     signed char* __restrict__ out)
{
    int t = blockIdx.x * 256 + threadIdx.x;   // t = b*256 + hw
    int hw = t & 255; int b = t >> 8;
    uint4 av = ((const uint4*)act)[t];        // s0,s1,n0,n1
    signed char* op = out + (size_t)b * 256 * 256 + hw;
#pragma unroll 8
    for (int oc = 0; oc < 256; ++oc) {
        uint4 wv = ((const uint4*)wp)[oc];    // wave-uniform -> scalar loads
        u32 nz0 = av.z & wv.z, nz1 = av.w & wv.w;
        u32 m0 = (av.x ^ wv.x) & nz0, m1 = (av.y ^ wv.y) & nz1;
        int dot = __popc(nz0) + __popc(nz1) - 2 * (__popc(m0) + __popc(m1));
        op[(size_t)oc << 8] = (signed char)dot;
    }
}

// --- 1x1 conv, Cin=256, Cout=256 (4 chunks), HW=64, int16 out. ---
__global__ __launch_bounds__(256) void k_conv1x1_bp3(const u32* __restrict__ act,
                                                     const u32* __restrict__ wp,
                                                     short* __restrict__ out)
{
    int t = blockIdx.x * 256 + threadIdx.x;
    int hw = t & 63; int ch = (t >> 6) & 3; int b = t >> 8;
    const u32* ap = act + (size_t)(b * 64 + hw) * 16;
    u32 as[8], an[8];
#pragma unroll
    for (int j = 0; j < 8; ++j) { as[j] = ap[j]; an[j] = ap[8 + j]; }
    short* op = out + (size_t)b * 256 * 64 + hw;
#pragma unroll 4
    for (int oc = ch * 64; oc < ch * 64 + 64; ++oc) {
        const u32* wq = wp + oc * 16;
        int snz = 0, smis = 0;
#pragma unroll
        for (int j = 0; j < 8; ++j) {
            u32 nz = an[j] & wq[8 + j];
            u32 m = (as[j] ^ wq[j]) & nz;
            snz += __popc(nz); smis += __popc(m);
        }
        op[(size_t)oc * 64] = (short)(snz - 2 * smis);
    }
}

// --- FC prep (merged): fold bn3_2 into fc weights / bias ---
__global__ __launch_bounds__(256) void k_fcprep(const float* __restrict__ fcw,
                                                const float4* __restrict__ st,
                                                const float* __restrict__ fcb,
                                                float* __restrict__ w2,
                                                float* __restrict__ bias2)
{
    if (blockIdx.x < 640) {
        int idx = blockIdx.x * 256 + threadIdx.x;   // < 163840
        int k = idx & 16383;
        w2[idx] = fcw[idx] * st[k >> 6].y;
        return;
    }
    int n = blockIdx.x - 640;
    const float* p = fcw + (size_t)n * 16384;
    float acc = 0.f;
    for (int k = threadIdx.x; k < 16384; k += 256) {
        float4 s = st[k >> 6];
        acc += p[k] * (s.z - s.x * s.y);
    }
    __shared__ float ss[256];
    ss[threadIdx.x] = acc;
    __syncthreads();
    for (int stp = 128; stp > 0; stp >>= 1) {
        if (threadIdx.x < stp) ss[threadIdx.x] += ss[threadIdx.x + stp];
        __syncthreads();
    }
    if (threadIdx.x == 0) bias2[n] = ss[0] + fcb[n];
}

// --- FC: block per image, int16 features read once, 10 accumulators ---
__global__ __launch_bounds__(256) void k_fc2(const short* __restrict__ f,
                                             const float* __restrict__ w2,
                                             const float* __restrict__ bias2,
                                             float* __restrict__ out)
{
    int b = blockIdx.x, t = threadIdx.x;
    int lane = t & 63, wv = t >> 6;
    const u32* fp = (const u32*)(f + (size_t)b * 16384);
    float acc[10];
#pragma unroll
    for (int n = 0; n < 10; ++n) acc[n] = 0.f;
    for (int i = 0; i < 32; ++i) {
        int j = i * 256 + t;                 // u32 index; features 2j, 2j+1
        u32 v = fp[j];
        float f0 = (float)((int)(v << 16) >> 16);
        float f1 = (float)((int)v >> 16);
#pragma unroll
        for (int n = 0; n < 10; ++n) {
            float2 wv2 = *(const float2*)(w2 + (size_t)n * 16384 + 2 * j);
            acc[n] += f0 * wv2.x + f1 * wv2.y;
        }
    }
#pragma unroll
    for (int n = 0; n < 10; ++n)
#pragma unroll
        for (int m = 1; m < 64; m <<= 1) acc[n] += __shfl_xor(acc[n], m);
    __shared__ float sred[4][10];
    if (lane == 0)
#pragma unroll
        for (int n = 0; n < 10; ++n) sred[wv][n] = acc[n];
    __syncthreads();
    if (t < 10)
        out[b * 10 + t] = sred[0][t] + sred[1][t] + sred[2][t] + sred[3][t] + bias2[t];
}

extern "C" void kernel_launch(void* const* d_in, const int* in_sizes, int n_in,
                              void* d_out, int out_size, void* d_ws, size_t ws_size,
                              hipStream_t stream)
{
    const float* x    = (const float*)d_in[0];
    const float* w1   = (const float*)d_in[1];
    const float* g1   = (const float*)d_in[2];
    const float* b1   = (const float*)d_in[3];
    const float* w2_1 = (const float*)d_in[4];
    const float* g2_1 = (const float*)d_in[5];
    const float* b2_1 = (const float*)d_in[6];
    const float* w2_2 = (const float*)d_in[7];
    const float* g2_2 = (const float*)d_in[8];
    const float* b2_2 = (const float*)d_in[9];
    const float* w3_1 = (const float*)d_in[10];
    const float* g3_1 = (const float*)d_in[11];
    const float* b3_1 = (const float*)d_in[12];
    const float* w3_2 = (const float*)d_in[13];
    const float* g3_2 = (const float*)d_in[14];
    const float* b3_2 = (const float*)d_in[15];
    const float* fcw  = (const float*)d_in[16];
    const float* fcb  = (const float*)d_in[17];
    float* out = (float*)d_out;

    // workspace layout (bytes). pmax/pmin alias later c22/f3/q8 (write-after-
    // consume ordering verified in launch sequence below).
    const size_t OFF_PMAX = 0;          // 33,554,432  (-> c22 later)
    const size_t OFF_PMIN = 33554432;   // 33,554,432  (-> f3 @33.5M, q8 @50.3M)
    const size_t OFF_F3   = 33554432;   // 16,777,216  conv3_2 int16 out
    const size_t OFF_Q    = 50331648;   //  8,388,608  convg int8 outs
    const size_t OFF_SPK2 = 67108864;   //  2,621,440  [512][64][20]
    const size_t OFF_NPK2 = 69730304;   //  2,621,440
    const size_t OFF_SPK3 = 72351744;   //  6,291,456  [512][256][12]
    const size_t OFF_NPK3 = 78643200;   //  6,291,456
    const size_t OFF_A    = 84934656;   //  2,097,152  packed acts
    const size_t OFF_WPK21= 87031808;   //  2,048
    const size_t OFF_WPK31= 87033856;   //  8,192
    const size_t OFF_WP22 = 87042048;   //  4,096
    const size_t OFF_WP32 = 87046144;   //  16,384
    const size_t OFF_PART = 87062528;   //  2,097,152  (max 256ch x 512 x 2 f64)
    const size_t OFF_ST   = 89159680;   //  20,480     5 x 256 float4
    const size_t OFF_SW1  = 89180160;   //  12,288     conv1 signed weights f32
    const size_t OFF_W2   = 89192448;   //  655,360    bn-folded fc weights
    const size_t OFF_B2   = 89847808;   //  256        bn-folded fc bias
    const size_t NEED     = OFF_B2 + 256;
    if (ws_size < NEED) return;

    char* ws = (char*)d_ws;
    float* pmax = (float*)(ws + OFF_PMAX);
    float* pmin = (float*)(ws + OFF_PMIN);
    signed char* c22 = (signed char*)(ws + OFF_PMAX);  // after bnpick consumes pmax
    short* f3  = (short*)(ws + OFF_F3);                // after bnpick consumes pmin
    signed char* q8 = (signed char*)(ws + OFF_Q);      // after bnpick consumes pmin
    u32* spk2  = (u32*)(ws + OFF_SPK2);
    u32* npk2  = (u32*)(ws + OFF_NPK2);
    u32* spk3  = (u32*)(ws + OFF_SPK3);
    u32* npk3  = (u32*)(ws + OFF_NPK3);
    u32* actA  = (u32*)(ws + OFF_A);
    u32* wpk21 = (u32*)(ws + OFF_WPK21);
    u32* wpk31 = (u32*)(ws + OFF_WPK31);
    u32* wp22  = (u32*)(ws + OFF_WP22);
    u32* wp32  = (u32*)(ws + OFF_WP32);
    double* part = (double*)(ws + OFF_PART);
    float4* st1  = (float4*)(ws + OFF_ST);
    float4* st21 = st1 + 256;
    float4* st22 = st21 + 256;
    float4* st31 = st22 + 256;
    float4* st32 = st31 + 256;
    float* sw1f  = (float*)(ws + OFF_SW1);
    float* w2f   = (float*)(ws + OFF_W2);
    float* b2f   = (float*)(ws + OFF_B2);

    // ---- weight prep (all binarized weights, one launch) ----
    k_wprep<<<14, 256, 0, stream>>>(w1, sw1f, w2_1, wpk21, w3_1, wpk31, w2_2, wp22, w3_2, wp32);

    // ---- layer 1: one fused conv pass ----
    k_conv1f<<<2048, 256, 0, stream>>>(x, sw1f, pmax, pmin, part);
    k_finalize2<<<64, 256, 0, stream>>>(part, 2048, 512 * 1024, g1, b1, st1);
    k_bnpick<<<32768, 256, 0, stream>>>(pmax, pmin, st1, spk2, npk2);    // packed 16x16

    // ---- layer 2 ----
    k_convg_bp<64, 16><<<1024, 256, 0, stream>>>(spk2, npk2, wpk21, q8, part);
    k_finalize2<<<64, 256, 0, stream>>>(part, 512, 512 * 256, g2_1, b2_1, st21);
    k_bnpackC<64, 256><<<512, 256, 0, stream>>>(q8, st21, actA);
    k_conv1x1_bp2<<<512, 256, 0, stream>>>(actA, wp22, c22);             // [512,256,16,16] i8
    k_stats_i8<<<dim3(256, 32), 256, 0, stream>>>(c22, part, 256, 256, 16);
    k_finalize2<<<256, 256, 0, stream>>>(part, 32, 512 * 256, g2_2, b2_2, st22);
    k_poolpack3<<<32768, 256, 0, stream>>>(c22, st22, spk3, npk3);       // packed 8x8

    // ---- layer 3 ----
    k_convg_bp<256, 8><<<2048, 256, 0, stream>>>(spk3, npk3, wpk31, q8, part);
    k_finalize2<<<256, 256, 0, stream>>>(part, 512, 512 * 64, g3_1, b3_1, st31);
    k_bnpackC<256, 64><<<128, 256, 0, stream>>>(q8, st31, actA);
    k_conv1x1_bp3<<<512, 256, 0, stream>>>(actA, wp32, f3);              // [512,256,8,8] i16
    k_stats_i16<<<dim3(256, 32), 256, 0, stream>>>(f3, part, 256, 64, 16);
    k_finalize2<<<256, 256, 0, stream>>>(part, 32, 512 * 64, g3_2, b3_2, st32);

    // ---- FC (bn3_2 folded into weights) ----
    k_fcprep<<<650, 256, 0, stream>>>(fcw, st32, fcb, w2f, b2f);
    k_fc2<<<512, 256, 0, stream>>>(f3, w2f, b2f, out);
}

// Round 9
// 341.401 us; speedup vs baseline: 1.0860x; 1.0860x over previous
//
#include <hip/hip_runtime.h>

typedef unsigned int u32;

// ---------------------------------------------------------------------------
// LiBNet forward, bit-packed ternary arithmetic + integer intermediates.
// dot over taps = popc(nzA & nzW) - 2*popc((sA ^ sW) & nzA & nzW)
// conv1: padded-global window (register-resident by alias analysis),
// DPP-quad pool/stats (no LDS-pipe cross-lane ops).
// ---------------------------------------------------------------------------

static __device__ __forceinline__ float fsign(float x) {
    return (x > 0.f) ? 1.f : ((x < 0.f) ? -1.f : 0.f);
}
static __device__ __forceinline__ u32 pack4(int a, int b, int c, int d) {
    return (a & 0xff) | ((b & 0xff) << 8) | ((c & 0xff) << 16) | ((u32)(d & 0xff) << 24);
}
// quad_perm DPP on float (VALU, no LDS pipe). 0xB1 = lane^1, 0x4E = lane^2.
template <int CTRL>
static __device__ __forceinline__ float dppf(float x) {
    int i = __builtin_amdgcn_mov_dpp(__float_as_int(x), CTRL, 0xF, 0xF, true);
    return __int_as_float(i);
}

// --- weight prep + input padding (one launch) ---
__global__ __launch_bounds__(256) void k_wprep(const float* __restrict__ w1, float* __restrict__ sw1f,
                                               const float* __restrict__ w2_1, u32* __restrict__ wpk21,
                                               const float* __restrict__ w3_1, u32* __restrict__ wpk31,
                                               const float* __restrict__ w2_2, u32* __restrict__ wp22,
                                               const float* __restrict__ w3_2, u32* __restrict__ wp32,
                                               const float* __restrict__ x, float* __restrict__ xpad)
{
    int blk = blockIdx.x, tid = threadIdx.x;
    if (blk >= 14) {                    // pad x -> xpad[512*3][35][35]
        int i = (blk - 14) * 256 + tid;
        if (i < 1881600) {
            int bic = i / 1225;
            int rem = i - bic * 1225;
            int r = rem / 35, c = rem - r * 35;
            float v = 0.f;
            if (r >= 1 && r <= 32 && c >= 1 && c <= 32)
                v = x[bic * 1024 + (r - 1) * 32 + (c - 1)];
            xpad[i] = v;
        }
        return;
    }
    if (blk < 12) {
        int i = blk * 256 + tid;
        if (i < 3072) sw1f[i] = fsign(w1[i]);
        return;
    }
    if (blk == 12) {
        if (tid < 64) {   // grouped 4x4 weights, C=64
            const float* p = w2_1 + tid * 32;
            for (int r = 0; r < 8; ++r) {
                u32 sn = 0, nz = 0;
                for (int kw = 0; kw < 4; ++kw) {
                    float v = p[r * 4 + kw];
                    sn |= (u32)(v > 0.f) << kw;
                    nz |= (u32)(v != 0.f) << kw;
                }
                wpk21[tid * 8 + r] = sn | (nz << 8);
            }
        }
        {                 // 1x1 weights 256x64
            const float* p = w2_2 + (size_t)tid * 64;
            for (int j = 0; j < 2; ++j) {
                u32 sv = 0, nv = 0;
                for (int k = 0; k < 32; ++k) {
                    float v = p[j * 32 + k];
                    sv |= (u32)(v > 0.f) << k;
                    nv |= (u32)(v != 0.f) << k;
                }
                wp22[tid * 4 + j] = sv;
                wp22[tid * 4 + 2 + j] = nv;
            }
        }
        return;
    }
    {                     // blk == 13
        {                 // grouped 4x4 weights, C=256
            const float* p = w3_1 + tid * 32;
            for (int r = 0; r < 8; ++r) {
                u32 sn = 0, nz = 0;
                for (int kw = 0; kw < 4; ++kw) {
                    float v = p[r * 4 + kw];
                    sn |= (u32)(v > 0.f) << kw;
                    nz |= (u32)(v != 0.f) << kw;
                }
                wpk31[tid * 8 + r] = sn | (nz << 8);
            }
        }
        {                 // 1x1 weights 256x256
            const float* p = w3_2 + (size_t)tid * 256;
            for (int j = 0; j < 8; ++j) {
                u32 sv = 0, nv = 0;
                for (int k = 0; k < 32; ++k) {
                    float v = p[j * 32 + k];
                    sv |= (u32)(v > 0.f) << k;
                    nv |= (u32)(v != 0.f) << k;
                }
                wp32[tid * 16 + j] = sv;
                wp32[tid * 16 + 8 + j] = nv;
            }
        }
    }
}

// --- conv1 fused: global padded window, DPP-quad pool + stats ---
// lane = (w<<1)|hb: quad of 4 lanes == one 2x2 pool window.
__global__ __launch_bounds__(256, 4) void k_conv1f(const float* __restrict__ xpad,
                                                   const float* __restrict__ swf,
                                                   float* __restrict__ pmax,
                                                   float* __restrict__ pmin,
                                                   double* __restrict__ part)
{
    __shared__ float sacc_s[64 * 65];   // [oc][64 s4-partials], pad 65
    __shared__ float sacc_q[64 * 65];
    int b = blockIdx.x >> 2, q = blockIdx.x & 3;
    int lane = threadIdx.x & 63, wv = threadIdx.x >> 6;
    int w = lane >> 1, hb = lane & 1;
    int h = q * 8 + wv * 2 + hb;
    int oh = q * 4 + wv;
    int ow = lane >> 2;
    const float* xb = xpad + (size_t)b * 3675;
    float in[48];
#pragma unroll
    for (int ic = 0; ic < 3; ++ic)
#pragma unroll
        for (int kh = 0; kh < 4; ++kh)
#pragma unroll
            for (int kw = 0; kw < 4; ++kw)
                in[ic * 16 + kh * 4 + kw] = xb[ic * 1225 + (h + kh) * 35 + w + kw];
    bool owner = ((lane & 3) == 0);
    float* pmaxb = pmax + (size_t)(b * 64) * 256 + oh * 16 + ow;
    float* pminb = pmin + (size_t)(b * 64) * 256 + oh * 16 + ow;
#pragma unroll 2
    for (int oc = 0; oc < 64; ++oc) {
        const float* wp = swf + oc * 48;   // wave-uniform -> s_load
        float a0 = 0.f, a1 = 0.f, a2 = 0.f, a3 = 0.f;
#pragma unroll
        for (int k = 0; k < 48; k += 4) {
            a0 += in[k]     * wp[k];
            a1 += in[k + 1] * wp[k + 1];
            a2 += in[k + 2] * wp[k + 2];
            a3 += in[k + 3] * wp[k + 3];
        }
        float v = (a0 + a1) + (a2 + a3);
        float p  = dppf<0xB1>(v);                 // vertical neighbor (lane^1)
        float s2 = v + p;
        float sq2 = v * v + p * p;
        float mx = fmaxf(v, p), mn = fminf(v, p);
        float s4  = s2  + dppf<0x4E>(s2);         // horizontal (lane^2)
        float sq4 = sq2 + dppf<0x4E>(sq2);
        float mx2 = fmaxf(mx, dppf<0x4E>(mx));
        float mn2 = fminf(mn, dppf<0x4E>(mn));
        if (owner) {
            int idx = oc * 65 + wv * 16 + ow;
            sacc_s[idx] = s4;
            sacc_q[idx] = sq4;
            pmaxb[oc * 256] = mx2;
            pminb[oc * 256] = mn2;
        }
    }
    __syncthreads();
    if (threadIdx.x < 128) {
        int oc = threadIdx.x >> 1, half = threadIdx.x & 1;
        const float* sp = (half ? sacc_q : sacc_s) + oc * 65;
        double acc = 0.0;
        for (int j = 0; j < 64; ++j) acc += (double)sp[j];
        part[((size_t)oc * 2048 + blockIdx.x) * 2 + half] = acc;
    }
}

// --- bn pick (max if scale>0 else min) + binarize + row-bitpack ---
__global__ __launch_bounds__(256) void k_bnpick(const float* __restrict__ pmax,
                                                const float* __restrict__ pmin,
                                                const float4* __restrict__ st,
                                                u32* __restrict__ spk,
                                                u32* __restrict__ npk)
{
    int bc = blockIdx.x;              // b*64 + c
    int c = bc & 63;
    int t = threadIdx.x;
    int lane = t & 63, wv = t >> 6;
    float4 s = st[c];
    float mx = pmax[(size_t)bc * 256 + t];
    float mn = pmin[(size_t)bc * 256 + t];
    float raw = (s.y > 0.f) ? mx : mn;
    float v = (raw - s.x) * s.y + s.z;
    unsigned long long bs = __ballot(v > 0.f);
    unsigned long long bn = __ballot(v != 0.f);
    int r = lane >> 4;                // row within wave (4 rows x 16 cols)
    int oh = wv * 4 + r;
    size_t base = (size_t)bc * 20;
    if ((lane & 15) == 0) {
        spk[base + 1 + oh] = (((u32)(bs >> (16 * r))) & 0xffffu) << 1;
        npk[base + 1 + oh] = (((u32)(bn >> (16 * r))) & 0xffffu) << 1;
    }
    if (t < 4) {                      // zero margin slots 0,17,18,19
        int zs = (t == 0) ? 0 : (16 + t);
        spk[base + zs] = 0; npk[base + zs] = 0;
    }
}

// --- int8 stats: exact int32 block sums -> double partials ---
__global__ __launch_bounds__(256) void k_stats_i8(const signed char* __restrict__ in,
                                                  double* __restrict__ part,
                                                  int C, int HW, int bPerChunk)
{
    int c = blockIdx.x, chunk = blockIdx.y, b0 = chunk * bPerChunk;
    int q4 = HW >> 2;
    int s = 0, sq = 0;
    for (int b = b0; b < b0 + bPerChunk; ++b) {
        const u32* p = (const u32*)(in + (size_t)(b * C + c) * HW);
        for (int i = threadIdx.x; i < q4; i += 256) {
            u32 v = p[i];
            int x0 = (int)(v << 24) >> 24, x1 = (int)(v << 16) >> 24;
            int x2 = (int)(v << 8) >> 24,  x3 = (int)v >> 24;
            s += x0 + x1 + x2 + x3;
            sq += x0 * x0 + x1 * x1 + x2 * x2 + x3 * x3;
        }
    }
    __shared__ int ss[256];
    __shared__ int sb[256];
    ss[threadIdx.x] = s; sb[threadIdx.x] = sq;
    __syncthreads();
    for (int st = 128; st > 0; st >>= 1) {
        if (threadIdx.x < st) {
            ss[threadIdx.x] += ss[threadIdx.x + st];
            sb[threadIdx.x] += sb[threadIdx.x + st];
        }
        __syncthreads();
    }
    if (threadIdx.x == 0) {
        int nch = gridDim.y;
        part[(size_t)(c * nch + chunk) * 2]     = (double)ss[0];
        part[(size_t)(c * nch + chunk) * 2 + 1] = (double)sb[0];
    }
}

// --- int16 stats ---
__global__ __launch_bounds__(256) void k_stats_i16(const short* __restrict__ in,
                                                   double* __restrict__ part,
                                                   int C, int HW, int bPerChunk)
{
    int c = blockIdx.x, chunk = blockIdx.y, b0 = chunk * bPerChunk;
    int q2 = HW >> 1;
    int s = 0, sq = 0;
    for (int b = b0; b < b0 + bPerChunk; ++b) {
        const u32* p = (const u32*)(in + (size_t)(b * C + c) * HW);
        for (int i = threadIdx.x; i < q2; i += 256) {
            u32 v = p[i];
            int x0 = (int)(v << 16) >> 16, x1 = (int)v >> 16;
            s += x0 + x1;
            sq += x0 * x0 + x1 * x1;
        }
    }
    __shared__ int ss[256];
    __shared__ int sb[256];
    ss[threadIdx.x] = s; sb[threadIdx.x] = sq;
    __syncthreads();
    for (int st = 128; st > 0; st >>= 1) {
        if (threadIdx.x < st) {
            ss[threadIdx.x] += ss[threadIdx.x + st];
            sb[threadIdx.x] += sb[threadIdx.x + st];
        }
        __syncthreads();
    }
    if (threadIdx.x == 0) {
        int nch = gridDim.y;
        part[(size_t)(c * nch + chunk) * 2]     = (double)ss[0];
        part[(size_t)(c * nch + chunk) * 2 + 1] = (double)sb[0];
    }
}

// --- finalize: block per channel; mean/var -> power-of-two shift scale ---
__global__ __launch_bounds__(256) void k_finalize2(const double* __restrict__ part,
                                                   int nch, int N,
                                                   const float* __restrict__ gamma,
                                                   const float* __restrict__ beta,
                                                   float4* __restrict__ st)
{
    int c = blockIdx.x;
    double s = 0.0, sq = 0.0;
    for (int i = threadIdx.x; i < nch; i += 256) {
        s  += part[((size_t)c * nch + i) * 2];
        sq += part[((size_t)c * nch + i) * 2 + 1];
    }
    __shared__ double ss[256];
    __shared__ double sb[256];
    ss[threadIdx.x] = s; sb[threadIdx.x] = sq;
    __syncthreads();
    for (int stp = 128; stp > 0; stp >>= 1) {
        if (threadIdx.x < stp) {
            ss[threadIdx.x] += ss[threadIdx.x + stp];
            sb[threadIdx.x] += sb[threadIdx.x + stp];
        }
        __syncthreads();
    }
    if (threadIdx.x == 0) {
        double mean = ss[0] / (double)N;
        double var = sb[0] / (double)N - mean * mean;
        float inv = gamma[c] / sqrtf((float)var + 1e-5f);
        float sh = rintf(log2f(fabsf(inv) + 1e-12f));
        sh = fminf(fmaxf(sh, -4.f), 4.f);
        float scale = copysignf(exp2f(sh), inv);
        st[c] = make_float4((float)mean, scale, beta[c], 0.f);
    }
}

// --- layer2->3 bn+pool+pack: int8 in [512,256,16,16], wave per channel ---
__global__ __launch_bounds__(256) void k_poolpack3(const signed char* __restrict__ in,
                                                   const float4* __restrict__ st,
                                                   u32* __restrict__ spk,
                                                   u32* __restrict__ npk)
{
    int wv = threadIdx.x >> 6, lane = threadIdx.x & 63;
    int bc = blockIdx.x * 4 + wv;     // b*256 + c
    int c = bc & 255;
    int oh = lane >> 3, ow = lane & 7;
    float4 s = st[c];
    const signed char* p = in + (size_t)bc * 256 + (2 * oh) * 16 + 2 * ow;
    short s01 = *(const short*)p;
    short s23 = *(const short*)(p + 16);
    int a0 = (int)(signed char)(s01 & 0xff), a1 = (int)(s01 >> 8);
    int a2 = (int)(signed char)(s23 & 0xff), a3 = (int)(s23 >> 8);
    bool pos = (s.y > 0.f);
    int raw = pos ? max(max(a0, a1), max(a2, a3)) : min(min(a0, a1), min(a2, a3));
    float v = ((float)raw - s.x) * s.y + s.z;
    unsigned long long bs = __ballot(v > 0.f);
    unsigned long long bn = __ballot(v != 0.f);
    size_t base = (size_t)bc * 12;
    if (ow == 0) {
        spk[base + 1 + oh] = (((u32)(bs >> (8 * oh))) & 0xffu) << 1;
        npk[base + 1 + oh] = (((u32)(bn >> (8 * oh))) & 0xffu) << 1;
    }
    if (lane < 4) {                   // zero margin slots 0,9,10,11
        int zs = (lane == 0) ? 0 : (8 + lane);
        spk[base + zs] = 0; npk[base + zs] = 0;
    }
}

// --- grouped 4x4 binary conv, bit-packed in, int8 out, FUSED bn stats. ---
template <int C, int H>
__global__ __launch_bounds__(256) void k_convg_bp(const u32* __restrict__ spk,
                                                  const u32* __restrict__ npk,
                                                  const u32* __restrict__ wpk,
                                                  signed char* __restrict__ out,
                                                  double* __restrict__ part)
{
    constexpr int SLOTS = (H == 16) ? 20 : 12;
    int t = blockIdx.x * 256 + threadIdx.x;
    int h = t % H; int r0 = t / H;
    int g = r0 % (C / 2); int b = r0 / (C / 2);
    int lane = threadIdx.x & 63;
    const u32* sp = spk + (size_t)(b * C + 2 * g) * SLOTS + h;
    const u32* np = npk + (size_t)(b * C + 2 * g) * SLOTS + h;
    u32 S[8], N[8];
#pragma unroll
    for (int jc = 0; jc < 2; ++jc)
#pragma unroll
        for (int jj = 0; jj < 4; ++jj) {    // slot h+jj = input row h-1+jj
            S[jc * 4 + jj] = sp[jc * SLOTS + jj];
            N[jc * 4 + jj] = np[jc * SLOTS + jj];
        }
    const u32* wq = wpk + (size_t)(2 * g) * 8;
    u32 Ws0[8], Wn0[8], Ws1[8], Wn1[8];
#pragma unroll
    for (int r = 0; r < 8; ++r) {
        u32 a = wq[r];      Ws0[r] = a & 15u;  Wn0[r] = (a >> 8) & 15u;
        u32 bb = wq[8 + r]; Ws1[r] = bb & 15u; Wn1[r] = (bb >> 8) & 15u;
    }
    int v0[H], v1[H];
    int s0 = 0, q0 = 0, s1 = 0, q1 = 0;
#pragma unroll
    for (int w = 0; w < H; ++w) {
        int snz0 = 0, smis0 = 0, snz1 = 0, smis1 = 0;
#pragma unroll
        for (int r = 0; r < 8; ++r) {
            u32 ss = (S[r] >> w) & 15u;
            u32 nn = (N[r] >> w) & 15u;
            u32 nz0 = nn & Wn0[r]; u32 m0 = (ss ^ Ws0[r]) & nz0;
            snz0 += __popc(nz0); smis0 += __popc(m0);
            u32 nz1 = nn & Wn1[r]; u32 m1 = (ss ^ Ws1[r]) & nz1;
            snz1 += __popc(nz1); smis1 += __popc(m1);
        }
        v0[w] = snz0 - 2 * smis0;
        v1[w] = snz1 - 2 * smis1;
        s0 += v0[w]; q0 += v0[w] * v0[w];
        s1 += v1[w]; q1 += v1[w] * v1[w];
    }
    // group-of-H lanes (aligned) hold one (b, g): butterfly int reduce
#pragma unroll
    for (int m = 1; m < H; m <<= 1) {
        s0 += __shfl_xor(s0, m); q0 += __shfl_xor(q0, m);
        s1 += __shfl_xor(s1, m); q1 += __shfl_xor(q1, m);
    }
    if ((lane & (H - 1)) == 0) {
        part[((size_t)(2 * g) * 512 + b) * 2]         = (double)s0;
        part[((size_t)(2 * g) * 512 + b) * 2 + 1]     = (double)q0;
        part[((size_t)(2 * g + 1) * 512 + b) * 2]     = (double)s1;
        part[((size_t)(2 * g + 1) * 512 + b) * 2 + 1] = (double)q1;
    }
    signed char* o0 = out + ((size_t)((b * C + 2 * g) * H + h)) * H;
    signed char* o1 = o0 + (size_t)H * H;
    u32 wb0[H / 4], wb1[H / 4];
#pragma unroll
    for (int j = 0; j < H / 4; ++j) {
        wb0[j] = pack4(v0[4*j], v0[4*j+1], v0[4*j+2], v0[4*j+3]);
        wb1[j] = pack4(v1[4*j], v1[4*j+1], v1[4*j+2], v1[4*j+3]);
    }
    if constexpr (H == 16) {
        *(uint4*)o0 = make_uint4(wb0[0], wb0[1], wb0[2], wb0[3]);
        *(uint4*)o1 = make_uint4(wb1[0], wb1[1], wb1[2], wb1[3]);
    } else {
        *(uint2*)o0 = make_uint2(wb0[0], wb0[1]);
        *(uint2*)o1 = make_uint2(wb1[0], wb1[1]);
    }
}

// --- 1x1 conv Cin=64->Cout=256, HW=256, int8 out, FUSED bn2_1 binarize+pack ---
__global__ __launch_bounds__(256) void k_conv1x1_bp2(const signed char* __restrict__ q8,
                                                     const float4* __restrict__ st,
                                                     const u32* __restrict__ wp,
                                                     signed char* __restrict__ out)
{
    int t = blockIdx.x * 256 + threadIdx.x;   // t = b*256 + hw
    int hw = t & 255; int b = t >> 8;
    const signed char* qp = q8 + (size_t)b * 64 * 256 + hw;
    u32 as0 = 0, as1 = 0, an0 = 0, an1 = 0;
#pragma unroll
    for (int k = 0; k < 32; ++k) {
        float4 s = st[k];                       // uniform -> s_load
        float v = ((float)qp[k * 256] - s.x) * s.y + s.z;   // coalesced byte load
        as0 |= (u32)(v > 0.f) << k;
        an0 |= (u32)(v != 0.f) << k;
    }
#pragma unroll
    for (int k = 0; k < 32; ++k) {
        float4 s = st[32 + k];
        float v = ((float)qp[(32 + k) * 256] - s.x) * s.y + s.z;
        as1 |= (u32)(v > 0.f) << k;
        an1 |= (u32)(v != 0.f) << k;
    }
    signed char* op = out + (size_t)b * 256 * 256 + hw;
#pragma unroll 8
    for (int oc = 0; oc < 256; ++oc) {
        uint4 wv = ((const uint4*)wp)[oc];      // wave-uniform -> scalar loads
        u32 nz0 = an0 & wv.z, nz1 = an1 & wv.w;
        u32 m0 = (as0 ^ wv.x) & nz0, m1 = (as1 ^ wv.y) & nz1;
        int dot = __popc(nz0) + __popc(nz1) - 2 * (__popc(m0) + __popc(m1));
        op[(size_t)oc << 8] = (signed char)dot;
    }
}

// --- bn + binarize + channel-pack, C=256 HW=64, LDS-staged transpose ---
__global__ __launch_bounds__(256) void k_bnpackC256(const signed char* __restrict__ q8,
                                                    const float4* __restrict__ st,
                                                    u32* __restrict__ act)
{
    __shared__ u32 sq[4096];   // one image: 256ch x 64hw bytes
    int b = blockIdx.x;
    const u32* qb = (const u32*)(q8 + (size_t)b * 16384);
    for (int i = threadIdx.x; i < 4096; i += 256) sq[i] = qb[i];
    __syncthreads();
    const signed char* s8p = (const signed char*)sq;
    int hw = threadIdx.x & 63, qd = threadIdx.x >> 6;   // qd: 64-channel quarter
    u32 sv0 = 0, nv0 = 0, sv1 = 0, nv1 = 0;
#pragma unroll
    for (int k = 0; k < 32; ++k) {
        int c = qd * 64 + k;
        float4 s = st[c];
        float v = ((float)s8p[c * 64 + hw] - s.x) * s.y + s.z;
        sv0 |= (u32)(v > 0.f) << k;
        nv0 |= (u32)(v != 0.f) << k;
    }
#pragma unroll
    for (int k = 0; k < 32; ++k) {
        int c = qd * 64 + 32 + k;
        float4 s = st[c];
        float v = ((float)s8p[c * 64 + hw] - s.x) * s.y + s.z;
        sv1 |= (u32)(v > 0.f) << k;
        nv1 |= (u32)(v != 0.f) << k;
    }
    u32* ap = act + ((size_t)b * 64 + hw) * 16;
    ap[qd * 2]     = sv0;
    ap[qd * 2 + 1] = sv1;
    ap[8 + qd * 2]     = nv0;
    ap[8 + qd * 2 + 1] = nv1;
}

// --- 1x1 conv, Cin=256, Cout=256 (4 chunks), HW=64, int16 out. ---
__global__ __launch_bounds__(256) void k_conv1x1_bp3(const u32* __restrict__ act,
                                                     const u32* __restrict__ wp,
                                                     short* __restrict__ out)
{
    int t = blockIdx.x * 256 + threadIdx.x;
    int hw = t & 63; int ch = (t >> 6) & 3; int b = t >> 8;
    const u32* ap = act + (size_t)(b * 64 + hw) * 16;
    u32 as[8], an[8];
#pragma unroll
    for (int j = 0; j < 8; ++j) { as[j] = ap[j]; an[j] = ap[8 + j]; }
    short* op = out + (size_t)b * 256 * 64 + hw;
#pragma unroll 4
    for (int oc = ch * 64; oc < ch * 64 + 64; ++oc) {
        const u32* wq = wp + oc * 16;
        int snz = 0, smis = 0;
#pragma unroll
        for (int j = 0; j < 8; ++j) {
            u32 nz = an[j] & wq[8 + j];
            u32 m = (as[j] ^ wq[j]) & nz;
            snz += __popc(nz); smis += __popc(m);
        }
        op[(size_t)oc * 64] = (short)(snz - 2 * smis);
    }
}

// --- FC prep (merged): fold bn3_2 into fc weights / bias ---
__global__ __launch_bounds__(256) void k_fcprep(const float* __restrict__ fcw,
                                                const float4* __restrict__ st,
                                                const float* __restrict__ fcb,
                                                float* __restrict__ w2,
                                                float* __restrict__ bias2)
{
    if (blockIdx.x < 640) {
        int idx = blockIdx.x * 256 + threadIdx.x;   // < 163840
        int k = idx & 16383;
        w2[idx] = fcw[idx] * st[k >> 6].y;
        return;
    }
    int n = blockIdx.x - 640;
    const float* p = fcw + (size_t)n * 16384;
    float acc = 0.f;
    for (int k = threadIdx.x; k < 16384; k += 256) {
        float4 s = st[k >> 6];
        acc += p[k] * (s.z - s.x * s.y);
    }
    __shared__ float ss[256];
    ss[threadIdx.x] = acc;
    __syncthreads();
    for (int stp = 128; stp > 0; stp >>= 1) {
        if (threadIdx.x < stp) ss[threadIdx.x] += ss[threadIdx.x + stp];
        __syncthreads();
    }
    if (threadIdx.x == 0) bias2[n] = ss[0] + fcb[n];
}

// --- FC: block per image, int16 features read once, 10 accumulators ---
__global__ __launch_bounds__(256) void k_fc2(const short* __restrict__ f,
                                             const float* __restrict__ w2,
                                             const float* __restrict__ bias2,
                                             float* __restrict__ out)
{
    int b = blockIdx.x, t = threadIdx.x;
    int lane = t & 63, wv = t >> 6;
    const u32* fp = (const u32*)(f + (size_t)b * 16384);
    float acc[10];
#pragma unroll
    for (int n = 0; n < 10; ++n) acc[n] = 0.f;
    for (int i = 0; i < 32; ++i) {
        int j = i * 256 + t;                 // u32 index; features 2j, 2j+1
        u32 v = fp[j];
        float f0 = (float)((int)(v << 16) >> 16);
        float f1 = (float)((int)v >> 16);
#pragma unroll
        for (int n = 0; n < 10; ++n) {
            float2 wv2 = *(const float2*)(w2 + (size_t)n * 16384 + 2 * j);
            acc[n] += f0 * wv2.x + f1 * wv2.y;
        }
    }
#pragma unroll
    for (int n = 0; n < 10; ++n)
#pragma unroll
        for (int m = 1; m < 64; m <<= 1) acc[n] += __shfl_xor(acc[n], m);
    __shared__ float sred[4][10];
    if (lane == 0)
#pragma unroll
        for (int n = 0; n < 10; ++n) sred[wv][n] = acc[n];
    __syncthreads();
    if (t < 10)
        out[b * 10 + t] = sred[0][t] + sred[1][t] + sred[2][t] + sred[3][t] + bias2[t];
}

extern "C" void kernel_launch(void* const* d_in, const int* in_sizes, int n_in,
                              void* d_out, int out_size, void* d_ws, size_t ws_size,
                              hipStream_t stream)
{
    const float* x    = (const float*)d_in[0];
    const float* w1   = (const float*)d_in[1];
    const float* g1   = (const float*)d_in[2];
    const float* b1   = (const float*)d_in[3];
    const float* w2_1 = (const float*)d_in[4];
    const float* g2_1 = (const float*)d_in[5];
    const float* b2_1 = (const float*)d_in[6];
    const float* w2_2 = (const float*)d_in[7];
    const float* g2_2 = (const float*)d_in[8];
    const float* b2_2 = (const float*)d_in[9];
    const float* w3_1 = (const float*)d_in[10];
    const float* g3_1 = (const float*)d_in[11];
    const float* b3_1 = (const float*)d_in[12];
    const float* w3_2 = (const float*)d_in[13];
    const float* g3_2 = (const float*)d_in[14];
    const float* b3_2 = (const float*)d_in[15];
    const float* fcw  = (const float*)d_in[16];
    const float* fcb  = (const float*)d_in[17];
    float* out = (float*)d_out;

    // workspace layout (bytes). pmax/pmin alias later c22/f3/q8 (write-after-
    // consume ordering per launch sequence).
    const size_t OFF_PMAX = 0;          // 33,554,432  (-> c22 later)
    const size_t OFF_PMIN = 33554432;   // 33,554,432  (-> f3, q8 later)
    const size_t OFF_F3   = 33554432;   // 16,777,216  conv3_2 int16 out
    const size_t OFF_Q    = 50331648;   //  8,388,608  convg int8 outs
    const size_t OFF_SPK2 = 67108864;   //  2,621,440  [512][64][20]
    const size_t OFF_NPK2 = 69730304;   //  2,621,440
    const size_t OFF_SPK3 = 72351744;   //  6,291,456  [512][256][12]
    const size_t OFF_NPK3 = 78643200;   //  6,291,456
    const size_t OFF_A    = 84934656;   //  2,097,152  packed acts (layer 3)
    const size_t OFF_WPK21= 87031808;   //  2,048
    const size_t OFF_WPK31= 87033856;   //  8,192
    const size_t OFF_WP22 = 87042048;   //  4,096
    const size_t OFF_WP32 = 87046144;   //  16,384
    const size_t OFF_PART = 87062528;   //  2,097,152
    const size_t OFF_ST   = 89159680;   //  20,480     5 x 256 float4
    const size_t OFF_SW1  = 89180160;   //  12,288     conv1 signed weights f32
    const size_t OFF_W2   = 89192448;   //  655,360    bn-folded fc weights
    const size_t OFF_B2   = 89847808;   //  1,024
    const size_t OFF_XPAD = 89848832;   //  7,526,400  padded input
    const size_t NEED     = OFF_XPAD + 7526400;
    if (ws_size < NEED) return;

    char* ws = (char*)d_ws;
    float* pmax = (float*)(ws + OFF_PMAX);
    float* pmin = (float*)(ws + OFF_PMIN);
    signed char* c22 = (signed char*)(ws + OFF_PMAX);  // after bnpick consumes pmax
    short* f3  = (short*)(ws + OFF_F3);                // after bnpick consumes pmin
    signed char* q8 = (signed char*)(ws + OFF_Q);      // after bnpick consumes pmin
    u32* spk2  = (u32*)(ws + OFF_SPK2);
    u32* npk2  = (u32*)(ws + OFF_NPK2);
    u32* spk3  = (u32*)(ws + OFF_SPK3);
    u32* npk3  = (u32*)(ws + OFF_NPK3);
    u32* actA  = (u32*)(ws + OFF_A);
    u32* wpk21 = (u32*)(ws + OFF_WPK21);
    u32* wpk31 = (u32*)(ws + OFF_WPK31);
    u32* wp22  = (u32*)(ws + OFF_WP22);
    u32* wp32  = (u32*)(ws + OFF_WP32);
    double* part = (double*)(ws + OFF_PART);
    float4* st1  = (float4*)(ws + OFF_ST);
    float4* st21 = st1 + 256;
    float4* st22 = st21 + 256;
    float4* st31 = st22 + 256;
    float4* st32 = st31 + 256;
    float* sw1f  = (float*)(ws + OFF_SW1);
    float* w2f   = (float*)(ws + OFF_W2);
    float* b2f   = (float*)(ws + OFF_B2);
    float* xpad  = (float*)(ws + OFF_XPAD);

    // ---- weight prep + input pad (one launch) ----
    k_wprep<<<7364, 256, 0, stream>>>(w1, sw1f, w2_1, wpk21, w3_1, wpk31,
                                      w2_2, wp22, w3_2, wp32, x, xpad);

    // ---- layer 1: one fused conv pass (global window, DPP pool/stats) ----
    k_conv1f<<<2048, 256, 0, stream>>>(xpad, sw1f, pmax, pmin, part);
    k_finalize2<<<64, 256, 0, stream>>>(part, 2048, 512 * 1024, g1, b1, st1);
    k_bnpick<<<32768, 256, 0, stream>>>(pmax, pmin, st1, spk2, npk2);    // packed 16x16

    // ---- layer 2 ----
    k_convg_bp<64, 16><<<1024, 256, 0, stream>>>(spk2, npk2, wpk21, q8, part);
    k_finalize2<<<64, 256, 0, stream>>>(part, 512, 512 * 256, g2_1, b2_1, st21);
    k_conv1x1_bp2<<<512, 256, 0, stream>>>(q8, st21, wp22, c22);         // pack fused
    k_stats_i8<<<dim3(256, 32), 256, 0, stream>>>(c22, part, 256, 256, 16);
    k_finalize2<<<256, 256, 0, stream>>>(part, 32, 512 * 256, g2_2, b2_2, st22);
    k_poolpack3<<<32768, 256, 0, stream>>>(c22, st22, spk3, npk3);       // packed 8x8

    // ---- layer 3 ----
    k_convg_bp<256, 8><<<2048, 256, 0, stream>>>(spk3, npk3, wpk31, q8, part);
    k_finalize2<<<256, 256, 0, stream>>>(part, 512, 512 * 64, g3_1, b3_1, st31);
    k_bnpackC256<<<512, 256, 0, stream>>>(q8, st31, actA);
    k_conv1x1_bp3<<<512, 256, 0, stream>>>(actA, wp32, f3);              // [512,256,8,8] i16
    k_stats_i16<<<dim3(256, 32), 256, 0, stream>>>(f3, part, 256, 64, 16);
    k_finalize2<<<256, 256, 0, stream>>>(part, 32, 512 * 64, g3_2, b3_2, st32);

    // ---- FC (bn3_2 folded into weights) ----
    k_fcprep<<<650, 256, 0, stream>>>(fcw, st32, fcb, w2f, b2f);
    k_fc2<<<512, 256, 0, stream>>>(f3, w2f, b2f, out);
}

// Round 10
// 320.701 us; speedup vs baseline: 1.1561x; 1.0645x over previous
//
#include <hip/hip_runtime.h>

typedef unsigned int u32;

// ---------------------------------------------------------------------------
// LiBNet forward, bit-packed ternary arithmetic + integer intermediates.
// dot over taps = popc(nzA & nzW) - 2*popc((sA ^ sW) & nzA & nzW)
// conv1: accumulator-major loop (64 per-oc acc in VGPRs, forced live by the
// accumulation chain); taps streamed from padded global, weights tap-major
// via scalar loads. DPP-quad pool/stats.
// ---------------------------------------------------------------------------

static __device__ __forceinline__ float fsign(float x) {
    return (x > 0.f) ? 1.f : ((x < 0.f) ? -1.f : 0.f);
}
static __device__ __forceinline__ u32 pack4(int a, int b, int c, int d) {
    return (a & 0xff) | ((b & 0xff) << 8) | ((c & 0xff) << 16) | ((u32)(d & 0xff) << 24);
}
// quad_perm DPP on float (VALU, no LDS pipe). 0xB1 = lane^1, 0x4E = lane^2.
template <int CTRL>
static __device__ __forceinline__ float dppf(float x) {
    int i = __builtin_amdgcn_mov_dpp(__float_as_int(x), CTRL, 0xF, 0xF, true);
    return __int_as_float(i);
}

// --- weight prep + input padding (one launch) ---
// conv1 weights stored TAP-MAJOR: swt[k*64 + oc] = sign(w1[oc*48 + k])
__global__ __launch_bounds__(256) void k_wprep(const float* __restrict__ w1, float* __restrict__ swt,
                                               const float* __restrict__ w2_1, u32* __restrict__ wpk21,
                                               const float* __restrict__ w3_1, u32* __restrict__ wpk31,
                                               const float* __restrict__ w2_2, u32* __restrict__ wp22,
                                               const float* __restrict__ w3_2, u32* __restrict__ wp32,
                                               const float* __restrict__ x, float* __restrict__ xpad)
{
    int blk = blockIdx.x, tid = threadIdx.x;
    if (blk >= 14) {                    // pad x -> xpad[512*3][35][35]
        int i = (blk - 14) * 256 + tid;
        if (i < 1881600) {
            int bic = i / 1225;
            int rem = i - bic * 1225;
            int r = rem / 35, c = rem - r * 35;
            float v = 0.f;
            if (r >= 1 && r <= 32 && c >= 1 && c <= 32)
                v = x[bic * 1024 + (r - 1) * 32 + (c - 1)];
            xpad[i] = v;
        }
        return;
    }
    if (blk < 12) {
        int i = blk * 256 + tid;
        if (i < 3072) {
            int k = i >> 6, oc = i & 63;
            swt[i] = fsign(w1[oc * 48 + k]);
        }
        return;
    }
    if (blk == 12) {
        if (tid < 64) {   // grouped 4x4 weights, C=64
            const float* p = w2_1 + tid * 32;
            for (int r = 0; r < 8; ++r) {
                u32 sn = 0, nz = 0;
                for (int kw = 0; kw < 4; ++kw) {
                    float v = p[r * 4 + kw];
                    sn |= (u32)(v > 0.f) << kw;
                    nz |= (u32)(v != 0.f) << kw;
                }
                wpk21[tid * 8 + r] = sn | (nz << 8);
            }
        }
        {                 // 1x1 weights 256x64
            const float* p = w2_2 + (size_t)tid * 64;
            for (int j = 0; j < 2; ++j) {
                u32 sv = 0, nv = 0;
                for (int k = 0; k < 32; ++k) {
                    float v = p[j * 32 + k];
                    sv |= (u32)(v > 0.f) << k;
                    nv |= (u32)(v != 0.f) << k;
                }
                wp22[tid * 4 + j] = sv;
                wp22[tid * 4 + 2 + j] = nv;
            }
        }
        return;
    }
    {                     // blk == 13
        {                 // grouped 4x4 weights, C=256
            const float* p = w3_1 + tid * 32;
            for (int r = 0; r < 8; ++r) {
                u32 sn = 0, nz = 0;
                for (int kw = 0; kw < 4; ++kw) {
                    float v = p[r * 4 + kw];
                    sn |= (u32)(v > 0.f) << kw;
                    nz |= (u32)(v != 0.f) << kw;
                }
                wpk31[tid * 8 + r] = sn | (nz << 8);
            }
        }
        {                 // 1x1 weights 256x256
            const float* p = w3_2 + (size_t)tid * 256;
            for (int j = 0; j < 8; ++j) {
                u32 sv = 0, nv = 0;
                for (int k = 0; k < 32; ++k) {
                    float v = p[j * 32 + k];
                    sv |= (u32)(v > 0.f) << k;
                    nv |= (u32)(v != 0.f) << k;
                }
                wp32[tid * 16 + j] = sv;
                wp32[tid * 16 + 8 + j] = nv;
            }
        }
    }
}

// --- conv1 fused: accumulator-major; DPP-quad pool + stats ---
// lane = (w<<1)|hb: quad of 4 lanes == one 2x2 pool window.
__global__ __launch_bounds__(256, 4) void k_conv1f(const float* __restrict__ xpad,
                                                   const float* __restrict__ swt,
                                                   float* __restrict__ pmax,
                                                   float* __restrict__ pmin,
                                                   double* __restrict__ part)
{
    __shared__ float sacc_s[64 * 65];   // [oc][64 s4-partials], pad 65
    __shared__ float sacc_q[64 * 65];
    int b = blockIdx.x >> 2, q = blockIdx.x & 3;
    int lane = threadIdx.x & 63, wv = threadIdx.x >> 6;
    int w = lane >> 1, hb = lane & 1;
    int h = q * 8 + wv * 2 + hb;
    int oh = q * 4 + wv;
    int ow = lane >> 2;
    const float* xb = xpad + (size_t)b * 3675 + h * 35 + w;
    float acc[64];
#pragma unroll
    for (int oc = 0; oc < 64; ++oc) acc[oc] = 0.f;
    const float* wr = swt;
#pragma unroll 1
    for (int r = 0; r < 12; ++r) {      // r = ic*4 + kh
        const float* xr = xb + (r >> 2) * 1225 + (r & 3) * 35;
        float x0 = xr[0], x1 = xr[1], x2 = xr[2], x3 = xr[3];
#pragma unroll
        for (int oc = 0; oc < 64; ++oc)
            acc[oc] += x0 * wr[oc] + x1 * wr[64 + oc]
                     + x2 * wr[128 + oc] + x3 * wr[192 + oc];
        wr += 256;
    }
    bool owner = ((lane & 3) == 0);
    float* pmaxb = pmax + (size_t)(b * 64) * 256 + oh * 16 + ow;
    float* pminb = pmin + (size_t)(b * 64) * 256 + oh * 16 + ow;
#pragma unroll
    for (int oc = 0; oc < 64; ++oc) {
        float v = acc[oc];
        float p  = dppf<0xB1>(v);                 // vertical neighbor (lane^1)
        float s2 = v + p;
        float sq2 = v * v + p * p;
        float mx = fmaxf(v, p), mn = fminf(v, p);
        float s4  = s2  + dppf<0x4E>(s2);         // horizontal (lane^2)
        float sq4 = sq2 + dppf<0x4E>(sq2);
        float mx2 = fmaxf(mx, dppf<0x4E>(mx));
        float mn2 = fminf(mn, dppf<0x4E>(mn));
        if (owner) {
            int idx = oc * 65 + wv * 16 + ow;
            sacc_s[idx] = s4;
            sacc_q[idx] = sq4;
            pmaxb[oc * 256] = mx2;
            pminb[oc * 256] = mn2;
        }
    }
    __syncthreads();
    if (threadIdx.x < 128) {
        int oc = threadIdx.x >> 1, half = threadIdx.x & 1;
        const float* sp = (half ? sacc_q : sacc_s) + oc * 65;
        double acc2 = 0.0;
        for (int j = 0; j < 64; ++j) acc2 += (double)sp[j];
        part[((size_t)oc * 2048 + blockIdx.x) * 2 + half] = acc2;
    }
}

// --- bn pick (max if scale>0 else min) + binarize + row-bitpack ---
__global__ __launch_bounds__(256) void k_bnpick(const float* __restrict__ pmax,
                                                const float* __restrict__ pmin,
                                                const float4* __restrict__ st,
                                                u32* __restrict__ spk,
                                                u32* __restrict__ npk)
{
    int bc = blockIdx.x;              // b*64 + c
    int c = bc & 63;
    int t = threadIdx.x;
    int lane = t & 63, wv = t >> 6;
    float4 s = st[c];
    float mx = pmax[(size_t)bc * 256 + t];
    float mn = pmin[(size_t)bc * 256 + t];
    float raw = (s.y > 0.f) ? mx : mn;
    float v = (raw - s.x) * s.y + s.z;
    unsigned long long bs = __ballot(v > 0.f);
    unsigned long long bn = __ballot(v != 0.f);
    int r = lane >> 4;                // row within wave (4 rows x 16 cols)
    int oh = wv * 4 + r;
    size_t base = (size_t)bc * 20;
    if ((lane & 15) == 0) {
        spk[base + 1 + oh] = (((u32)(bs >> (16 * r))) & 0xffffu) << 1;
        npk[base + 1 + oh] = (((u32)(bn >> (16 * r))) & 0xffffu) << 1;
    }
    if (t < 4) {                      // zero margin slots 0,17,18,19
        int zs = (t == 0) ? 0 : (16 + t);
        spk[base + zs] = 0; npk[base + zs] = 0;
    }
}

// --- int8 stats: exact int32 block sums -> double partials ---
__global__ __launch_bounds__(256) void k_stats_i8(const signed char* __restrict__ in,
                                                  double* __restrict__ part,
                                                  int C, int HW, int bPerChunk)
{
    int c = blockIdx.x, chunk = blockIdx.y, b0 = chunk * bPerChunk;
    int q4 = HW >> 2;
    int s = 0, sq = 0;
    for (int b = b0; b < b0 + bPerChunk; ++b) {
        const u32* p = (const u32*)(in + (size_t)(b * C + c) * HW);
        for (int i = threadIdx.x; i < q4; i += 256) {
            u32 v = p[i];
            int x0 = (int)(v << 24) >> 24, x1 = (int)(v << 16) >> 24;
            int x2 = (int)(v << 8) >> 24,  x3 = (int)v >> 24;
            s += x0 + x1 + x2 + x3;
            sq += x0 * x0 + x1 * x1 + x2 * x2 + x3 * x3;
        }
    }
    __shared__ int ss[256];
    __shared__ int sb[256];
    ss[threadIdx.x] = s; sb[threadIdx.x] = sq;
    __syncthreads();
    for (int st = 128; st > 0; st >>= 1) {
        if (threadIdx.x < st) {
            ss[threadIdx.x] += ss[threadIdx.x + st];
            sb[threadIdx.x] += sb[threadIdx.x + st];
        }
        __syncthreads();
    }
    if (threadIdx.x == 0) {
        int nch = gridDim.y;
        part[(size_t)(c * nch + chunk) * 2]     = (double)ss[0];
        part[(size_t)(c * nch + chunk) * 2 + 1] = (double)sb[0];
    }
}

// --- int16 stats ---
__global__ __launch_bounds__(256) void k_stats_i16(const short* __restrict__ in,
                                                   double* __restrict__ part,
                                                   int C, int HW, int bPerChunk)
{
    int c = blockIdx.x, chunk = blockIdx.y, b0 = chunk * bPerChunk;
    int q2 = HW >> 1;
    int s = 0, sq = 0;
    for (int b = b0; b < b0 + bPerChunk; ++b) {
        const u32* p = (const u32*)(in + (size_t)(b * C + c) * HW);
        for (int i = threadIdx.x; i < q2; i += 256) {
            u32 v = p[i];
            int x0 = (int)(v << 16) >> 16, x1 = (int)v >> 16;
            s += x0 + x1;
            sq += x0 * x0 + x1 * x1;
        }
    }
    __shared__ int ss[256];
    __shared__ int sb[256];
    ss[threadIdx.x] = s; sb[threadIdx.x] = sq;
    __syncthreads();
    for (int st = 128; st > 0; st >>= 1) {
        if (threadIdx.x < st) {
            ss[threadIdx.x] += ss[threadIdx.x + st];
            sb[threadIdx.x] += sb[threadIdx.x + st];
        }
        __syncthreads();
    }
    if (threadIdx.x == 0) {
        int nch = gridDim.y;
        part[(size_t)(c * nch + chunk) * 2]     = (double)ss[0];
        part[(size_t)(c * nch + chunk) * 2 + 1] = (double)sb[0];
    }
}

// --- finalize: block per channel; mean/var -> power-of-two shift scale ---
__global__ __launch_bounds__(256) void k_finalize2(const double* __restrict__ part,
                                                   int nch, int N,
                                                   const float* __restrict__ gamma,
                                                   const float* __restrict__ beta,
                                                   float4* __restrict__ st)
{
    int c = blockIdx.x;
    double s = 0.0, sq = 0.0;
    for (int i = threadIdx.x; i < nch; i += 256) {
        s  += part[((size_t)c * nch + i) * 2];
        sq += part[((size_t)c * nch + i) * 2 + 1];
    }
    __shared__ double ss[256];
    __shared__ double sb[256];
    ss[threadIdx.x] = s; sb[threadIdx.x] = sq;
    __syncthreads();
    for (int stp = 128; stp > 0; stp >>= 1) {
        if (threadIdx.x < stp) {
            ss[threadIdx.x] += ss[threadIdx.x + stp];
            sb[threadIdx.x] += sb[threadIdx.x + stp];
        }
        __syncthreads();
    }
    if (threadIdx.x == 0) {
        double mean = ss[0] / (double)N;
        double var = sb[0] / (double)N - mean * mean;
        float inv = gamma[c] / sqrtf((float)var + 1e-5f);
        float sh = rintf(log2f(fabsf(inv) + 1e-12f));
        sh = fminf(fmaxf(sh, -4.f), 4.f);
        float scale = copysignf(exp2f(sh), inv);
        st[c] = make_float4((float)mean, scale, beta[c], 0.f);
    }
}

// --- layer2->3 bn+pool+pack: thread = (bc, oh), coalesced uint4 reads ---
__global__ __launch_bounds__(256) void k_poolpack3(const signed char* __restrict__ in,
                                                   const float4* __restrict__ st,
                                                   u32* __restrict__ spk,
                                                   u32* __restrict__ npk)
{
    int t = blockIdx.x * 256 + threadIdx.x;   // t = bc*8 + oh
    int oh = t & 7; int bc = t >> 3;
    int c = bc & 255;
    float4 s = st[c];
    const uint4* p = (const uint4*)(in + (size_t)bc * 256 + (size_t)(2 * oh) * 16);
    uint4 r0 = p[0], r1 = p[1];               // two input rows (16 int8 each)
    bool pos = (s.y > 0.f);
    u32 rows0[4] = {r0.x, r0.y, r0.z, r0.w};
    u32 rows1[4] = {r1.x, r1.y, r1.z, r1.w};
    u32 sb = 0, nb = 0;
#pragma unroll
    for (int j = 0; j < 4; ++j) {
        u32 a = rows0[j], bw = rows1[j];
#pragma unroll
        for (int k = 0; k < 2; ++k) {          // pool column within word
            int sh0 = 24 - 16 * k, sh1 = 16 - 16 * k;
            int a0 = (int)(a  << sh0) >> 24, a1 = (int)(a  << sh1) >> 24;
            int a2 = (int)(bw << sh0) >> 24, a3 = (int)(bw << sh1) >> 24;
            int raw = pos ? max(max(a0, a1), max(a2, a3))
                          : min(min(a0, a1), min(a2, a3));
            float v = ((float)raw - s.x) * s.y + s.z;
            int ow = j * 2 + k;
            sb |= (u32)(v > 0.f) << (ow + 1);
            nb |= (u32)(v != 0.f) << (ow + 1);
        }
    }
    size_t base = (size_t)bc * 12;
    spk[base + 1 + oh] = sb;
    npk[base + 1 + oh] = nb;
    if (oh < 4) {                              // zero margin slots 0,9,10,11
        int zs = (oh == 0) ? 0 : (8 + oh);
        spk[base + zs] = 0; npk[base + zs] = 0;
    }
}

// --- grouped 4x4 binary conv, bit-packed in, int8 out, FUSED bn stats. ---
template <int C, int H>
__global__ __launch_bounds__(256) void k_convg_bp(const u32* __restrict__ spk,
                                                  const u32* __restrict__ npk,
                                                  const u32* __restrict__ wpk,
                                                  signed char* __restrict__ out,
                                                  double* __restrict__ part)
{
    constexpr int SLOTS = (H == 16) ? 20 : 12;
    int t = blockIdx.x * 256 + threadIdx.x;
    int h = t % H; int r0 = t / H;
    int g = r0 % (C / 2); int b = r0 / (C / 2);
    int lane = threadIdx.x & 63;
    const u32* sp = spk + (size_t)(b * C + 2 * g) * SLOTS + h;
    const u32* np = npk + (size_t)(b * C + 2 * g) * SLOTS + h;
    u32 S[8], N[8];
#pragma unroll
    for (int jc = 0; jc < 2; ++jc)
#pragma unroll
        for (int jj = 0; jj < 4; ++jj) {    // slot h+jj = input row h-1+jj
            S[jc * 4 + jj] = sp[jc * SLOTS + jj];
            N[jc * 4 + jj] = np[jc * SLOTS + jj];
        }
    const u32* wq = wpk + (size_t)(2 * g) * 8;
    u32 Ws0[8], Wn0[8], Ws1[8], Wn1[8];
#pragma unroll
    for (int r = 0; r < 8; ++r) {
        u32 a = wq[r];      Ws0[r] = a & 15u;  Wn0[r] = (a >> 8) & 15u;
        u32 bb = wq[8 + r]; Ws1[r] = bb & 15u; Wn1[r] = (bb >> 8) & 15u;
    }
    int v0[H], v1[H];
    int s0 = 0, q0 = 0, s1 = 0, q1 = 0;
#pragma unroll
    for (int w = 0; w < H; ++w) {
        int snz0 = 0, smis0 = 0, snz1 = 0, smis1 = 0;
#pragma unroll
        for (int r = 0; r < 8; ++r) {
            u32 ss = (S[r] >> w) & 15u;
            u32 nn = (N[r] >> w) & 15u;
            u32 nz0 = nn & Wn0[r]; u32 m0 = (ss ^ Ws0[r]) & nz0;
            snz0 += __popc(nz0); smis0 += __popc(m0);
            u32 nz1 = nn & Wn1[r]; u32 m1 = (ss ^ Ws1[r]) & nz1;
            snz1 += __popc(nz1); smis1 += __popc(m1);
        }
        v0[w] = snz0 - 2 * smis0;
        v1[w] = snz1 - 2 * smis1;
        s0 += v0[w]; q0 += v0[w] * v0[w];
        s1 += v1[w]; q1 += v1[w] * v1[w];
    }
    // group-of-H lanes (aligned) hold one (b, g): butterfly int reduce
#pragma unroll
    for (int m = 1; m < H; m <<= 1) {
        s0 += __shfl_xor(s0, m); q0 += __shfl_xor(q0, m);
        s1 += __shfl_xor(s1, m); q1 += __shfl_xor(q1, m);
    }
    if ((lane & (H - 1)) == 0) {
        part[((size_t)(2 * g) * 512 + b) * 2]         = (double)s0;
        part[((size_t)(2 * g) * 512 + b) * 2 + 1]     = (double)q0;
        part[((size_t)(2 * g + 1) * 512 + b) * 2]     = (double)s1;
        part[((size_t)(2 * g + 1) * 512 + b) * 2 + 1] = (double)q1;
    }
    signed char* o0 = out + ((size_t)((b * C + 2 * g) * H + h)) * H;
    signed char* o1 = o0 + (size_t)H * H;
    u32 wb0[H / 4], wb1[H / 4];
#pragma unroll
    for (int j = 0; j < H / 4; ++j) {
        wb0[j] = pack4(v0[4*j], v0[4*j+1], v0[4*j+2], v0[4*j+3]);
        wb1[j] = pack4(v1[4*j], v1[4*j+1], v1[4*j+2], v1[4*j+3]);
    }
    if constexpr (H == 16) {
        *(uint4*)o0 = make_uint4(wb0[0], wb0[1], wb0[2], wb0[3]);
        *(uint4*)o1 = make_uint4(wb1[0], wb1[1], wb1[2], wb1[3]);
    } else {
        *(uint2*)o0 = make_uint2(wb0[0], wb0[1]);
        *(uint2*)o1 = make_uint2(wb1[0], wb1[1]);
    }
}

// --- 1x1 conv Cin=64->Cout=256, HW=256, int8 out, FUSED bn2_1 binarize+pack ---
__global__ __launch_bounds__(256) void k_conv1x1_bp2(const signed char* __restrict__ q8,
                                                     const float4* __restrict__ st,
                                                     const u32* __restrict__ wp,
                                                     signed char* __restrict__ out)
{
    int t = blockIdx.x * 256 + threadIdx.x;   // t = b*256 + hw
    int hw = t & 255; int b = t >> 8;
    const signed char* qp = q8 + (size_t)b * 64 * 256 + hw;
    u32 as0 = 0, as1 = 0, an0 = 0, an1 = 0;
#pragma unroll
    for (int k = 0; k < 32; ++k) {
        float4 s = st[k];                       // uniform -> s_load
        float v = ((float)qp[k * 256] - s.x) * s.y + s.z;   // coalesced byte load
        as0 |= (u32)(v > 0.f) << k;
        an0 |= (u32)(v != 0.f) << k;
    }
#pragma unroll
    for (int k = 0; k < 32; ++k) {
        float4 s = st[32 + k];
        float v = ((float)qp[(32 + k) * 256] - s.x) * s.y + s.z;
        as1 |= (u32)(v > 0.f) << k;
        an1 |= (u32)(v != 0.f) << k;
    }
    signed char* op = out + (size_t)b * 256 * 256 + hw;
#pragma unroll 8
    for (int oc = 0; oc < 256; ++oc) {
        uint4 wv = ((const uint4*)wp)[oc];      // wave-uniform -> scalar loads
        u32 nz0 = an0 & wv.z, nz1 = an1 & wv.w;
        u32 m0 = (as0 ^ wv.x) & nz0, m1 = (as1 ^ wv.y) & nz1;
        int dot = __popc(nz0) + __popc(nz1) - 2 * (__popc(m0) + __popc(m1));
        op[(size_t)oc << 8] = (signed char)dot;
    }
}

// --- bn + binarize + channel-pack, C=256 HW=64, LDS-staged transpose ---
__global__ __launch_bounds__(256) void k_bnpackC256(const signed char* __restrict__ q8,
                                                    const float4* __restrict__ st,
                                                    u32* __restrict__ act)
{
    __shared__ u32 sq[4096];   // one image: 256ch x 64hw bytes
    int b = blockIdx.x;
    const u32* qb = (const u32*)(q8 + (size_t)b * 16384);
    for (int i = threadIdx.x; i < 4096; i += 256) sq[i] = qb[i];
    __syncthreads();
    const signed char* s8p = (const signed char*)sq;
    int hw = threadIdx.x & 63, qd = threadIdx.x >> 6;   // qd: 64-channel quarter
    u32 sv0 = 0, nv0 = 0, sv1 = 0, nv1 = 0;
#pragma unroll
    for (int k = 0; k < 32; ++k) {
        int c = qd * 64 + k;
        float4 s = st[c];
        float v = ((float)s8p[c * 64 + hw] - s.x) * s.y + s.z;
        sv0 |= (u32)(v > 0.f) << k;
        nv0 |= (u32)(v != 0.f) << k;
    }
#pragma unroll
    for (int k = 0; k < 32; ++k) {
        int c = qd * 64 + 32 + k;
        float4 s = st[c];
        float v = ((float)s8p[c * 64 + hw] - s.x) * s.y + s.z;
        sv1 |= (u32)(v > 0.f) << k;
        nv1 |= (u32)(v != 0.f) << k;
    }
    u32* ap = act + ((size_t)b * 64 + hw) * 16;
    ap[qd * 2]     = sv0;
    ap[qd * 2 + 1] = sv1;
    ap[8 + qd * 2]     = nv0;
    ap[8 + qd * 2 + 1] = nv1;
}

// --- 1x1 conv, Cin=256, Cout=256 (4 chunks), HW=64, int16 out. ---
__global__ __launch_bounds__(256) void k_conv1x1_bp3(const u32* __restrict__ act,
                                                     const u32* __restrict__ wp,
                                                     short* __restrict__ out)
{
    int t = blockIdx.x * 256 + threadIdx.x;
    int hw = t & 63; int ch = (t >> 6) & 3; int b = t >> 8;
    const u32* ap = act + (size_t)(b * 64 + hw) * 16;
    u32 as[8], an[8];
#pragma unroll
    for (int j = 0; j < 8; ++j) { as[j] = ap[j]; an[j] = ap[8 + j]; }
    short* op = out + (size_t)b * 256 * 64 + hw;
#pragma unroll 4
    for (int oc = ch * 64; oc < ch * 64 + 64; ++oc) {
        const u32* wq = wp + oc * 16;
        int snz = 0, smis = 0;
#pragma unroll
        for (int j = 0; j < 8; ++j) {
            u32 nz = an[j] & wq[8 + j];
            u32 m = (as[j] ^ wq[j]) & nz;
            snz += __popc(nz); smis += __popc(m);
        }
        op[(size_t)oc * 64] = (short)(snz - 2 * smis);
    }
}

// --- FC prep (merged): fold bn3_2 into fc weights / bias ---
__global__ __launch_bounds__(256) void k_fcprep(const float* __restrict__ fcw,
                                                const float4* __restrict__ st,
                                                const float* __restrict__ fcb,
                                                float* __restrict__ w2,
                                                float* __restrict__ bias2)
{
    if (blockIdx.x < 640) {
        int idx = blockIdx.x * 256 + threadIdx.x;   // < 163840
        int k = idx & 16383;
        w2[idx] = fcw[idx] * st[k >> 6].y;
        return;
    }
    int n = blockIdx.x - 640;
    const float* p = fcw + (size_t)n * 16384;
    float acc = 0.f;
    for (int k = threadIdx.x; k < 16384; k += 256) {
        float4 s = st[k >> 6];
        acc += p[k] * (s.z - s.x * s.y);
    }
    __shared__ float ss[256];
    ss[threadIdx.x] = acc;
    __syncthreads();
    for (int stp = 128; stp > 0; stp >>= 1) {
        if (threadIdx.x < stp) ss[threadIdx.x] += ss[threadIdx.x + stp];
        __syncthreads();
    }
    if (threadIdx.x == 0) bias2[n] = ss[0] + fcb[n];
}

// --- FC: block per image, int16 features read once, 10 accumulators ---
__global__ __launch_bounds__(256) void k_fc2(const short* __restrict__ f,
                                             const float* __restrict__ w2,
                                             const float* __restrict__ bias2,
                                             float* __restrict__ out)
{
    int b = blockIdx.x, t = threadIdx.x;
    int lane = t & 63, wv = t >> 6;
    const u32* fp = (const u32*)(f + (size_t)b * 16384);
    float acc[10];
#pragma unroll
    for (int n = 0; n < 10; ++n) acc[n] = 0.f;
    for (int i = 0; i < 32; ++i) {
        int j = i * 256 + t;                 // u32 index; features 2j, 2j+1
        u32 v = fp[j];
        float f0 = (float)((int)(v << 16) >> 16);
        float f1 = (float)((int)v >> 16);
#pragma unroll
        for (int n = 0; n < 10; ++n) {
            float2 wv2 = *(const float2*)(w2 + (size_t)n * 16384 + 2 * j);
            acc[n] += f0 * wv2.x + f1 * wv2.y;
        }
    }
#pragma unroll
    for (int n = 0; n < 10; ++n)
#pragma unroll
        for (int m = 1; m < 64; m <<= 1) acc[n] += __shfl_xor(acc[n], m);
    __shared__ float sred[4][10];
    if (lane == 0)
#pragma unroll
        for (int n = 0; n < 10; ++n) sred[wv][n] = acc[n];
    __syncthreads();
    if (t < 10)
        out[b * 10 + t] = sred[0][t] + sred[1][t] + sred[2][t] + sred[3][t] + bias2[t];
}

extern "C" void kernel_launch(void* const* d_in, const int* in_sizes, int n_in,
                              void* d_out, int out_size, void* d_ws, size_t ws_size,
                              hipStream_t stream)
{
    const float* x    = (const float*)d_in[0];
    const float* w1   = (const float*)d_in[1];
    const float* g1   = (const float*)d_in[2];
    const float* b1   = (const float*)d_in[3];
    const float* w2_1 = (const float*)d_in[4];
    const float* g2_1 = (const float*)d_in[5];
    const float* b2_1 = (const float*)d_in[6];
    const float* w2_2 = (const float*)d_in[7];
    const float* g2_2 = (const float*)d_in[8];
    const float* b2_2 = (const float*)d_in[9];
    const float* w3_1 = (const float*)d_in[10];
    const float* g3_1 = (const float*)d_in[11];
    const float* b3_1 = (const float*)d_in[12];
    const float* w3_2 = (const float*)d_in[13];
    const float* g3_2 = (const float*)d_in[14];
    const float* b3_2 = (const float*)d_in[15];
    const float* fcw  = (const float*)d_in[16];
    const float* fcb  = (const float*)d_in[17];
    float* out = (float*)d_out;

    // workspace layout (bytes). pmax/pmin alias later c22/f3/q8 (write-after-
    // consume ordering per launch sequence).
    const size_t OFF_PMAX = 0;          // 33,554,432  (-> c22 later)
    const size_t OFF_PMIN = 33554432;   // 33,554,432  (-> f3, q8 later)
    const size_t OFF_F3   = 33554432;   // 16,777,216  conv3_2 int16 out
    const size_t OFF_Q    = 50331648;   //  8,388,608  convg int8 outs
    const size_t OFF_SPK2 = 67108864;   //  2,621,440  [512][64][20]
    const size_t OFF_NPK2 = 69730304;   //  2,621,440
    const size_t OFF_SPK3 = 72351744;   //  6,291,456  [512][256][12]
    const size_t OFF_NPK3 = 78643200;   //  6,291,456
    const size_t OFF_A    = 84934656;   //  2,097,152  packed acts (layer 3)
    const size_t OFF_WPK21= 87031808;   //  2,048
    const size_t OFF_WPK31= 87033856;   //  8,192
    const size_t OFF_WP22 = 87042048;   //  4,096
    const size_t OFF_WP32 = 87046144;   //  16,384
    const size_t OFF_PART = 87062528;   //  2,097,152
    const size_t OFF_ST   = 89159680;   //  20,480     5 x 256 float4
    const size_t OFF_SWT  = 89180160;   //  12,288     conv1 signed weights, tap-major f32
    const size_t OFF_W2   = 89192448;   //  655,360    bn-folded fc weights
    const size_t OFF_B2   = 89847808;   //  1,024
    const size_t OFF_XPAD = 89848832;   //  7,526,400  padded input
    const size_t NEED     = OFF_XPAD + 7526400;
    if (ws_size < NEED) return;

    char* ws = (char*)d_ws;
    float* pmax = (float*)(ws + OFF_PMAX);
    float* pmin = (float*)(ws + OFF_PMIN);
    signed char* c22 = (signed char*)(ws + OFF_PMAX);  // after bnpick consumes pmax
    short* f3  = (short*)(ws + OFF_F3);                // after bnpick consumes pmin
    signed char* q8 = (signed char*)(ws + OFF_Q);      // after bnpick consumes pmin
    u32* spk2  = (u32*)(ws + OFF_SPK2);
    u32* npk2  = (u32*)(ws + OFF_NPK2);
    u32* spk3  = (u32*)(ws + OFF_SPK3);
    u32* npk3  = (u32*)(ws + OFF_NPK3);
    u32* actA  = (u32*)(ws + OFF_A);
    u32* wpk21 = (u32*)(ws + OFF_WPK21);
    u32* wpk31 = (u32*)(ws + OFF_WPK31);
    u32* wp22  = (u32*)(ws + OFF_WP22);
    u32* wp32  = (u32*)(ws + OFF_WP32);
    double* part = (double*)(ws + OFF_PART);
    float4* st1  = (float4*)(ws + OFF_ST);
    float4* st21 = st1 + 256;
    float4* st22 = st21 + 256;
    float4* st31 = st22 + 256;
    float4* st32 = st31 + 256;
    float* swt   = (float*)(ws + OFF_SWT);
    float* w2f   = (float*)(ws + OFF_W2);
    float* b2f   = (float*)(ws + OFF_B2);
    float* xpad  = (float*)(ws + OFF_XPAD);

    // ---- weight prep + input pad (one launch) ----
    k_wprep<<<7364, 256, 0, stream>>>(w1, swt, w2_1, wpk21, w3_1, wpk31,
                                      w2_2, wp22, w3_2, wp32, x, xpad);

    // ---- layer 1: one fused conv pass (accumulator-major, DPP pool/stats) ----
    k_conv1f<<<2048, 256, 0, stream>>>(xpad, swt, pmax, pmin, part);
    k_finalize2<<<64, 256, 0, stream>>>(part, 2048, 512 * 1024, g1, b1, st1);
    k_bnpick<<<32768, 256, 0, stream>>>(pmax, pmin, st1, spk2, npk2);    // packed 16x16

    // ---- layer 2 ----
    k_convg_bp<64, 16><<<1024, 256, 0, stream>>>(spk2, npk2, wpk21, q8, part);
    k_finalize2<<<64, 256, 0, stream>>>(part, 512, 512 * 256, g2_1, b2_1, st21);
    k_conv1x1_bp2<<<512, 256, 0, stream>>>(q8, st21, wp22, c22);         // pack fused
    k_stats_i8<<<dim3(256, 32), 256, 0, stream>>>(c22, part, 256, 256, 16);
    k_finalize2<<<256, 256, 0, stream>>>(part, 32, 512 * 256, g2_2, b2_2, st22);
    k_poolpack3<<<4096, 256, 0, stream>>>(c22, st22, spk3, npk3);        // packed 8x8

    // ---- layer 3 ----
    k_convg_bp<256, 8><<<2048, 256, 0, stream>>>(spk3, npk3, wpk31, q8, part);
    k_finalize2<<<256, 256, 0, stream>>>(part, 512, 512 * 64, g3_1, b3_1, st31);
    k_bnpackC256<<<512, 256, 0, stream>>>(q8, st31, actA);
    k_conv1x1_bp3<<<512, 256, 0, stream>>>(actA, wp32, f3);              // [512,256,8,8] i16
    k_stats_i16<<<dim3(256, 32), 256, 0, stream>>>(f3, part, 256, 64, 16);
    k_finalize2<<<256, 256, 0, stream>>>(part, 32, 512 * 64, g3_2, b3_2, st32);

    // ---- FC (bn3_2 folded into weights) ----
    k_fcprep<<<650, 256, 0, stream>>>(fcw, st32, fcb, w2f, b2f);
    k_fc2<<<512, 256, 0, stream>>>(f3, w2f, b2f, out);
}

// Round 11
// 301.345 us; speedup vs baseline: 1.2303x; 1.0642x over previous
//
#include <hip/hip_runtime.h>

typedef unsigned int u32;

// ---------------------------------------------------------------------------
// LiBNet forward, bit-packed ternary arithmetic + integer intermediates.
// dot over taps = popc(nzA & nzW) - 2*popc((sA ^ sW) & nzA & nzW)
// conv1: accumulator-major; pool pick by sign(gamma) (== sign(bn scale),
// exact since inv = gamma/sqrt(var+eps)); s16 DPP stat partials.
// ---------------------------------------------------------------------------

static __device__ __forceinline__ float fsign(float x) {
    return (x > 0.f) ? 1.f : ((x < 0.f) ? -1.f : 0.f);
}
static __device__ __forceinline__ u32 pack4(int a, int b, int c, int d) {
    return (a & 0xff) | ((b & 0xff) << 8) | ((c & 0xff) << 16) | ((u32)(d & 0xff) << 24);
}
// DPP on float (VALU pipe). 0xB1 = quad lane^1, 0x4E = quad lane^2,
// 0x124 = row_ror:4, 0x128 = row_ror:8 (16-lane row rotations).
template <int CTRL>
static __device__ __forceinline__ float dppf(float x) {
    int i = __builtin_amdgcn_mov_dpp(__float_as_int(x), CTRL, 0xF, 0xF, true);
    return __int_as_float(i);
}

// --- weight prep + input padding (one launch) ---
// conv1 weights stored TAP-MAJOR: swt[k*64 + oc] = sign(w1[oc*48 + k])
__global__ __launch_bounds__(256) void k_wprep(const float* __restrict__ w1, float* __restrict__ swt,
                                               const float* __restrict__ w2_1, u32* __restrict__ wpk21,
                                               const float* __restrict__ w3_1, u32* __restrict__ wpk31,
                                               const float* __restrict__ w2_2, u32* __restrict__ wp22,
                                               const float* __restrict__ w3_2, u32* __restrict__ wp32,
                                               const float* __restrict__ x, float* __restrict__ xpad)
{
    int blk = blockIdx.x, tid = threadIdx.x;
    if (blk >= 14) {                    // pad x -> xpad[512*3][35][35]
        int i = (blk - 14) * 256 + tid;
        if (i < 1881600) {
            int bic = i / 1225;
            int rem = i - bic * 1225;
            int r = rem / 35, c = rem - r * 35;
            float v = 0.f;
            if (r >= 1 && r <= 32 && c >= 1 && c <= 32)
                v = x[bic * 1024 + (r - 1) * 32 + (c - 1)];
            xpad[i] = v;
        }
        return;
    }
    if (blk < 12) {
        int i = blk * 256 + tid;
        if (i < 3072) {
            int k = i >> 6, oc = i & 63;
            swt[i] = fsign(w1[oc * 48 + k]);
        }
        return;
    }
    if (blk == 12) {
        if (tid < 64) {   // grouped 4x4 weights, C=64
            const float* p = w2_1 + tid * 32;
            for (int r = 0; r < 8; ++r) {
                u32 sn = 0, nz = 0;
                for (int kw = 0; kw < 4; ++kw) {
                    float v = p[r * 4 + kw];
                    sn |= (u32)(v > 0.f) << kw;
                    nz |= (u32)(v != 0.f) << kw;
                }
                wpk21[tid * 8 + r] = sn | (nz << 8);
            }
        }
        {                 // 1x1 weights 256x64
            const float* p = w2_2 + (size_t)tid * 64;
            for (int j = 0; j < 2; ++j) {
                u32 sv = 0, nv = 0;
                for (int k = 0; k < 32; ++k) {
                    float v = p[j * 32 + k];
                    sv |= (u32)(v > 0.f) << k;
                    nv |= (u32)(v != 0.f) << k;
                }
                wp22[tid * 4 + j] = sv;
                wp22[tid * 4 + 2 + j] = nv;
            }
        }
        return;
    }
    {                     // blk == 13
        {                 // grouped 4x4 weights, C=256
            const float* p = w3_1 + tid * 32;
            for (int r = 0; r < 8; ++r) {
                u32 sn = 0, nz = 0;
                for (int kw = 0; kw < 4; ++kw) {
                    float v = p[r * 4 + kw];
                    sn |= (u32)(v > 0.f) << kw;
                    nz |= (u32)(v != 0.f) << kw;
                }
                wpk31[tid * 8 + r] = sn | (nz << 8);
            }
        }
        {                 // 1x1 weights 256x256
            const float* p = w3_2 + (size_t)tid * 256;
            for (int j = 0; j < 8; ++j) {
                u32 sv = 0, nv = 0;
                for (int k = 0; k < 32; ++k) {
                    float v = p[j * 32 + k];
                    sv |= (u32)(v > 0.f) << k;
                    nv |= (u32)(v != 0.f) << k;
                }
                wp32[tid * 16 + j] = sv;
                wp32[tid * 16 + 8 + j] = nv;
            }
        }
    }
}

// --- conv1 fused: accumulator-major; gamma-sign pool pick; s16 DPP stats ---
// lane = (w<<1)|hb: quad of 4 lanes == one 2x2 pool window.
__global__ __launch_bounds__(256, 4) void k_conv1f(const float* __restrict__ xpad,
                                                   const float* __restrict__ swt,
                                                   const float* __restrict__ g1,
                                                   float* __restrict__ ppool,
                                                   double* __restrict__ part)
{
    __shared__ float sacc_s[64 * 17];   // [oc][16 s16-partials], pad 17
    __shared__ float sacc_q[64 * 17];
    int b = blockIdx.x >> 2, q = blockIdx.x & 3;
    int lane = threadIdx.x & 63, wv = threadIdx.x >> 6;
    int w = lane >> 1, hb = lane & 1;
    int h = q * 8 + wv * 2 + hb;
    int oh = q * 4 + wv;
    int ow = lane >> 2;
    const float* xb = xpad + (size_t)b * 3675 + h * 35 + w;
    float acc[64];
#pragma unroll
    for (int oc = 0; oc < 64; ++oc) acc[oc] = 0.f;
    const float* wr = swt;
#pragma unroll 1
    for (int r = 0; r < 12; ++r) {      // r = ic*4 + kh
        const float* xr = xb + (r >> 2) * 1225 + (r & 3) * 35;
        float x0 = xr[0], x1 = xr[1], x2 = xr[2], x3 = xr[3];
#pragma unroll
        for (int oc = 0; oc < 64; ++oc)
            acc[oc] += x0 * wr[oc] + x1 * wr[64 + oc]
                     + x2 * wr[128 + oc] + x3 * wr[192 + oc];
        wr += 256;
    }
    bool owner = ((lane & 3) == 0);
    bool owner16 = ((lane & 15) == 0);
    float* ppb = ppool + (size_t)(b * 64) * 256 + oh * 16 + ow;
#pragma unroll
    for (int oc = 0; oc < 64; ++oc) {
        float v = acc[oc];
        bool posi = (g1[oc] > 0.f);               // == sign(bn scale), uniform
        float p  = dppf<0xB1>(v);                 // vertical neighbor (lane^1)
        float s2 = v + p;
        float sq2 = v * v + p * p;
        float e1 = posi ? fmaxf(v, p) : fminf(v, p);
        float s4  = s2  + dppf<0x4E>(s2);         // horizontal (lane^2)
        float sq4 = sq2 + dppf<0x4E>(sq2);
        float e2r = dppf<0x4E>(e1);
        float pooled = posi ? fmaxf(e1, e2r) : fminf(e1, e2r);
        float s8  = s4  + dppf<0x124>(s4);        // row_ror:4
        float sq8 = sq4 + dppf<0x124>(sq4);
        float s16  = s8  + dppf<0x128>(s8);       // row_ror:8
        float sq16 = sq8 + dppf<0x128>(sq8);
        if (owner16) {
            int idx = oc * 17 + wv * 4 + (lane >> 4);
            sacc_s[idx] = s16;
            sacc_q[idx] = sq16;
        }
        if (owner)
            ppb[oc * 256] = pooled;
    }
    __syncthreads();
    if (threadIdx.x < 128) {
        int oc = threadIdx.x >> 1, half = threadIdx.x & 1;
        const float* sp = (half ? sacc_q : sacc_s) + oc * 17;
        double acc2 = 0.0;
        for (int j = 0; j < 16; ++j) acc2 += (double)sp[j];
        part[((size_t)oc * 2048 + blockIdx.x) * 2 + half] = acc2;
    }
}

// --- bn apply on pre-picked pooled value + binarize + row-bitpack ---
__global__ __launch_bounds__(256) void k_bnpick(const float* __restrict__ ppool,
                                                const float4* __restrict__ st,
                                                u32* __restrict__ spk,
                                                u32* __restrict__ npk)
{
    int bc = blockIdx.x;              // b*64 + c
    int c = bc & 63;
    int t = threadIdx.x;
    int lane = t & 63, wv = t >> 6;
    float4 s = st[c];
    float raw = ppool[(size_t)bc * 256 + t];
    float v = (raw - s.x) * s.y + s.z;
    unsigned long long bs = __ballot(v > 0.f);
    unsigned long long bn = __ballot(v != 0.f);
    int r = lane >> 4;                // row within wave (4 rows x 16 cols)
    int oh = wv * 4 + r;
    size_t base = (size_t)bc * 20;
    if ((lane & 15) == 0) {
        spk[base + 1 + oh] = (((u32)(bs >> (16 * r))) & 0xffffu) << 1;
        npk[base + 1 + oh] = (((u32)(bn >> (16 * r))) & 0xffffu) << 1;
    }
    if (t < 4) {                      // zero margin slots 0,17,18,19
        int zs = (t == 0) ? 0 : (16 + t);
        spk[base + zs] = 0; npk[base + zs] = 0;
    }
}

// --- int8 stats: exact int32 block sums -> double partials ---
__global__ __launch_bounds__(256) void k_stats_i8(const signed char* __restrict__ in,
                                                  double* __restrict__ part,
                                                  int C, int HW, int bPerChunk)
{
    int c = blockIdx.x, chunk = blockIdx.y, b0 = chunk * bPerChunk;
    int q4 = HW >> 2;
    int s = 0, sq = 0;
    for (int b = b0; b < b0 + bPerChunk; ++b) {
        const u32* p = (const u32*)(in + (size_t)(b * C + c) * HW);
        for (int i = threadIdx.x; i < q4; i += 256) {
            u32 v = p[i];
            int x0 = (int)(v << 24) >> 24, x1 = (int)(v << 16) >> 24;
            int x2 = (int)(v << 8) >> 24,  x3 = (int)v >> 24;
            s += x0 + x1 + x2 + x3;
            sq += x0 * x0 + x1 * x1 + x2 * x2 + x3 * x3;
        }
    }
    __shared__ int ss[256];
    __shared__ int sb[256];
    ss[threadIdx.x] = s; sb[threadIdx.x] = sq;
    __syncthreads();
    for (int st = 128; st > 0; st >>= 1) {
        if (threadIdx.x < st) {
            ss[threadIdx.x] += ss[threadIdx.x + st];
            sb[threadIdx.x] += sb[threadIdx.x + st];
        }
        __syncthreads();
    }
    if (threadIdx.x == 0) {
        int nch = gridDim.y;
        part[(size_t)(c * nch + chunk) * 2]     = (double)ss[0];
        part[(size_t)(c * nch + chunk) * 2 + 1] = (double)sb[0];
    }
}

// --- int16 stats ---
__global__ __launch_bounds__(256) void k_stats_i16(const short* __restrict__ in,
                                                   double* __restrict__ part,
                                                   int C, int HW, int bPerChunk)
{
    int c = blockIdx.x, chunk = blockIdx.y, b0 = chunk * bPerChunk;
    int q2 = HW >> 1;
    int s = 0, sq = 0;
    for (int b = b0; b < b0 + bPerChunk; ++b) {
        const u32* p = (const u32*)(in + (size_t)(b * C + c) * HW);
        for (int i = threadIdx.x; i < q2; i += 256) {
            u32 v = p[i];
            int x0 = (int)(v << 16) >> 16, x1 = (int)v >> 16;
            s += x0 + x1;
            sq += x0 * x0 + x1 * x1;
        }
    }
    __shared__ int ss[256];
    __shared__ int sb[256];
    ss[threadIdx.x] = s; sb[threadIdx.x] = sq;
    __syncthreads();
    for (int st = 128; st > 0; st >>= 1) {
        if (threadIdx.x < st) {
            ss[threadIdx.x] += ss[threadIdx.x + st];
            sb[threadIdx.x] += sb[threadIdx.x + st];
        }
        __syncthreads();
    }
    if (threadIdx.x == 0) {
        int nch = gridDim.y;
        part[(size_t)(c * nch + chunk) * 2]     = (double)ss[0];
        part[(size_t)(c * nch + chunk) * 2 + 1] = (double)sb[0];
    }
}

// --- finalize: block per channel; mean/var -> power-of-two shift scale ---
__global__ __launch_bounds__(256) void k_finalize2(const double* __restrict__ part,
                                                   int nch, int N,
                                                   const float* __restrict__ gamma,
                                                   const float* __restrict__ beta,
                                                   float4* __restrict__ st)
{
    int c = blockIdx.x;
    double s = 0.0, sq = 0.0;
    for (int i = threadIdx.x; i < nch; i += 256) {
        s  += part[((size_t)c * nch + i) * 2];
        sq += part[((size_t)c * nch + i) * 2 + 1];
    }
    __shared__ double ss[256];
    __shared__ double sb[256];
    ss[threadIdx.x] = s; sb[threadIdx.x] = sq;
    __syncthreads();
    for (int stp = 128; stp > 0; stp >>= 1) {
        if (threadIdx.x < stp) {
            ss[threadIdx.x] += ss[threadIdx.x + stp];
            sb[threadIdx.x] += sb[threadIdx.x + stp];
        }
        __syncthreads();
    }
    if (threadIdx.x == 0) {
        double mean = ss[0] / (double)N;
        double var = sb[0] / (double)N - mean * mean;
        float inv = gamma[c] / sqrtf((float)var + 1e-5f);
        float sh = rintf(log2f(fabsf(inv) + 1e-12f));
        sh = fminf(fmaxf(sh, -4.f), 4.f);
        float scale = copysignf(exp2f(sh), inv);
        st[c] = make_float4((float)mean, scale, beta[c], 0.f);
    }
}

// --- layer2->3 bn+pool+pack: thread = (bc, oh), coalesced uint4 reads ---
__global__ __launch_bounds__(256) void k_poolpack3(const signed char* __restrict__ in,
                                                   const float4* __restrict__ st,
                                                   u32* __restrict__ spk,
                                                   u32* __restrict__ npk)
{
    int t = blockIdx.x * 256 + threadIdx.x;   // t = bc*8 + oh
    int oh = t & 7; int bc = t >> 3;
    int c = bc & 255;
    float4 s = st[c];
    const uint4* p = (const uint4*)(in + (size_t)bc * 256 + (size_t)(2 * oh) * 16);
    uint4 r0 = p[0], r1 = p[1];               // two input rows (16 int8 each)
    bool pos = (s.y > 0.f);
    u32 rows0[4] = {r0.x, r0.y, r0.z, r0.w};
    u32 rows1[4] = {r1.x, r1.y, r1.z, r1.w};
    u32 sb = 0, nb = 0;
#pragma unroll
    for (int j = 0; j < 4; ++j) {
        u32 a = rows0[j], bw = rows1[j];
#pragma unroll
        for (int k = 0; k < 2; ++k) {          // pool column within word
            int sh0 = 24 - 16 * k, sh1 = 16 - 16 * k;
            int a0 = (int)(a  << sh0) >> 24, a1 = (int)(a  << sh1) >> 24;
            int a2 = (int)(bw << sh0) >> 24, a3 = (int)(bw << sh1) >> 24;
            int raw = pos ? max(max(a0, a1), max(a2, a3))
                          : min(min(a0, a1), min(a2, a3));
            float v = ((float)raw - s.x) * s.y + s.z;
            int ow = j * 2 + k;
            sb |= (u32)(v > 0.f) << (ow + 1);
            nb |= (u32)(v != 0.f) << (ow + 1);
        }
    }
    size_t base = (size_t)bc * 12;
    spk[base + 1 + oh] = sb;
    npk[base + 1 + oh] = nb;
    if (oh < 4) {                              // zero margin slots 0,9,10,11
        int zs = (oh == 0) ? 0 : (8 + oh);
        spk[base + zs] = 0; npk[base + zs] = 0;
    }
}

// --- grouped 4x4 binary conv, bit-packed in, int8 out, FUSED bn stats. ---
template <int C, int H>
__global__ __launch_bounds__(256) void k_convg_bp(const u32* __restrict__ spk,
                                                  const u32* __restrict__ npk,
                                                  const u32* __restrict__ wpk,
                                                  signed char* __restrict__ out,
                                                  double* __restrict__ part)
{
    constexpr int SLOTS = (H == 16) ? 20 : 12;
    int t = blockIdx.x * 256 + threadIdx.x;
    int h = t % H; int r0 = t / H;
    int g = r0 % (C / 2); int b = r0 / (C / 2);
    int lane = threadIdx.x & 63;
    const u32* sp = spk + (size_t)(b * C + 2 * g) * SLOTS + h;
    const u32* np = npk + (size_t)(b * C + 2 * g) * SLOTS + h;
    u32 S[8], N[8];
#pragma unroll
    for (int jc = 0; jc < 2; ++jc)
#pragma unroll
        for (int jj = 0; jj < 4; ++jj) {    // slot h+jj = input row h-1+jj
            S[jc * 4 + jj] = sp[jc * SLOTS + jj];
            N[jc * 4 + jj] = np[jc * SLOTS + jj];
        }
    const u32* wq = wpk + (size_t)(2 * g) * 8;
    u32 Ws0[8], Wn0[8], Ws1[8], Wn1[8];
#pragma unroll
    for (int r = 0; r < 8; ++r) {
        u32 a = wq[r];      Ws0[r] = a & 15u;  Wn0[r] = (a >> 8) & 15u;
        u32 bb = wq[8 + r]; Ws1[r] = bb & 15u; Wn1[r] = (bb >> 8) & 15u;
    }
    int v0[H], v1[H];
    int s0 = 0, q0 = 0, s1 = 0, q1 = 0;
#pragma unroll
    for (int w = 0; w < H; ++w) {
        int snz0 = 0, smis0 = 0, snz1 = 0, smis1 = 0;
#pragma unroll
        for (int r = 0; r < 8; ++r) {
            u32 ss = (S[r] >> w) & 15u;
            u32 nn = (N[r] >> w) & 15u;
            u32 nz0 = nn & Wn0[r]; u32 m0 = (ss ^ Ws0[r]) & nz0;
            snz0 += __popc(nz0); smis0 += __popc(m0);
            u32 nz1 = nn & Wn1[r]; u32 m1 = (ss ^ Ws1[r]) & nz1;
            snz1 += __popc(nz1); smis1 += __popc(m1);
        }
        v0[w] = snz0 - 2 * smis0;
        v1[w] = snz1 - 2 * smis1;
        s0 += v0[w]; q0 += v0[w] * v0[w];
        s1 += v1[w]; q1 += v1[w] * v1[w];
    }
    // group-of-H lanes (aligned) hold one (b, g): butterfly int reduce
#pragma unroll
    for (int m = 1; m < H; m <<= 1) {
        s0 += __shfl_xor(s0, m); q0 += __shfl_xor(q0, m);
        s1 += __shfl_xor(s1, m); q1 += __shfl_xor(q1, m);
    }
    if ((lane & (H - 1)) == 0) {
        part[((size_t)(2 * g) * 512 + b) * 2]         = (double)s0;
        part[((size_t)(2 * g) * 512 + b) * 2 + 1]     = (double)q0;
        part[((size_t)(2 * g + 1) * 512 + b) * 2]     = (double)s1;
        part[((size_t)(2 * g + 1) * 512 + b) * 2 + 1] = (double)q1;
    }
    signed char* o0 = out + ((size_t)((b * C + 2 * g) * H + h)) * H;
    signed char* o1 = o0 + (size_t)H * H;
    u32 wb0[H / 4], wb1[H / 4];
#pragma unroll
    for (int j = 0; j < H / 4; ++j) {
        wb0[j] = pack4(v0[4*j], v0[4*j+1], v0[4*j+2], v0[4*j+3]);
        wb1[j] = pack4(v1[4*j], v1[4*j+1], v1[4*j+2], v1[4*j+3]);
    }
    if constexpr (H == 16) {
        *(uint4*)o0 = make_uint4(wb0[0], wb0[1], wb0[2], wb0[3]);
        *(uint4*)o1 = make_uint4(wb1[0], wb1[1], wb1[2], wb1[3]);
    } else {
        *(uint2*)o0 = make_uint2(wb0[0], wb0[1]);
        *(uint2*)o1 = make_uint2(wb1[0], wb1[1]);
    }
}

// --- 1x1 conv Cin=64->Cout=256, HW=256, int8 out, FUSED bn2_1 binarize+pack ---
__global__ __launch_bounds__(256) void k_conv1x1_bp2(const signed char* __restrict__ q8,
                                                     const float4* __restrict__ st,
                                                     const u32* __restrict__ wp,
                                                     signed char* __restrict__ out)
{
    int t = blockIdx.x * 256 + threadIdx.x;   // t = b*256 + hw
    int hw = t & 255; int b = t >> 8;
    const signed char* qp = q8 + (size_t)b * 64 * 256 + hw;
    u32 as0 = 0, as1 = 0, an0 = 0, an1 = 0;
#pragma unroll
    for (int k = 0; k < 32; ++k) {
        float4 s = st[k];                       // uniform -> s_load
        float v = ((float)qp[k * 256] - s.x) * s.y + s.z;   // coalesced byte load
        as0 |= (u32)(v > 0.f) << k;
        an0 |= (u32)(v != 0.f) << k;
    }
#pragma unroll
    for (int k = 0; k < 32; ++k) {
        float4 s = st[32 + k];
        float v = ((float)qp[(32 + k) * 256] - s.x) * s.y + s.z;
        as1 |= (u32)(v > 0.f) << k;
        an1 |= (u32)(v != 0.f) << k;
    }
    signed char* op = out + (size_t)b * 256 * 256 + hw;
#pragma unroll 8
    for (int oc = 0; oc < 256; ++oc) {
        uint4 wv = ((const uint4*)wp)[oc];      // wave-uniform -> scalar loads
        u32 nz0 = an0 & wv.z, nz1 = an1 & wv.w;
        u32 m0 = (as0 ^ wv.x) & nz0, m1 = (as1 ^ wv.y) & nz1;
        int dot = __popc(nz0) + __popc(nz1) - 2 * (__popc(m0) + __popc(m1));
        op[(size_t)oc << 8] = (signed char)dot;
    }
}

// --- bn + binarize + channel-pack, C=256 HW=64, LDS-staged transpose ---
__global__ __launch_bounds__(256) void k_bnpackC256(const signed char* __restrict__ q8,
                                                    const float4* __restrict__ st,
                                                    u32* __restrict__ act)
{
    __shared__ u32 sq[4096];   // one image: 256ch x 64hw bytes
    int b = blockIdx.x;
    const u32* qb = (const u32*)(q8 + (size_t)b * 16384);
    for (int i = threadIdx.x; i < 4096; i += 256) sq[i] = qb[i];
    __syncthreads();
    const signed char* s8p = (const signed char*)sq;
    int hw = threadIdx.x & 63, qd = threadIdx.x >> 6;   // qd: 64-channel quarter
    u32 sv0 = 0, nv0 = 0, sv1 = 0, nv1 = 0;
#pragma unroll
    for (int k = 0; k < 32; ++k) {
        int c = qd * 64 + k;
        float4 s = st[c];
        float v = ((float)s8p[c * 64 + hw] - s.x) * s.y + s.z;
        sv0 |= (u32)(v > 0.f) << k;
        nv0 |= (u32)(v != 0.f) << k;
    }
#pragma unroll
    for (int k = 0; k < 32; ++k) {
        int c = qd * 64 + 32 + k;
        float4 s = st[c];
        float v = ((float)s8p[c * 64 + hw] - s.x) * s.y + s.z;
        sv1 |= (u32)(v > 0.f) << k;
        nv1 |= (u32)(v != 0.f) << k;
    }
    u32* ap = act + ((size_t)b * 64 + hw) * 16;
    ap[qd * 2]     = sv0;
    ap[qd * 2 + 1] = sv1;
    ap[8 + qd * 2]     = nv0;
    ap[8 + qd * 2 + 1] = nv1;
}

// --- 1x1 conv, Cin=256, Cout=256 (4 chunks), HW=64, int16 out. ---
__global__ __launch_bounds__(256) void k_conv1x1_bp3(const u32* __restrict__ act,
                                                     const u32* __restrict__ wp,
                                                     short* __restrict__ out)
{
    int t = blockIdx.x * 256 + threadIdx.x;
    int hw = t & 63; int ch = (t >> 6) & 3; int b = t >> 8;
    const u32* ap = act + (size_t)(b * 64 + hw) * 16;
    u32 as[8], an[8];
#pragma unroll
    for (int j = 0; j < 8; ++j) { as[j] = ap[j]; an[j] = ap[8 + j]; }
    short* op = out + (size_t)b * 256 * 64 + hw;
#pragma unroll 4
    for (int oc = ch * 64; oc < ch * 64 + 64; ++oc) {
        const u32* wq = wp + oc * 16;
        int snz = 0, smis = 0;
#pragma unroll
        for (int j = 0; j < 8; ++j) {
            u32 nz = an[j] & wq[8 + j];
            u32 m = (as[j] ^ wq[j]) & nz;
            snz += __popc(nz); smis += __popc(m);
        }
        op[(size_t)oc * 64] = (short)(snz - 2 * smis);
    }
}

// --- FC: block per image, bn3_2 applied inline, features read once ---
__global__ __launch_bounds__(256) void k_fc2(const short* __restrict__ f,
                                             const float4* __restrict__ st,
                                             const float* __restrict__ fcw,
                                             const float* __restrict__ fcb,
                                             float* __restrict__ out)
{
    int b = blockIdx.x, t = threadIdx.x;
    int lane = t & 63, wv = t >> 6;
    const u32* fp = (const u32*)(f + (size_t)b * 16384);
    float acc[10];
#pragma unroll
    for (int n = 0; n < 10; ++n) acc[n] = 0.f;
    for (int i = 0; i < 32; ++i) {
        int j = i * 256 + t;                 // u32 index; features 2j, 2j+1
        u32 v = fp[j];
        float4 s = st[j >> 5];               // channel = (2j)>>6 = j>>5
        float f0 = ((float)((int)(v << 16) >> 16) - s.x) * s.y + s.z;
        float f1 = ((float)((int)v >> 16) - s.x) * s.y + s.z;
#pragma unroll
        for (int n = 0; n < 10; ++n) {
            float2 wv2 = *(const float2*)(fcw + (size_t)n * 16384 + 2 * j);
            acc[n] += f0 * wv2.x + f1 * wv2.y;
        }
    }
#pragma unroll
    for (int n = 0; n < 10; ++n)
#pragma unroll
        for (int m = 1; m < 64; m <<= 1) acc[n] += __shfl_xor(acc[n], m);
    __shared__ float sred[4][10];
    if (lane == 0)
#pragma unroll
        for (int n = 0; n < 10; ++n) sred[wv][n] = acc[n];
    __syncthreads();
    if (t < 10)
        out[b * 10 + t] = sred[0][t] + sred[1][t] + sred[2][t] + sred[3][t] + fcb[t];
}

extern "C" void kernel_launch(void* const* d_in, const int* in_sizes, int n_in,
                              void* d_out, int out_size, void* d_ws, size_t ws_size,
                              hipStream_t stream)
{
    const float* x    = (const float*)d_in[0];
    const float* w1   = (const float*)d_in[1];
    const float* g1   = (const float*)d_in[2];
    const float* b1   = (const float*)d_in[3];
    const float* w2_1 = (const float*)d_in[4];
    const float* g2_1 = (const float*)d_in[5];
    const float* b2_1 = (const float*)d_in[6];
    const float* w2_2 = (const float*)d_in[7];
    const float* g2_2 = (const float*)d_in[8];
    const float* b2_2 = (const float*)d_in[9];
    const float* w3_1 = (const float*)d_in[10];
    const float* g3_1 = (const float*)d_in[11];
    const float* b3_1 = (const float*)d_in[12];
    const float* w3_2 = (const float*)d_in[13];
    const float* g3_2 = (const float*)d_in[14];
    const float* b3_2 = (const float*)d_in[15];
    const float* fcw  = (const float*)d_in[16];
    const float* fcb  = (const float*)d_in[17];
    float* out = (float*)d_out;

    // workspace layout (bytes). ppool aliases later c22 (write-after-consume
    // ordering per launch sequence).
    const size_t OFF_PPOOL= 0;          // 33,554,432  (-> c22 later)
    const size_t OFF_F3   = 33554432;   // 16,777,216  conv3_2 int16 out
    const size_t OFF_Q    = 50331648;   //  8,388,608  convg int8 outs
    const size_t OFF_SPK2 = 67108864;   //  2,621,440  [512][64][20]
    const size_t OFF_NPK2 = 69730304;   //  2,621,440
    const size_t OFF_SPK3 = 72351744;   //  6,291,456  [512][256][12]
    const size_t OFF_NPK3 = 78643200;   //  6,291,456
    const size_t OFF_A    = 84934656;   //  2,097,152  packed acts (layer 3)
    const size_t OFF_WPK21= 87031808;   //  2,048
    const size_t OFF_WPK31= 87033856;   //  8,192
    const size_t OFF_WP22 = 87042048;   //  4,096
    const size_t OFF_WP32 = 87046144;   //  16,384
    const size_t OFF_PART = 87062528;   //  2,097,152
    const size_t OFF_ST   = 89159680;   //  20,480     5 x 256 float4
    const size_t OFF_SWT  = 89180160;   //  12,288     conv1 signed weights, tap-major f32
    const size_t OFF_XPAD = 89192448;   //  7,526,400  padded input
    const size_t NEED     = OFF_XPAD + 7526400;
    if (ws_size < NEED) return;

    char* ws = (char*)d_ws;
    float* ppool = (float*)(ws + OFF_PPOOL);
    signed char* c22 = (signed char*)(ws + OFF_PPOOL); // after bnpick consumes ppool
    short* f3  = (short*)(ws + OFF_F3);
    signed char* q8 = (signed char*)(ws + OFF_Q);
    u32* spk2  = (u32*)(ws + OFF_SPK2);
    u32* npk2  = (u32*)(ws + OFF_NPK2);
    u32* spk3  = (u32*)(ws + OFF_SPK3);
    u32* npk3  = (u32*)(ws + OFF_NPK3);
    u32* actA  = (u32*)(ws + OFF_A);
    u32* wpk21 = (u32*)(ws + OFF_WPK21);
    u32* wpk31 = (u32*)(ws + OFF_WPK31);
    u32* wp22  = (u32*)(ws + OFF_WP22);
    u32* wp32  = (u32*)(ws + OFF_WP32);
    double* part = (double*)(ws + OFF_PART);
    float4* st1  = (float4*)(ws + OFF_ST);
    float4* st21 = st1 + 256;
    float4* st22 = st21 + 256;
    float4* st31 = st22 + 256;
    float4* st32 = st31 + 256;
    float* swt   = (float*)(ws + OFF_SWT);
    float* xpad  = (float*)(ws + OFF_XPAD);

    // ---- weight prep + input pad (one launch) ----
    k_wprep<<<7364, 256, 0, stream>>>(w1, swt, w2_1, wpk21, w3_1, wpk31,
                                      w2_2, wp22, w3_2, wp32, x, xpad);

    // ---- layer 1: one fused conv pass ----
    k_conv1f<<<2048, 256, 0, stream>>>(xpad, swt, g1, ppool, part);
    k_finalize2<<<64, 256, 0, stream>>>(part, 2048, 512 * 1024, g1, b1, st1);
    k_bnpick<<<32768, 256, 0, stream>>>(ppool, st1, spk2, npk2);         // packed 16x16

    // ---- layer 2 ----
    k_convg_bp<64, 16><<<1024, 256, 0, stream>>>(spk2, npk2, wpk21, q8, part);
    k_finalize2<<<64, 256, 0, stream>>>(part, 512, 512 * 256, g2_1, b2_1, st21);
    k_conv1x1_bp2<<<512, 256, 0, stream>>>(q8, st21, wp22, c22);         // pack fused
    k_stats_i8<<<dim3(256, 32), 256, 0, stream>>>(c22, part, 256, 256, 16);
    k_finalize2<<<256, 256, 0, stream>>>(part, 32, 512 * 256, g2_2, b2_2, st22);
    k_poolpack3<<<4096, 256, 0, stream>>>(c22, st22, spk3, npk3);        // packed 8x8

    // ---- layer 3 ----
    k_convg_bp<256, 8><<<2048, 256, 0, stream>>>(spk3, npk3, wpk31, q8, part);
    k_finalize2<<<256, 256, 0, stream>>>(part, 512, 512 * 64, g3_1, b3_1, st31);
    k_bnpackC256<<<512, 256, 0, stream>>>(q8, st31, actA);
    k_conv1x1_bp3<<<512, 256, 0, stream>>>(actA, wp32, f3);              // [512,256,8,8] i16
    k_stats_i16<<<dim3(256, 32), 256, 0, stream>>>(f3, part, 256, 64, 16);
    k_finalize2<<<256, 256, 0, stream>>>(part, 32, 512 * 64, g3_2, b3_2, st32);

    // ---- FC (bn3_2 inline) ----
    k_fc2<<<512, 256, 0, stream>>>(f3, st32, fcw, fcb, out);
}

// Round 12
// 294.908 us; speedup vs baseline: 1.2572x; 1.0218x over previous
//
#include <hip/hip_runtime.h>

typedef unsigned int u32;

// ---------------------------------------------------------------------------
// LiBNet forward, bit-packed ternary arithmetic + integer intermediates.
// dot over taps = popc(nzA & nzW) - 2*popc((sA ^ sW) & nzA & nzW)
// conv1: thread = 2x2 pooled window x 8 oc -> acc[4][8] fits registers,
// pooling in-thread (gamma-sign pick), s4 stats amortized over 4 positions.
// ---------------------------------------------------------------------------

static __device__ __forceinline__ float fsign(float x) {
    return (x > 0.f) ? 1.f : ((x < 0.f) ? -1.f : 0.f);
}
static __device__ __forceinline__ u32 pack4(int a, int b, int c, int d) {
    return (a & 0xff) | ((b & 0xff) << 8) | ((c & 0xff) << 16) | ((u32)(d & 0xff) << 24);
}
// DPP on float (VALU pipe). 0xB1 = quad lane^1, 0x4E = quad lane^2,
// 0x124 = row_ror:4, 0x128 = row_ror:8 (16-lane row rotations).
template <int CTRL>
static __device__ __forceinline__ float dppf(float x) {
    int i = __builtin_amdgcn_mov_dpp(__float_as_int(x), CTRL, 0xF, 0xF, true);
    return __int_as_float(i);
}

// --- weight prep + input padding (one launch) ---
// conv1 weights stored TAP-MAJOR: swt[k*64 + oc] = sign(w1[oc*48 + k])
__global__ __launch_bounds__(256) void k_wprep(const float* __restrict__ w1, float* __restrict__ swt,
                                               const float* __restrict__ w2_1, u32* __restrict__ wpk21,
                                               const float* __restrict__ w3_1, u32* __restrict__ wpk31,
                                               const float* __restrict__ w2_2, u32* __restrict__ wp22,
                                               const float* __restrict__ w3_2, u32* __restrict__ wp32,
                                               const float* __restrict__ x, float* __restrict__ xpad)
{
    int blk = blockIdx.x, tid = threadIdx.x;
    if (blk >= 14) {                    // pad x -> xpad[512*3][35][35]
        int i = (blk - 14) * 256 + tid;
        if (i < 1881600) {
            int bic = i / 1225;
            int rem = i - bic * 1225;
            int r = rem / 35, c = rem - r * 35;
            float v = 0.f;
            if (r >= 1 && r <= 32 && c >= 1 && c <= 32)
                v = x[bic * 1024 + (r - 1) * 32 + (c - 1)];
            xpad[i] = v;
        }
        return;
    }
    if (blk < 12) {
        int i = blk * 256 + tid;
        if (i < 3072) {
            int k = i >> 6, oc = i & 63;
            swt[i] = fsign(w1[oc * 48 + k]);
        }
        return;
    }
    if (blk == 12) {
        if (tid < 64) {   // grouped 4x4 weights, C=64
            const float* p = w2_1 + tid * 32;
            for (int r = 0; r < 8; ++r) {
                u32 sn = 0, nz = 0;
                for (int kw = 0; kw < 4; ++kw) {
                    float v = p[r * 4 + kw];
                    sn |= (u32)(v > 0.f) << kw;
                    nz |= (u32)(v != 0.f) << kw;
                }
                wpk21[tid * 8 + r] = sn | (nz << 8);
            }
        }
        {                 // 1x1 weights 256x64
            const float* p = w2_2 + (size_t)tid * 64;
            for (int j = 0; j < 2; ++j) {
                u32 sv = 0, nv = 0;
                for (int k = 0; k < 32; ++k) {
                    float v = p[j * 32 + k];
                    sv |= (u32)(v > 0.f) << k;
                    nv |= (u32)(v != 0.f) << k;
                }
                wp22[tid * 4 + j] = sv;
                wp22[tid * 4 + 2 + j] = nv;
            }
        }
        return;
    }
    {                     // blk == 13
        {                 // grouped 4x4 weights, C=256
            const float* p = w3_1 + tid * 32;
            for (int r = 0; r < 8; ++r) {
                u32 sn = 0, nz = 0;
                for (int kw = 0; kw < 4; ++kw) {
                    float v = p[r * 4 + kw];
                    sn |= (u32)(v > 0.f) << kw;
                    nz |= (u32)(v != 0.f) << kw;
                }
                wpk31[tid * 8 + r] = sn | (nz << 8);
            }
        }
        {                 // 1x1 weights 256x256
            const float* p = w3_2 + (size_t)tid * 256;
            for (int j = 0; j < 8; ++j) {
                u32 sv = 0, nv = 0;
                for (int k = 0; k < 32; ++k) {
                    float v = p[j * 32 + k];
                    sv |= (u32)(v > 0.f) << k;
                    nv |= (u32)(v != 0.f) << k;
                }
                wp32[tid * 16 + j] = sv;
                wp32[tid * 16 + 8 + j] = nv;
            }
        }
    }
}

// --- conv1 fused: block = (image, oc-group of 8); thread = 2x2 pool window ---
__global__ __launch_bounds__(256, 4) void k_conv1f(const float* __restrict__ xpad,
                                                   const float* __restrict__ swt,
                                                   const float* __restrict__ g1,
                                                   float* __restrict__ ppool,
                                                   double* __restrict__ part)
{
    __shared__ float sacc_s[8 * 17];    // [j][16 s16-partials], pad 17
    __shared__ float sacc_q[8 * 17];
    int b = blockIdx.x >> 3, ocg = blockIdx.x & 7;
    int t = threadIdx.x;
    int lane = t & 63, wv = t >> 6;
    int oh = t >> 4, ow = t & 15;       // pooled position
    const float* xb = xpad + (size_t)b * 3675 + (2 * oh) * 35 + 2 * ow;
    float acc0[8], acc1[8], acc2[8], acc3[8];   // [pos(r,c)][oc j]
#pragma unroll
    for (int j = 0; j < 8; ++j) { acc0[j] = 0.f; acc1[j] = 0.f; acc2[j] = 0.f; acc3[j] = 0.f; }
#pragma unroll 1
    for (int ic = 0; ic < 3; ++ic) {
        const float* xr = xb + ic * 1225;
        const float* wic = swt + ic * 1024 + ocg * 8;
#pragma unroll 1
        for (int rr = 0; rr < 5; ++rr) {
            float x0 = xr[0], x1 = xr[1], x2 = xr[2], x3 = xr[3], x4 = xr[4];
            if (rr <= 3) {              // contributes to out-row 2oh via kh=rr
                const float* wA = wic + rr * 256;
#pragma unroll
                for (int j = 0; j < 8; ++j) {
                    float w0 = wA[j], w1 = wA[64 + j], w2 = wA[128 + j], w3 = wA[192 + j];
                    acc0[j] += x0 * w0 + x1 * w1 + x2 * w2 + x3 * w3;
                    acc1[j] += x1 * w0 + x2 * w1 + x3 * w2 + x4 * w3;
                }
            }
            if (rr >= 1) {              // contributes to out-row 2oh+1 via kh=rr-1
                const float* wB = wic + (rr - 1) * 256;
#pragma unroll
                for (int j = 0; j < 8; ++j) {
                    float w0 = wB[j], w1 = wB[64 + j], w2 = wB[128 + j], w3 = wB[192 + j];
                    acc2[j] += x0 * w0 + x1 * w1 + x2 * w2 + x3 * w3;
                    acc3[j] += x1 * w0 + x2 * w1 + x3 * w2 + x4 * w3;
                }
            }
            xr += 35;
        }
    }
    bool owner16 = ((lane & 15) == 0);
    float* ppb = ppool + ((size_t)(b * 64 + ocg * 8)) * 256 + t;
#pragma unroll
    for (int j = 0; j < 8; ++j) {
        float a0 = acc0[j], a1 = acc1[j], a2 = acc2[j], a3 = acc3[j];
        bool posi = (g1[ocg * 8 + j] > 0.f);    // == sign(bn scale), uniform
        float pooled = posi ? fmaxf(fmaxf(a0, a1), fmaxf(a2, a3))
                            : fminf(fminf(a0, a1), fminf(a2, a3));
        float s = (a0 + a1) + (a2 + a3);
        float sq = a0 * a0 + a1 * a1 + a2 * a2 + a3 * a3;
        // 16-lane DPP reduce (positions share oh within each 16-lane group)
        s += dppf<0xB1>(s);   sq += dppf<0xB1>(sq);
        s += dppf<0x4E>(s);   sq += dppf<0x4E>(sq);
        s += dppf<0x124>(s);  sq += dppf<0x124>(sq);
        s += dppf<0x128>(s);  sq += dppf<0x128>(sq);
        if (owner16) {
            int idx = j * 17 + wv * 4 + (lane >> 4);
            sacc_s[idx] = s;
            sacc_q[idx] = sq;
        }
        ppb[j * 256] = pooled;
    }
    __syncthreads();
    if (t < 16) {
        int j = t >> 1, half = t & 1;
        const float* sp = (half ? sacc_q : sacc_s) + j * 17;
        double acc = 0.0;
        for (int i = 0; i < 16; ++i) acc += (double)sp[i];
        part[(((size_t)(ocg * 8 + j)) * 512 + b) * 2 + half] = acc;
    }
}

// --- bn apply on pre-picked pooled value + binarize + row-bitpack ---
// thread = (bc, oh): reads 16 floats (4x float4), builds the row's bits.
__global__ __launch_bounds__(256) void k_bnpick(const float* __restrict__ ppool,
                                                const float4* __restrict__ st,
                                                u32* __restrict__ spk,
                                                u32* __restrict__ npk)
{
    int t = blockIdx.x * 256 + threadIdx.x;   // t = bc*16 + oh
    int oh = t & 15; int bc = t >> 4;
    int c = bc & 63;
    float4 s = st[c];
    const float4* p = (const float4*)(ppool + (size_t)bc * 256 + oh * 16);
    u32 sb = 0, nb = 0;
#pragma unroll
    for (int j = 0; j < 4; ++j) {
        float4 v4 = p[j];
        float vs[4] = {v4.x, v4.y, v4.z, v4.w};
#pragma unroll
        for (int k = 0; k < 4; ++k) {
            float v = (vs[k] - s.x) * s.y + s.z;
            int ow = j * 4 + k;
            sb |= (u32)(v > 0.f) << (ow + 1);
            nb |= (u32)(v != 0.f) << (ow + 1);
        }
    }
    size_t base = (size_t)bc * 20;
    spk[base + 1 + oh] = sb;
    npk[base + 1 + oh] = nb;
    if (oh < 4) {                      // zero margin slots 0,17,18,19
        int zs = (oh == 0) ? 0 : (16 + oh);
        spk[base + zs] = 0; npk[base + zs] = 0;
    }
}

// --- int8 stats: exact int32 block sums -> double partials ---
__global__ __launch_bounds__(256) void k_stats_i8(const signed char* __restrict__ in,
                                                  double* __restrict__ part,
                                                  int C, int HW, int bPerChunk)
{
    int c = blockIdx.x, chunk = blockIdx.y, b0 = chunk * bPerChunk;
    int q4 = HW >> 2;
    int s = 0, sq = 0;
    for (int b = b0; b < b0 + bPerChunk; ++b) {
        const u32* p = (const u32*)(in + (size_t)(b * C + c) * HW);
        for (int i = threadIdx.x; i < q4; i += 256) {
            u32 v = p[i];
            int x0 = (int)(v << 24) >> 24, x1 = (int)(v << 16) >> 24;
            int x2 = (int)(v << 8) >> 24,  x3 = (int)v >> 24;
            s += x0 + x1 + x2 + x3;
            sq += x0 * x0 + x1 * x1 + x2 * x2 + x3 * x3;
        }
    }
    __shared__ int ss[256];
    __shared__ int sb[256];
    ss[threadIdx.x] = s; sb[threadIdx.x] = sq;
    __syncthreads();
    for (int st = 128; st > 0; st >>= 1) {
        if (threadIdx.x < st) {
            ss[threadIdx.x] += ss[threadIdx.x + st];
            sb[threadIdx.x] += sb[threadIdx.x + st];
        }
        __syncthreads();
    }
    if (threadIdx.x == 0) {
        int nch = gridDim.y;
        part[(size_t)(c * nch + chunk) * 2]     = (double)ss[0];
        part[(size_t)(c * nch + chunk) * 2 + 1] = (double)sb[0];
    }
}

// --- int16 stats ---
__global__ __launch_bounds__(256) void k_stats_i16(const short* __restrict__ in,
                                                   double* __restrict__ part,
                                                   int C, int HW, int bPerChunk)
{
    int c = blockIdx.x, chunk = blockIdx.y, b0 = chunk * bPerChunk;
    int q2 = HW >> 1;
    int s = 0, sq = 0;
    for (int b = b0; b < b0 + bPerChunk; ++b) {
        const u32* p = (const u32*)(in + (size_t)(b * C + c) * HW);
        for (int i = threadIdx.x; i < q2; i += 256) {
            u32 v = p[i];
            int x0 = (int)(v << 16) >> 16, x1 = (int)v >> 16;
            s += x0 + x1;
            sq += x0 * x0 + x1 * x1;
        }
    }
    __shared__ int ss[256];
    __shared__ int sb[256];
    ss[threadIdx.x] = s; sb[threadIdx.x] = sq;
    __syncthreads();
    for (int st = 128; st > 0; st >>= 1) {
        if (threadIdx.x < st) {
            ss[threadIdx.x] += ss[threadIdx.x + st];
            sb[threadIdx.x] += sb[threadIdx.x + st];
        }
        __syncthreads();
    }
    if (threadIdx.x == 0) {
        int nch = gridDim.y;
        part[(size_t)(c * nch + chunk) * 2]     = (double)ss[0];
        part[(size_t)(c * nch + chunk) * 2 + 1] = (double)sb[0];
    }
}

// --- finalize: block per channel; mean/var -> power-of-two shift scale ---
__global__ __launch_bounds__(256) void k_finalize2(const double* __restrict__ part,
                                                   int nch, int N,
                                                   const float* __restrict__ gamma,
                                                   const float* __restrict__ beta,
                                                   float4* __restrict__ st)
{
    int c = blockIdx.x;
    double s = 0.0, sq = 0.0;
    for (int i = threadIdx.x; i < nch; i += 256) {
        s  += part[((size_t)c * nch + i) * 2];
        sq += part[((size_t)c * nch + i) * 2 + 1];
    }
    __shared__ double ss[256];
    __shared__ double sb[256];
    ss[threadIdx.x] = s; sb[threadIdx.x] = sq;
    __syncthreads();
    for (int stp = 128; stp > 0; stp >>= 1) {
        if (threadIdx.x < stp) {
            ss[threadIdx.x] += ss[threadIdx.x + stp];
            sb[threadIdx.x] += sb[threadIdx.x + stp];
        }
        __syncthreads();
    }
    if (threadIdx.x == 0) {
        double mean = ss[0] / (double)N;
        double var = sb[0] / (double)N - mean * mean;
        float inv = gamma[c] / sqrtf((float)var + 1e-5f);
        float sh = rintf(log2f(fabsf(inv) + 1e-12f));
        sh = fminf(fmaxf(sh, -4.f), 4.f);
        float scale = copysignf(exp2f(sh), inv);
        st[c] = make_float4((float)mean, scale, beta[c], 0.f);
    }
}

// --- layer2->3 bn+pool+pack: thread = (bc, oh), coalesced uint4 reads ---
__global__ __launch_bounds__(256) void k_poolpack3(const signed char* __restrict__ in,
                                                   const float4* __restrict__ st,
                                                   u32* __restrict__ spk,
                                                   u32* __restrict__ npk)
{
    int t = blockIdx.x * 256 + threadIdx.x;   // t = bc*8 + oh
    int oh = t & 7; int bc = t >> 3;
    int c = bc & 255;
    float4 s = st[c];
    const uint4* p = (const uint4*)(in + (size_t)bc * 256 + (size_t)(2 * oh) * 16);
    uint4 r0 = p[0], r1 = p[1];               // two input rows (16 int8 each)
    bool pos = (s.y > 0.f);
    u32 rows0[4] = {r0.x, r0.y, r0.z, r0.w};
    u32 rows1[4] = {r1.x, r1.y, r1.z, r1.w};
    u32 sb = 0, nb = 0;
#pragma unroll
    for (int j = 0; j < 4; ++j) {
        u32 a = rows0[j], bw = rows1[j];
#pragma unroll
        for (int k = 0; k < 2; ++k) {          // pool column within word
            int sh0 = 24 - 16 * k, sh1 = 16 - 16 * k;
            int a0 = (int)(a  << sh0) >> 24, a1 = (int)(a  << sh1) >> 24;
            int a2 = (int)(bw << sh0) >> 24, a3 = (int)(bw << sh1) >> 24;
            int raw = pos ? max(max(a0, a1), max(a2, a3))
                          : min(min(a0, a1), min(a2, a3));
            float v = ((float)raw - s.x) * s.y + s.z;
            int ow = j * 2 + k;
            sb |= (u32)(v > 0.f) << (ow + 1);
            nb |= (u32)(v != 0.f) << (ow + 1);
        }
    }
    size_t base = (size_t)bc * 12;
    spk[base + 1 + oh] = sb;
    npk[base + 1 + oh] = nb;
    if (oh < 4) {                              // zero margin slots 0,9,10,11
        int zs = (oh == 0) ? 0 : (8 + oh);
        spk[base + zs] = 0; npk[base + zs] = 0;
    }
}

// --- grouped 4x4 binary conv, bit-packed in, int8 out, FUSED bn stats. ---
template <int C, int H>
__global__ __launch_bounds__(256) void k_convg_bp(const u32* __restrict__ spk,
                                                  const u32* __restrict__ npk,
                                                  const u32* __restrict__ wpk,
                                                  signed char* __restrict__ out,
                                                  double* __restrict__ part)
{
    constexpr int SLOTS = (H == 16) ? 20 : 12;
    int t = blockIdx.x * 256 + threadIdx.x;
    int h = t % H; int r0 = t / H;
    int g = r0 % (C / 2); int b = r0 / (C / 2);
    int lane = threadIdx.x & 63;
    const u32* sp = spk + (size_t)(b * C + 2 * g) * SLOTS + h;
    const u32* np = npk + (size_t)(b * C + 2 * g) * SLOTS + h;
    u32 S[8], N[8];
#pragma unroll
    for (int jc = 0; jc < 2; ++jc)
#pragma unroll
        for (int jj = 0; jj < 4; ++jj) {    // slot h+jj = input row h-1+jj
            S[jc * 4 + jj] = sp[jc * SLOTS + jj];
            N[jc * 4 + jj] = np[jc * SLOTS + jj];
        }
    const u32* wq = wpk + (size_t)(2 * g) * 8;
    u32 Ws0[8], Wn0[8], Ws1[8], Wn1[8];
#pragma unroll
    for (int r = 0; r < 8; ++r) {
        u32 a = wq[r];      Ws0[r] = a & 15u;  Wn0[r] = (a >> 8) & 15u;
        u32 bb = wq[8 + r]; Ws1[r] = bb & 15u; Wn1[r] = (bb >> 8) & 15u;
    }
    int v0[H], v1[H];
    int s0 = 0, q0 = 0, s1 = 0, q1 = 0;
#pragma unroll
    for (int w = 0; w < H; ++w) {
        int snz0 = 0, smis0 = 0, snz1 = 0, smis1 = 0;
#pragma unroll
        for (int r = 0; r < 8; ++r) {
            u32 ss = (S[r] >> w) & 15u;
            u32 nn = (N[r] >> w) & 15u;
            u32 nz0 = nn & Wn0[r]; u32 m0 = (ss ^ Ws0[r]) & nz0;
            snz0 += __popc(nz0); smis0 += __popc(m0);
            u32 nz1 = nn & Wn1[r]; u32 m1 = (ss ^ Ws1[r]) & nz1;
            snz1 += __popc(nz1); smis1 += __popc(m1);
        }
        v0[w] = snz0 - 2 * smis0;
        v1[w] = snz1 - 2 * smis1;
        s0 += v0[w]; q0 += v0[w] * v0[w];
        s1 += v1[w]; q1 += v1[w] * v1[w];
    }
    // group-of-H lanes (aligned) hold one (b, g): butterfly int reduce
#pragma unroll
    for (int m = 1; m < H; m <<= 1) {
        s0 += __shfl_xor(s0, m); q0 += __shfl_xor(q0, m);
        s1 += __shfl_xor(s1, m); q1 += __shfl_xor(q1, m);
    }
    if ((lane & (H - 1)) == 0) {
        part[((size_t)(2 * g) * 512 + b) * 2]         = (double)s0;
        part[((size_t)(2 * g) * 512 + b) * 2 + 1]     = (double)q0;
        part[((size_t)(2 * g + 1) * 512 + b) * 2]     = (double)s1;
        part[((size_t)(2 * g + 1) * 512 + b) * 2 + 1] = (double)q1;
    }
    signed char* o0 = out + ((size_t)((b * C + 2 * g) * H + h)) * H;
    signed char* o1 = o0 + (size_t)H * H;
    u32 wb0[H / 4], wb1[H / 4];
#pragma unroll
    for (int j = 0; j < H / 4; ++j) {
        wb0[j] = pack4(v0[4*j], v0[4*j+1], v0[4*j+2], v0[4*j+3]);
        wb1[j] = pack4(v1[4*j], v1[4*j+1], v1[4*j+2], v1[4*j+3]);
    }
    if constexpr (H == 16) {
        *(uint4*)o0 = make_uint4(wb0[0], wb0[1], wb0[2], wb0[3]);
        *(uint4*)o1 = make_uint4(wb1[0], wb1[1], wb1[2], wb1[3]);
    } else {
        *(uint2*)o0 = make_uint2(wb0[0], wb0[1]);
        *(uint2*)o1 = make_uint2(wb1[0], wb1[1]);
    }
}

// --- 1x1 conv Cin=64->Cout=256, HW=256, int8 out, FUSED bn2_1 binarize+pack ---
__global__ __launch_bounds__(256) void k_conv1x1_bp2(const signed char* __restrict__ q8,
                                                     const float4* __restrict__ st,
                                                     const u32* __restrict__ wp,
                                                     signed char* __restrict__ out)
{
    int t = blockIdx.x * 256 + threadIdx.x;   // t = b*256 + hw
    int hw = t & 255; int b = t >> 8;
    const signed char* qp = q8 + (size_t)b * 64 * 256 + hw;
    u32 as0 = 0, as1 = 0, an0 = 0, an1 = 0;
#pragma unroll
    for (int k = 0; k < 32; ++k) {
        float4 s = st[k];                       // uniform -> s_load
        float v = ((float)qp[k * 256] - s.x) * s.y + s.z;   // coalesced byte load
        as0 |= (u32)(v > 0.f) << k;
        an0 |= (u32)(v != 0.f) << k;
    }
#pragma unroll
    for (int k = 0; k < 32; ++k) {
        float4 s = st[32 + k];
        float v = ((float)qp[(32 + k) * 256] - s.x) * s.y + s.z;
        as1 |= (u32)(v > 0.f) << k;
        an1 |= (u32)(v != 0.f) << k;
    }
    signed char* op = out + (size_t)b * 256 * 256 + hw;
#pragma unroll 8
    for (int oc = 0; oc < 256; ++oc) {
        uint4 wv = ((const uint4*)wp)[oc];      // wave-uniform -> scalar loads
        u32 nz0 = an0 & wv.z, nz1 = an1 & wv.w;
        u32 m0 = (as0 ^ wv.x) & nz0, m1 = (as1 ^ wv.y) & nz1;
        int dot = __popc(nz0) + __popc(nz1) - 2 * (__popc(m0) + __popc(m1));
        op[(size_t)oc << 8] = (signed char)dot;
    }
}

// --- bn + binarize + channel-pack, C=256 HW=64, LDS-staged transpose ---
__global__ __launch_bounds__(256) void k_bnpackC256(const signed char* __restrict__ q8,
                                                    const float4* __restrict__ st,
                                                    u32* __restrict__ act)
{
    __shared__ u32 sq[4096];   // one image: 256ch x 64hw bytes
    int b = blockIdx.x;
    const u32* qb = (const u32*)(q8 + (size_t)b * 16384);
    for (int i = threadIdx.x; i < 4096; i += 256) sq[i] = qb[i];
    __syncthreads();
    const signed char* s8p = (const signed char*)sq;
    int hw = threadIdx.x & 63, qd = threadIdx.x >> 6;   // qd: 64-channel quarter
    u32 sv0 = 0, nv0 = 0, sv1 = 0, nv1 = 0;
#pragma unroll
    for (int k = 0; k < 32; ++k) {
        int c = qd * 64 + k;
        float4 s = st[c];
        float v = ((float)s8p[c * 64 + hw] - s.x) * s.y + s.z;
        sv0 |= (u32)(v > 0.f) << k;
        nv0 |= (u32)(v != 0.f) << k;
    }
#pragma unroll
    for (int k = 0; k < 32; ++k) {
        int c = qd * 64 + 32 + k;
        float4 s = st[c];
        float v = ((float)s8p[c * 64 + hw] - s.x) * s.y + s.z;
        sv1 |= (u32)(v > 0.f) << k;
        nv1 |= (u32)(v != 0.f) << k;
    }
    u32* ap = act + ((size_t)b * 64 + hw) * 16;
    ap[qd * 2]     = sv0;
    ap[qd * 2 + 1] = sv1;
    ap[8 + qd * 2]     = nv0;
    ap[8 + qd * 2 + 1] = nv1;
}

// --- 1x1 conv, Cin=256, Cout=256 (4 chunks), HW=64, int16 out. ---
__global__ __launch_bounds__(256) void k_conv1x1_bp3(const u32* __restrict__ act,
                                                     const u32* __restrict__ wp,
                                                     short* __restrict__ out)
{
    int t = blockIdx.x * 256 + threadIdx.x;
    int hw = t & 63; int ch = (t >> 6) & 3; int b = t >> 8;
    const u32* ap = act + (size_t)(b * 64 + hw) * 16;
    u32 as[8], an[8];
#pragma unroll
    for (int j = 0; j < 8; ++j) { as[j] = ap[j]; an[j] = ap[8 + j]; }
    short* op = out + (size_t)b * 256 * 64 + hw;
#pragma unroll 4
    for (int oc = ch * 64; oc < ch * 64 + 64; ++oc) {
        const u32* wq = wp + oc * 16;
        int snz = 0, smis = 0;
#pragma unroll
        for (int j = 0; j < 8; ++j) {
            u32 nz = an[j] & wq[8 + j];
            u32 m = (as[j] ^ wq[j]) & nz;
            snz += __popc(nz); smis += __popc(m);
        }
        op[(size_t)oc * 64] = (short)(snz - 2 * smis);
    }
}

// --- FC: block per image, bn3_2 applied inline, features read once ---
__global__ __launch_bounds__(256) void k_fc2(const short* __restrict__ f,
                                             const float4* __restrict__ st,
                                             const float* __restrict__ fcw,
                                             const float* __restrict__ fcb,
                                             float* __restrict__ out)
{
    int b = blockIdx.x, t = threadIdx.x;
    int lane = t & 63, wv = t >> 6;
    const u32* fp = (const u32*)(f + (size_t)b * 16384);
    float acc[10];
#pragma unroll
    for (int n = 0; n < 10; ++n) acc[n] = 0.f;
    for (int i = 0; i < 32; ++i) {
        int j = i * 256 + t;                 // u32 index; features 2j, 2j+1
        u32 v = fp[j];
        float4 s = st[j >> 5];               // channel = (2j)>>6 = j>>5
        float f0 = ((float)((int)(v << 16) >> 16) - s.x) * s.y + s.z;
        float f1 = ((float)((int)v >> 16) - s.x) * s.y + s.z;
#pragma unroll
        for (int n = 0; n < 10; ++n) {
            float2 wv2 = *(const float2*)(fcw + (size_t)n * 16384 + 2 * j);
            acc[n] += f0 * wv2.x + f1 * wv2.y;
        }
    }
#pragma unroll
    for (int n = 0; n < 10; ++n)
#pragma unroll
        for (int m = 1; m < 64; m <<= 1) acc[n] += __shfl_xor(acc[n], m);
    __shared__ float sred[4][10];
    if (lane == 0)
#pragma unroll
        for (int n = 0; n < 10; ++n) sred[wv][n] = acc[n];
    __syncthreads();
    if (t < 10)
        out[b * 10 + t] = sred[0][t] + sred[1][t] + sred[2][t] + sred[3][t] + fcb[t];
}

extern "C" void kernel_launch(void* const* d_in, const int* in_sizes, int n_in,
                              void* d_out, int out_size, void* d_ws, size_t ws_size,
                              hipStream_t stream)
{
    const float* x    = (const float*)d_in[0];
    const float* w1   = (const float*)d_in[1];
    const float* g1   = (const float*)d_in[2];
    const float* b1   = (const float*)d_in[3];
    const float* w2_1 = (const float*)d_in[4];
    const float* g2_1 = (const float*)d_in[5];
    const float* b2_1 = (const float*)d_in[6];
    const float* w2_2 = (const float*)d_in[7];
    const float* g2_2 = (const float*)d_in[8];
    const float* b2_2 = (const float*)d_in[9];
    const float* w3_1 = (const float*)d_in[10];
    const float* g3_1 = (const float*)d_in[11];
    const float* b3_1 = (const float*)d_in[12];
    const float* w3_2 = (const float*)d_in[13];
    const float* g3_2 = (const float*)d_in[14];
    const float* b3_2 = (const float*)d_in[15];
    const float* fcw  = (const float*)d_in[16];
    const float* fcb  = (const float*)d_in[17];
    float* out = (float*)d_out;

    // workspace layout (bytes). ppool aliases later c22 (write-after-consume
    // ordering per launch sequence).
    const size_t OFF_PPOOL= 0;          // 33,554,432  (-> c22 later)
    const size_t OFF_F3   = 33554432;   // 16,777,216  conv3_2 int16 out
    const size_t OFF_Q    = 50331648;   //  8,388,608  convg int8 outs
    const size_t OFF_SPK2 = 67108864;   //  2,621,440  [512][64][20]
    const size_t OFF_NPK2 = 69730304;   //  2,621,440
    const size_t OFF_SPK3 = 72351744;   //  6,291,456  [512][256][12]
    const size_t OFF_NPK3 = 78643200;   //  6,291,456
    const size_t OFF_A    = 84934656;   //  2,097,152  packed acts (layer 3)
    const size_t OFF_WPK21= 87031808;   //  2,048
    const size_t OFF_WPK31= 87033856;   //  8,192
    const size_t OFF_WP22 = 87042048;   //  4,096
    const size_t OFF_WP32 = 87046144;   //  16,384
    const size_t OFF_PART = 87062528;   //  2,097,152
    const size_t OFF_ST   = 89159680;   //  20,480     5 x 256 float4
    const size_t OFF_SWT  = 89180160;   //  12,288     conv1 signed weights, tap-major f32
    const size_t OFF_XPAD = 89192448;   //  7,526,400  padded input
    const size_t NEED     = OFF_XPAD + 7526400;
    if (ws_size < NEED) return;

    char* ws = (char*)d_ws;
    float* ppool = (float*)(ws + OFF_PPOOL);
    signed char* c22 = (signed char*)(ws + OFF_PPOOL); // after bnpick consumes ppool
    short* f3  = (short*)(ws + OFF_F3);
    signed char* q8 = (signed char*)(ws + OFF_Q);
    u32* spk2  = (u32*)(ws + OFF_SPK2);
    u32* npk2  = (u32*)(ws + OFF_NPK2);
    u32* spk3  = (u32*)(ws + OFF_SPK3);
    u32* npk3  = (u32*)(ws + OFF_NPK3);
    u32* actA  = (u32*)(ws + OFF_A);
    u32* wpk21 = (u32*)(ws + OFF_WPK21);
    u32* wpk31 = (u32*)(ws + OFF_WPK31);
    u32* wp22  = (u32*)(ws + OFF_WP22);
    u32* wp32  = (u32*)(ws + OFF_WP32);
    double* part = (double*)(ws + OFF_PART);
    float4* st1  = (float4*)(ws + OFF_ST);
    float4* st21 = st1 + 256;
    float4* st22 = st21 + 256;
    float4* st31 = st22 + 256;
    float4* st32 = st31 + 256;
    float* swt   = (float*)(ws + OFF_SWT);
    float* xpad  = (float*)(ws + OFF_XPAD);

    // ---- weight prep + input pad (one launch) ----
    k_wprep<<<7364, 256, 0, stream>>>(w1, swt, w2_1, wpk21, w3_1, wpk31,
                                      w2_2, wp22, w3_2, wp32, x, xpad);

    // ---- layer 1: one fused conv pass ----
    k_conv1f<<<4096, 256, 0, stream>>>(xpad, swt, g1, ppool, part);
    k_finalize2<<<64, 256, 0, stream>>>(part, 512, 512 * 1024, g1, b1, st1);
    k_bnpick<<<2048, 256, 0, stream>>>(ppool, st1, spk2, npk2);          // packed 16x16

    // ---- layer 2 ----
    k_convg_bp<64, 16><<<1024, 256, 0, stream>>>(spk2, npk2, wpk21, q8, part);
    k_finalize2<<<64, 256, 0, stream>>>(part, 512, 512 * 256, g2_1, b2_1, st21);
    k_conv1x1_bp2<<<512, 256, 0, stream>>>(q8, st21, wp22, c22);         // pack fused
    k_stats_i8<<<dim3(256, 32), 256, 0, stream>>>(c22, part, 256, 256, 16);
    k_finalize2<<<256, 256, 0, stream>>>(part, 32, 512 * 256, g2_2, b2_2, st22);
    k_poolpack3<<<4096, 256, 0, stream>>>(c22, st22, spk3, npk3);        // packed 8x8

    // ---- layer 3 ----
    k_convg_bp<256, 8><<<2048, 256, 0, stream>>>(spk3, npk3, wpk31, q8, part);
    k_finalize2<<<256, 256, 0, stream>>>(part, 512, 512 * 64, g3_1, b3_1, st31);
    k_bnpackC256<<<512, 256, 0, stream>>>(q8, st31, actA);
    k_conv1x1_bp3<<<512, 256, 0, stream>>>(actA, wp32, f3);              // [512,256,8,8] i16
    k_stats_i16<<<dim3(256, 32), 256, 0, stream>>>(f3, part, 256, 64, 16);
    k_finalize2<<<256, 256, 0, stream>>>(part, 32, 512 * 64, g3_2, b3_2, st32);

    // ---- FC (bn3_2 inline) ----
    k_fc2<<<512, 256, 0, stream>>>(f3, st32, fcw, fcb, out);
}

// Round 13
// 271.242 us; speedup vs baseline: 1.3669x; 1.0873x over previous
//
#include <hip/hip_runtime.h>

typedef unsigned int u32;

// ---------------------------------------------------------------------------
// LiBNet forward, bit-packed ternary arithmetic + integer intermediates.
// dot over taps = popc(nzA & nzW) - 2*popc((sA ^ sW) & nzA & nzW)
// conv1: thread = 2x2 pooled window x 8 oc, pure-fmaf accumulation chains.
// Pack->conv stages fused per image with LDS-resident packed rows.
// ---------------------------------------------------------------------------

static __device__ __forceinline__ float fsign(float x) {
    return (x > 0.f) ? 1.f : ((x < 0.f) ? -1.f : 0.f);
}
static __device__ __forceinline__ u32 pack4(int a, int b, int c, int d) {
    return (a & 0xff) | ((b & 0xff) << 8) | ((c & 0xff) << 16) | ((u32)(d & 0xff) << 24);
}
// DPP on float (VALU pipe). 0xB1 = quad lane^1, 0x4E = quad lane^2,
// 0x124 = row_ror:4, 0x128 = row_ror:8 (16-lane row rotations).
template <int CTRL>
static __device__ __forceinline__ float dppf(float x) {
    int i = __builtin_amdgcn_mov_dpp(__float_as_int(x), CTRL, 0xF, 0xF, true);
    return __int_as_float(i);
}

// --- weight prep + input padding (one launch) ---
// conv1 weights stored TAP-MAJOR: swt[k*64 + oc] = sign(w1[oc*48 + k])
__global__ __launch_bounds__(256) void k_wprep(const float* __restrict__ w1, float* __restrict__ swt,
                                               const float* __restrict__ w2_1, u32* __restrict__ wpk21,
                                               const float* __restrict__ w3_1, u32* __restrict__ wpk31,
                                               const float* __restrict__ w2_2, u32* __restrict__ wp22,
                                               const float* __restrict__ w3_2, u32* __restrict__ wp32,
                                               const float* __restrict__ x, float* __restrict__ xpad)
{
    int blk = blockIdx.x, tid = threadIdx.x;
    if (blk >= 14) {                    // pad x -> xpad[512*3][35][35]
        int i = (blk - 14) * 256 + tid;
        if (i < 1881600) {
            int bic = i / 1225;
            int rem = i - bic * 1225;
            int r = rem / 35, c = rem - r * 35;
            float v = 0.f;
            if (r >= 1 && r <= 32 && c >= 1 && c <= 32)
                v = x[bic * 1024 + (r - 1) * 32 + (c - 1)];
            xpad[i] = v;
        }
        return;
    }
    if (blk < 12) {
        int i = blk * 256 + tid;
        if (i < 3072) {
            int k = i >> 6, oc = i & 63;
            swt[i] = fsign(w1[oc * 48 + k]);
        }
        return;
    }
    if (blk == 12) {
        if (tid < 64) {   // grouped 4x4 weights, C=64
            const float* p = w2_1 + tid * 32;
            for (int r = 0; r < 8; ++r) {
                u32 sn = 0, nz = 0;
                for (int kw = 0; kw < 4; ++kw) {
                    float v = p[r * 4 + kw];
                    sn |= (u32)(v > 0.f) << kw;
                    nz |= (u32)(v != 0.f) << kw;
                }
                wpk21[tid * 8 + r] = sn | (nz << 8);
            }
        }
        {                 // 1x1 weights 256x64
            const float* p = w2_2 + (size_t)tid * 64;
            for (int j = 0; j < 2; ++j) {
                u32 sv = 0, nv = 0;
                for (int k = 0; k < 32; ++k) {
                    float v = p[j * 32 + k];
                    sv |= (u32)(v > 0.f) << k;
                    nv |= (u32)(v != 0.f) << k;
                }
                wp22[tid * 4 + j] = sv;
                wp22[tid * 4 + 2 + j] = nv;
            }
        }
        return;
    }
    {                     // blk == 13
        {                 // grouped 4x4 weights, C=256
            const float* p = w3_1 + tid * 32;
            for (int r = 0; r < 8; ++r) {
                u32 sn = 0, nz = 0;
                for (int kw = 0; kw < 4; ++kw) {
                    float v = p[r * 4 + kw];
                    sn |= (u32)(v > 0.f) << kw;
                    nz |= (u32)(v != 0.f) << kw;
                }
                wpk31[tid * 8 + r] = sn | (nz << 8);
            }
        }
        {                 // 1x1 weights 256x256
            const float* p = w3_2 + (size_t)tid * 256;
            for (int j = 0; j < 8; ++j) {
                u32 sv = 0, nv = 0;
                for (int k = 0; k < 32; ++k) {
                    float v = p[j * 32 + k];
                    sv |= (u32)(v > 0.f) << k;
                    nv |= (u32)(v != 0.f) << k;
                }
                wp32[tid * 16 + j] = sv;
                wp32[tid * 16 + 8 + j] = nv;
            }
        }
    }
}

// --- conv1 fused: block = (image, oc-group of 8); thread = 2x2 pool window ---
__global__ __launch_bounds__(256, 4) void k_conv1f(const float* __restrict__ xpad,
                                                   const float* __restrict__ swt,
                                                   const float* __restrict__ g1,
                                                   float* __restrict__ ppool,
                                                   double* __restrict__ part)
{
    __shared__ float sacc_s[8 * 17];    // [j][16 s16-partials], pad 17
    __shared__ float sacc_q[8 * 17];
    int b = blockIdx.x >> 3, ocg = blockIdx.x & 7;
    int t = threadIdx.x;
    int lane = t & 63, wv = t >> 6;
    int oh = t >> 4, ow = t & 15;       // pooled position
    const float* xb = xpad + (size_t)b * 3675 + (2 * oh) * 35 + 2 * ow;
    float acc0[8], acc1[8], acc2[8], acc3[8];   // [pos(r,c)][oc j]
#pragma unroll
    for (int j = 0; j < 8; ++j) { acc0[j] = 0.f; acc1[j] = 0.f; acc2[j] = 0.f; acc3[j] = 0.f; }
#pragma unroll 1
    for (int ic = 0; ic < 3; ++ic) {
        const float* xr = xb + ic * 1225;
        const float* wic = swt + ic * 1024 + ocg * 8;
#pragma unroll 1
        for (int rr = 0; rr < 5; ++rr) {
            float x0 = xr[0], x1 = xr[1], x2 = xr[2], x3 = xr[3], x4 = xr[4];
            if (rr <= 3) {              // contributes to out-row 2oh via kh=rr
                const float* wA = wic + rr * 256;
#pragma unroll
                for (int j = 0; j < 8; ++j) {
                    float w0 = wA[j], w1 = wA[64 + j], w2 = wA[128 + j], w3 = wA[192 + j];
                    acc0[j] = __builtin_fmaf(x0, w0, acc0[j]);
                    acc0[j] = __builtin_fmaf(x1, w1, acc0[j]);
                    acc0[j] = __builtin_fmaf(x2, w2, acc0[j]);
                    acc0[j] = __builtin_fmaf(x3, w3, acc0[j]);
                    acc1[j] = __builtin_fmaf(x1, w0, acc1[j]);
                    acc1[j] = __builtin_fmaf(x2, w1, acc1[j]);
                    acc1[j] = __builtin_fmaf(x3, w2, acc1[j]);
                    acc1[j] = __builtin_fmaf(x4, w3, acc1[j]);
                }
            }
            if (rr >= 1) {              // contributes to out-row 2oh+1 via kh=rr-1
                const float* wB = wic + (rr - 1) * 256;
#pragma unroll
                for (int j = 0; j < 8; ++j) {
                    float w0 = wB[j], w1 = wB[64 + j], w2 = wB[128 + j], w3 = wB[192 + j];
                    acc2[j] = __builtin_fmaf(x0, w0, acc2[j]);
                    acc2[j] = __builtin_fmaf(x1, w1, acc2[j]);
                    acc2[j] = __builtin_fmaf(x2, w2, acc2[j]);
                    acc2[j] = __builtin_fmaf(x3, w3, acc2[j]);
                    acc3[j] = __builtin_fmaf(x1, w0, acc3[j]);
                    acc3[j] = __builtin_fmaf(x2, w1, acc3[j]);
                    acc3[j] = __builtin_fmaf(x3, w2, acc3[j]);
                    acc3[j] = __builtin_fmaf(x4, w3, acc3[j]);
                }
            }
            xr += 35;
        }
    }
    bool owner16 = ((lane & 15) == 0);
    float* ppb = ppool + ((size_t)(b * 64 + ocg * 8)) * 256 + t;
#pragma unroll
    for (int j = 0; j < 8; ++j) {
        float a0 = acc0[j], a1 = acc1[j], a2 = acc2[j], a3 = acc3[j];
        bool posi = (g1[ocg * 8 + j] > 0.f);    // == sign(bn scale), uniform
        float pooled = posi ? fmaxf(fmaxf(a0, a1), fmaxf(a2, a3))
                            : fminf(fminf(a0, a1), fminf(a2, a3));
        float s = (a0 + a1) + (a2 + a3);
        float sq = a0 * a0 + a1 * a1 + a2 * a2 + a3 * a3;
        // 16-lane DPP reduce (positions share oh within each 16-lane group)
        s += dppf<0xB1>(s);   sq += dppf<0xB1>(sq);
        s += dppf<0x4E>(s);   sq += dppf<0x4E>(sq);
        s += dppf<0x124>(s);  sq += dppf<0x124>(sq);
        s += dppf<0x128>(s);  sq += dppf<0x128>(sq);
        if (owner16) {
            int idx = j * 17 + wv * 4 + (lane >> 4);
            sacc_s[idx] = s;
            sacc_q[idx] = sq;
        }
        ppb[j * 256] = pooled;
    }
    __syncthreads();
    if (t < 16) {
        int j = t >> 1, half = t & 1;
        const float* sp = (half ? sacc_q : sacc_s) + j * 17;
        double acc = 0.0;
        for (int i = 0; i < 16; ++i) acc += (double)sp[i];
        part[(((size_t)(ocg * 8 + j)) * 512 + b) * 2 + half] = acc;
    }
}

// --- int8 stats: exact int32 block sums -> double partials ---
__global__ __launch_bounds__(256) void k_stats_i8(const signed char* __restrict__ in,
                                                  double* __restrict__ part,
                                                  int C, int HW, int bPerChunk)
{
    int c = blockIdx.x, chunk = blockIdx.y, b0 = chunk * bPerChunk;
    int q4 = HW >> 2;
    int s = 0, sq = 0;
    for (int b = b0; b < b0 + bPerChunk; ++b) {
        const u32* p = (const u32*)(in + (size_t)(b * C + c) * HW);
        for (int i = threadIdx.x; i < q4; i += 256) {
            u32 v = p[i];
            int x0 = (int)(v << 24) >> 24, x1 = (int)(v << 16) >> 24;
            int x2 = (int)(v << 8) >> 24,  x3 = (int)v >> 24;
            s += x0 + x1 + x2 + x3;
            sq += x0 * x0 + x1 * x1 + x2 * x2 + x3 * x3;
        }
    }
    __shared__ int ss[256];
    __shared__ int sb[256];
    ss[threadIdx.x] = s; sb[threadIdx.x] = sq;
    __syncthreads();
    for (int st = 128; st > 0; st >>= 1) {
        if (threadIdx.x < st) {
            ss[threadIdx.x] += ss[threadIdx.x + st];
            sb[threadIdx.x] += sb[threadIdx.x + st];
        }
        __syncthreads();
    }
    if (threadIdx.x == 0) {
        int nch = gridDim.y;
        part[(size_t)(c * nch + chunk) * 2]     = (double)ss[0];
        part[(size_t)(c * nch + chunk) * 2 + 1] = (double)sb[0];
    }
}

// --- int16 stats ---
__global__ __launch_bounds__(256) void k_stats_i16(const short* __restrict__ in,
                                                   double* __restrict__ part,
                                                   int C, int HW, int bPerChunk)
{
    int c = blockIdx.x, chunk = blockIdx.y, b0 = chunk * bPerChunk;
    int q2 = HW >> 1;
    int s = 0, sq = 0;
    for (int b = b0; b < b0 + bPerChunk; ++b) {
        const u32* p = (const u32*)(in + (size_t)(b * C + c) * HW);
        for (int i = threadIdx.x; i < q2; i += 256) {
            u32 v = p[i];
            int x0 = (int)(v << 16) >> 16, x1 = (int)v >> 16;
            s += x0 + x1;
            sq += x0 * x0 + x1 * x1;
        }
    }
    __shared__ int ss[256];
    __shared__ int sb[256];
    ss[threadIdx.x] = s; sb[threadIdx.x] = sq;
    __syncthreads();
    for (int st = 128; st > 0; st >>= 1) {
        if (threadIdx.x < st) {
            ss[threadIdx.x] += ss[threadIdx.x + st];
            sb[threadIdx.x] += sb[threadIdx.x + st];
        }
        __syncthreads();
    }
    if (threadIdx.x == 0) {
        int nch = gridDim.y;
        part[(size_t)(c * nch + chunk) * 2]     = (double)ss[0];
        part[(size_t)(c * nch + chunk) * 2 + 1] = (double)sb[0];
    }
}

// --- finalize: block per channel; mean/var -> power-of-two shift scale ---
__global__ __launch_bounds__(256) void k_finalize2(const double* __restrict__ part,
                                                   int nch, int N,
                                                   const float* __restrict__ gamma,
                                                   const float* __restrict__ beta,
                                                   float4* __restrict__ st)
{
    int c = blockIdx.x;
    double s = 0.0, sq = 0.0;
    for (int i = threadIdx.x; i < nch; i += 256) {
        s  += part[((size_t)c * nch + i) * 2];
        sq += part[((size_t)c * nch + i) * 2 + 1];
    }
    __shared__ double ss[256];
    __shared__ double sb[256];
    ss[threadIdx.x] = s; sb[threadIdx.x] = sq;
    __syncthreads();
    for (int stp = 128; stp > 0; stp >>= 1) {
        if (threadIdx.x < stp) {
            ss[threadIdx.x] += ss[threadIdx.x + stp];
            sb[threadIdx.x] += sb[threadIdx.x + stp];
        }
        __syncthreads();
    }
    if (threadIdx.x == 0) {
        double mean = ss[0] / (double)N;
        double var = sb[0] / (double)N - mean * mean;
        float inv = gamma[c] / sqrtf((float)var + 1e-5f);
        float sh = rintf(log2f(fabsf(inv) + 1e-12f));
        sh = fminf(fmaxf(sh, -4.f), 4.f);
        float scale = copysignf(exp2f(sh), inv);
        st[c] = make_float4((float)mean, scale, beta[c], 0.f);
    }
}

// --- FUSED layer-2 head: bnpick(ppool) -> LDS packed rows -> grouped conv ---
// block = image, 512 threads. Writes q8 int8 + bn stats partials.
__global__ __launch_bounds__(512) void k_fuse2(const float* __restrict__ ppool,
                                               const float4* __restrict__ st,
                                               const u32* __restrict__ wpk,
                                               signed char* __restrict__ out,
                                               double* __restrict__ part)
{
    __shared__ u32 lspk[64 * 20];
    __shared__ u32 lnpk[64 * 20];
    int b = blockIdx.x, t = threadIdx.x;
    // phase 1: bn + binarize + row-pack, 64 ch x 16 rows (2 items/thread)
#pragma unroll
    for (int k = 0; k < 2; ++k) {
        int e = t + k * 512;
        int c = e >> 4, oh = e & 15;
        float4 s = st[c];
        const float4* p = (const float4*)(ppool + ((size_t)(b * 64 + c)) * 256 + oh * 16);
        u32 sb = 0, nb = 0;
#pragma unroll
        for (int j = 0; j < 4; ++j) {
            float4 v4 = p[j];
            float vs[4] = {v4.x, v4.y, v4.z, v4.w};
#pragma unroll
            for (int kk = 0; kk < 4; ++kk) {
                float v = (vs[kk] - s.x) * s.y + s.z;
                int ow = j * 4 + kk;
                sb |= (u32)(v > 0.f) << (ow + 1);
                nb |= (u32)(v != 0.f) << (ow + 1);
            }
        }
        lspk[c * 20 + 1 + oh] = sb;
        lnpk[c * 20 + 1 + oh] = nb;
        if (oh < 4) {
            int zs = (oh == 0) ? 0 : (16 + oh);
            lspk[c * 20 + zs] = 0; lnpk[c * 20 + zs] = 0;
        }
    }
    __syncthreads();
    // phase 2: grouped conv, 32 groups x 16 rows (1 item/thread)
    int g = t >> 4, h = t & 15;
    const u32* sp = lspk + (2 * g) * 20 + h;
    const u32* np = lnpk + (2 * g) * 20 + h;
    u32 S[8], N[8];
#pragma unroll
    for (int jc = 0; jc < 2; ++jc)
#pragma unroll
        for (int jj = 0; jj < 4; ++jj) {
            S[jc * 4 + jj] = sp[jc * 20 + jj];
            N[jc * 4 + jj] = np[jc * 20 + jj];
        }
    const u32* wq = wpk + (size_t)(2 * g) * 8;
    u32 Ws0[8], Wn0[8], Ws1[8], Wn1[8];
#pragma unroll
    for (int r = 0; r < 8; ++r) {
        u32 a = wq[r];      Ws0[r] = a & 15u;  Wn0[r] = (a >> 8) & 15u;
        u32 bb = wq[8 + r]; Ws1[r] = bb & 15u; Wn1[r] = (bb >> 8) & 15u;
    }
    int v0[16], v1[16];
    int s0 = 0, q0 = 0, s1 = 0, q1 = 0;
#pragma unroll
    for (int w = 0; w < 16; ++w) {
        int snz0 = 0, smis0 = 0, snz1 = 0, smis1 = 0;
#pragma unroll
        for (int r = 0; r < 8; ++r) {
            u32 ss = (S[r] >> w) & 15u;
            u32 nn = (N[r] >> w) & 15u;
            u32 nz0 = nn & Wn0[r]; u32 m0 = (ss ^ Ws0[r]) & nz0;
            snz0 += __popc(nz0); smis0 += __popc(m0);
            u32 nz1 = nn & Wn1[r]; u32 m1 = (ss ^ Ws1[r]) & nz1;
            snz1 += __popc(nz1); smis1 += __popc(m1);
        }
        v0[w] = snz0 - 2 * smis0;
        v1[w] = snz1 - 2 * smis1;
        s0 += v0[w]; q0 += v0[w] * v0[w];
        s1 += v1[w]; q1 += v1[w] * v1[w];
    }
#pragma unroll
    for (int m = 1; m < 16; m <<= 1) {
        s0 += __shfl_xor(s0, m); q0 += __shfl_xor(q0, m);
        s1 += __shfl_xor(s1, m); q1 += __shfl_xor(q1, m);
    }
    if (h == 0) {
        part[((size_t)(2 * g) * 512 + b) * 2]         = (double)s0;
        part[((size_t)(2 * g) * 512 + b) * 2 + 1]     = (double)q0;
        part[((size_t)(2 * g + 1) * 512 + b) * 2]     = (double)s1;
        part[((size_t)(2 * g + 1) * 512 + b) * 2 + 1] = (double)q1;
    }
    signed char* o0 = out + ((size_t)((b * 64 + 2 * g) * 16 + h)) * 16;
    signed char* o1 = o0 + 256;
    u32 wb0[4], wb1[4];
#pragma unroll
    for (int j = 0; j < 4; ++j) {
        wb0[j] = pack4(v0[4*j], v0[4*j+1], v0[4*j+2], v0[4*j+3]);
        wb1[j] = pack4(v1[4*j], v1[4*j+1], v1[4*j+2], v1[4*j+3]);
    }
    *(uint4*)o0 = make_uint4(wb0[0], wb0[1], wb0[2], wb0[3]);
    *(uint4*)o1 = make_uint4(wb1[0], wb1[1], wb1[2], wb1[3]);
}

// --- 1x1 conv Cin=64->Cout=256, HW=256, int8 out, FUSED bn2_1 binarize+pack ---
__global__ __launch_bounds__(256) void k_conv1x1_bp2(const signed char* __restrict__ q8,
                                                     const float4* __restrict__ st,
                                                     const u32* __restrict__ wp,
                                                     signed char* __restrict__ out)
{
    int t = blockIdx.x * 256 + threadIdx.x;   // t = b*256 + hw
    int hw = t & 255; int b = t >> 8;
    const signed char* qp = q8 + (size_t)b * 64 * 256 + hw;
    u32 as0 = 0, as1 = 0, an0 = 0, an1 = 0;
#pragma unroll
    for (int k = 0; k < 32; ++k) {
        float4 s = st[k];                       // uniform -> s_load
        float v = ((float)qp[k * 256] - s.x) * s.y + s.z;   // coalesced byte load
        as0 |= (u32)(v > 0.f) << k;
        an0 |= (u32)(v != 0.f) << k;
    }
#pragma unroll
    for (int k = 0; k < 32; ++k) {
        float4 s = st[32 + k];
        float v = ((float)qp[(32 + k) * 256] - s.x) * s.y + s.z;
        as1 |= (u32)(v > 0.f) << k;
        an1 |= (u32)(v != 0.f) << k;
    }
    signed char* op = out + (size_t)b * 256 * 256 + hw;
#pragma unroll 8
    for (int oc = 0; oc < 256; ++oc) {
        uint4 wv = ((const uint4*)wp)[oc];      // wave-uniform -> scalar loads
        u32 nz0 = an0 & wv.z, nz1 = an1 & wv.w;
        u32 m0 = (as0 ^ wv.x) & nz0, m1 = (as1 ^ wv.y) & nz1;
        int dot = __popc(nz0) + __popc(nz1) - 2 * (__popc(m0) + __popc(m1));
        op[(size_t)oc << 8] = (signed char)dot;
    }
}

// --- FUSED layer-3 head: pool+pack(c22) -> LDS rows -> grouped conv ---
// block = image, 512 threads. Writes q8 + stats partials.
__global__ __launch_bounds__(512) void k_fuse3(const signed char* __restrict__ c22,
                                               const float4* __restrict__ st,
                                               const u32* __restrict__ wpk,
                                               signed char* __restrict__ out,
                                               double* __restrict__ part)
{
    __shared__ u32 lspk[256 * 12];
    __shared__ u32 lnpk[256 * 12];
    int b = blockIdx.x, t = threadIdx.x;
    // phase 1: bn+pool+binarize+pack, 256 ch x 8 rows (4 items/thread)
#pragma unroll
    for (int k = 0; k < 4; ++k) {
        int e = t + k * 512;
        int c = e >> 3, oh = e & 7;
        float4 s = st[c];
        const uint4* p = (const uint4*)(c22 + ((size_t)(b * 256 + c)) * 256 + (size_t)(2 * oh) * 16);
        uint4 r0 = p[0], r1 = p[1];
        bool pos = (s.y > 0.f);
        u32 rows0[4] = {r0.x, r0.y, r0.z, r0.w};
        u32 rows1[4] = {r1.x, r1.y, r1.z, r1.w};
        u32 sb = 0, nb = 0;
#pragma unroll
        for (int j = 0; j < 4; ++j) {
            u32 a = rows0[j], bw = rows1[j];
#pragma unroll
            for (int kk = 0; kk < 2; ++kk) {
                int sh0 = 24 - 16 * kk, sh1 = 16 - 16 * kk;
                int a0 = (int)(a  << sh0) >> 24, a1 = (int)(a  << sh1) >> 24;
                int a2 = (int)(bw << sh0) >> 24, a3 = (int)(bw << sh1) >> 24;
                int raw = pos ? max(max(a0, a1), max(a2, a3))
                              : min(min(a0, a1), min(a2, a3));
                float v = ((float)raw - s.x) * s.y + s.z;
                int ow = j * 2 + kk;
                sb |= (u32)(v > 0.f) << (ow + 1);
                nb |= (u32)(v != 0.f) << (ow + 1);
            }
        }
        lspk[c * 12 + 1 + oh] = sb;
        lnpk[c * 12 + 1 + oh] = nb;
        if (oh < 4) {
            int zs = (oh == 0) ? 0 : (8 + oh);
            lspk[c * 12 + zs] = 0; lnpk[c * 12 + zs] = 0;
        }
    }
    __syncthreads();
    // phase 2: grouped conv, 128 groups x 8 rows (2 items/thread)
#pragma unroll
    for (int k = 0; k < 2; ++k) {
        int e = t + k * 512;
        int g = e >> 3, h = e & 7;
        const u32* sp = lspk + (2 * g) * 12 + h;
        const u32* np = lnpk + (2 * g) * 12 + h;
        u32 S[8], N[8];
#pragma unroll
        for (int jc = 0; jc < 2; ++jc)
#pragma unroll
            for (int jj = 0; jj < 4; ++jj) {
                S[jc * 4 + jj] = sp[jc * 12 + jj];
                N[jc * 4 + jj] = np[jc * 12 + jj];
            }
        const u32* wq = wpk + (size_t)(2 * g) * 8;
        u32 Ws0[8], Wn0[8], Ws1[8], Wn1[8];
#pragma unroll
        for (int r = 0; r < 8; ++r) {
            u32 a = wq[r];      Ws0[r] = a & 15u;  Wn0[r] = (a >> 8) & 15u;
            u32 bb = wq[8 + r]; Ws1[r] = bb & 15u; Wn1[r] = (bb >> 8) & 15u;
        }
        int v0[8], v1[8];
        int s0 = 0, q0 = 0, s1 = 0, q1 = 0;
#pragma unroll
        for (int w = 0; w < 8; ++w) {
            int snz0 = 0, smis0 = 0, snz1 = 0, smis1 = 0;
#pragma unroll
            for (int r = 0; r < 8; ++r) {
                u32 ss = (S[r] >> w) & 15u;
                u32 nn = (N[r] >> w) & 15u;
                u32 nz0 = nn & Wn0[r]; u32 m0 = (ss ^ Ws0[r]) & nz0;
                snz0 += __popc(nz0); smis0 += __popc(m0);
                u32 nz1 = nn & Wn1[r]; u32 m1 = (ss ^ Ws1[r]) & nz1;
                snz1 += __popc(nz1); smis1 += __popc(m1);
            }
            v0[w] = snz0 - 2 * smis0;
            v1[w] = snz1 - 2 * smis1;
            s0 += v0[w]; q0 += v0[w] * v0[w];
            s1 += v1[w]; q1 += v1[w] * v1[w];
        }
#pragma unroll
        for (int m = 1; m < 8; m <<= 1) {
            s0 += __shfl_xor(s0, m); q0 += __shfl_xor(q0, m);
            s1 += __shfl_xor(s1, m); q1 += __shfl_xor(q1, m);
        }
        if (h == 0) {
            part[((size_t)(2 * g) * 512 + b) * 2]         = (double)s0;
            part[((size_t)(2 * g) * 512 + b) * 2 + 1]     = (double)q0;
            part[((size_t)(2 * g + 1) * 512 + b) * 2]     = (double)s1;
            part[((size_t)(2 * g + 1) * 512 + b) * 2 + 1] = (double)q1;
        }
        signed char* o0 = out + ((size_t)((b * 256 + 2 * g) * 8 + h)) * 8;
        signed char* o1 = o0 + 64;
        *(uint2*)o0 = make_uint2(pack4(v0[0], v0[1], v0[2], v0[3]),
                                 pack4(v0[4], v0[5], v0[6], v0[7]));
        *(uint2*)o1 = make_uint2(pack4(v1[0], v1[1], v1[2], v1[3]),
                                 pack4(v1[4], v1[5], v1[6], v1[7]));
    }
}

// --- FUSED: bn+binarize+channel-pack (LDS) -> 1x1 conv Cin=256, int16 out ---
// block = image, 256 threads.
__global__ __launch_bounds__(256) void k_fuse4(const signed char* __restrict__ q8,
                                               const float4* __restrict__ st,
                                               const u32* __restrict__ wp,
                                               short* __restrict__ out)
{
    __shared__ u32 sq[4096];       // one image: 256ch x 64hw bytes
    __shared__ u32 act[64 * 17];   // [hw][16 words], pad 17
    int b = blockIdx.x, t = threadIdx.x;
    const u32* qb = (const u32*)(q8 + (size_t)b * 16384);
    for (int i = t; i < 4096; i += 256) sq[i] = qb[i];
    __syncthreads();
    {
        const signed char* s8p = (const signed char*)sq;
        int hw = t & 63, qd = t >> 6;
        u32 sv0 = 0, nv0 = 0, sv1 = 0, nv1 = 0;
#pragma unroll
        for (int k = 0; k < 32; ++k) {
            int c = qd * 64 + k;
            float4 s = st[c];
            float v = ((float)s8p[c * 64 + hw] - s.x) * s.y + s.z;
            sv0 |= (u32)(v > 0.f) << k;
            nv0 |= (u32)(v != 0.f) << k;
        }
#pragma unroll
        for (int k = 0; k < 32; ++k) {
            int c = qd * 64 + 32 + k;
            float4 s = st[c];
            float v = ((float)s8p[c * 64 + hw] - s.x) * s.y + s.z;
            sv1 |= (u32)(v > 0.f) << k;
            nv1 |= (u32)(v != 0.f) << k;
        }
        u32* ap = act + hw * 17;
        ap[qd * 2]     = sv0;
        ap[qd * 2 + 1] = sv1;
        ap[8 + qd * 2]     = nv0;
        ap[8 + qd * 2 + 1] = nv1;
    }
    __syncthreads();
    int hw = t & 63, ch = t >> 6;
    const u32* ap = act + hw * 17;
    u32 as[8], an[8];
#pragma unroll
    for (int j = 0; j < 8; ++j) { as[j] = ap[j]; an[j] = ap[8 + j]; }
    short* op = out + (size_t)b * 256 * 64 + hw;
#pragma unroll 4
    for (int oc = ch * 64; oc < ch * 64 + 64; ++oc) {
        const u32* wq = wp + oc * 16;
        int snz = 0, smis = 0;
#pragma unroll
        for (int j = 0; j < 8; ++j) {
            u32 nz = an[j] & wq[8 + j];
            u32 m = (as[j] ^ wq[j]) & nz;
            snz += __popc(nz); smis += __popc(m);
        }
        op[(size_t)oc * 64] = (short)(snz - 2 * smis);
    }
}

// --- FC: block per image, bn3_2 applied inline, features read once ---
__global__ __launch_bounds__(256) void k_fc2(const short* __restrict__ f,
                                             const float4* __restrict__ st,
                                             const float* __restrict__ fcw,
                                             const float* __restrict__ fcb,
                                             float* __restrict__ out)
{
    int b = blockIdx.x, t = threadIdx.x;
    int lane = t & 63, wv = t >> 6;
    const u32* fp = (const u32*)(f + (size_t)b * 16384);
    float acc[10];
#pragma unroll
    for (int n = 0; n < 10; ++n) acc[n] = 0.f;
    for (int i = 0; i < 32; ++i) {
        int j = i * 256 + t;                 // u32 index; features 2j, 2j+1
        u32 v = fp[j];
        float4 s = st[j >> 5];               // channel = (2j)>>6 = j>>5
        float f0 = ((float)((int)(v << 16) >> 16) - s.x) * s.y + s.z;
        float f1 = ((float)((int)v >> 16) - s.x) * s.y + s.z;
#pragma unroll
        for (int n = 0; n < 10; ++n) {
            float2 wv2 = *(const float2*)(fcw + (size_t)n * 16384 + 2 * j);
            acc[n] += f0 * wv2.x + f1 * wv2.y;
        }
    }
#pragma unroll
    for (int n = 0; n < 10; ++n)
#pragma unroll
        for (int m = 1; m < 64; m <<= 1) acc[n] += __shfl_xor(acc[n], m);
    __shared__ float sred[4][10];
    if (lane == 0)
#pragma unroll
        for (int n = 0; n < 10; ++n) sred[wv][n] = acc[n];
    __syncthreads();
    if (t < 10)
        out[b * 10 + t] = sred[0][t] + sred[1][t] + sred[2][t] + sred[3][t] + fcb[t];
}

extern "C" void kernel_launch(void* const* d_in, const int* in_sizes, int n_in,
                              void* d_out, int out_size, void* d_ws, size_t ws_size,
                              hipStream_t stream)
{
    const float* x    = (const float*)d_in[0];
    const float* w1   = (const float*)d_in[1];
    const float* g1   = (const float*)d_in[2];
    const float* b1   = (const float*)d_in[3];
    const float* w2_1 = (const float*)d_in[4];
    const float* g2_1 = (const float*)d_in[5];
    const float* b2_1 = (const float*)d_in[6];
    const float* w2_2 = (const float*)d_in[7];
    const float* g2_2 = (const float*)d_in[8];
    const float* b2_2 = (const float*)d_in[9];
    const float* w3_1 = (const float*)d_in[10];
    const float* g3_1 = (const float*)d_in[11];
    const float* b3_1 = (const float*)d_in[12];
    const float* w3_2 = (const float*)d_in[13];
    const float* g3_2 = (const float*)d_in[14];
    const float* b3_2 = (const float*)d_in[15];
    const float* fcw  = (const float*)d_in[16];
    const float* fcb  = (const float*)d_in[17];
    float* out = (float*)d_out;

    // workspace layout (bytes). ppool aliases later c22 (write-after-consume
    // ordering per launch sequence).
    const size_t OFF_PPOOL= 0;          // 33,554,432  (-> c22 later)
    const size_t OFF_F3   = 33554432;   // 16,777,216  conv3_2 int16 out
    const size_t OFF_Q    = 50331648;   //  8,388,608  convg int8 outs
    const size_t OFF_WPK21= 67108864;   //  2,048
    const size_t OFF_WPK31= 67110912;   //  8,192
    const size_t OFF_WP22 = 67119104;   //  4,096
    const size_t OFF_WP32 = 67123200;   //  16,384
    const size_t OFF_PART = 67139584;   //  2,097,152
    const size_t OFF_ST   = 69236736;   //  20,480     5 x 256 float4
    const size_t OFF_SWT  = 69257216;   //  12,288     conv1 signed weights, tap-major f32
    const size_t OFF_XPAD = 69269504;   //  7,526,400  padded input
    const size_t NEED     = OFF_XPAD + 7526400;
    if (ws_size < NEED) return;

    char* ws = (char*)d_ws;
    float* ppool = (float*)(ws + OFF_PPOOL);
    signed char* c22 = (signed char*)(ws + OFF_PPOOL); // after k_fuse2 consumes ppool
    short* f3  = (short*)(ws + OFF_F3);
    signed char* q8 = (signed char*)(ws + OFF_Q);
    u32* wpk21 = (u32*)(ws + OFF_WPK21);
    u32* wpk31 = (u32*)(ws + OFF_WPK31);
    u32* wp22  = (u32*)(ws + OFF_WP22);
    u32* wp32  = (u32*)(ws + OFF_WP32);
    double* part = (double*)(ws + OFF_PART);
    float4* st1  = (float4*)(ws + OFF_ST);
    float4* st21 = st1 + 256;
    float4* st22 = st21 + 256;
    float4* st31 = st22 + 256;
    float4* st32 = st31 + 256;
    float* swt   = (float*)(ws + OFF_SWT);
    float* xpad  = (float*)(ws + OFF_XPAD);

    // ---- weight prep + input pad (one launch) ----
    k_wprep<<<7364, 256, 0, stream>>>(w1, swt, w2_1, wpk21, w3_1, wpk31,
                                      w2_2, wp22, w3_2, wp32, x, xpad);

    // ---- layer 1 ----
    k_conv1f<<<4096, 256, 0, stream>>>(xpad, swt, g1, ppool, part);
    k_finalize2<<<64, 256, 0, stream>>>(part, 512, 512 * 1024, g1, b1, st1);

    // ---- layer 2 (pack+gconv fused) ----
    k_fuse2<<<512, 512, 0, stream>>>(ppool, st1, wpk21, q8, part);
    k_finalize2<<<64, 256, 0, stream>>>(part, 512, 512 * 256, g2_1, b2_1, st21);
    k_conv1x1_bp2<<<512, 256, 0, stream>>>(q8, st21, wp22, c22);
    k_stats_i8<<<dim3(256, 32), 256, 0, stream>>>(c22, part, 256, 256, 16);
    k_finalize2<<<256, 256, 0, stream>>>(part, 32, 512 * 256, g2_2, b2_2, st22);

    // ---- layer 3 (pool+pack+gconv fused; pack+1x1 fused) ----
    k_fuse3<<<512, 512, 0, stream>>>(c22, st22, wpk31, q8, part);
    k_finalize2<<<256, 256, 0, stream>>>(part, 512, 512 * 64, g3_1, b3_1, st31);
    k_fuse4<<<512, 256, 0, stream>>>(q8, st31, wp32, f3);
    k_stats_i16<<<dim3(256, 32), 256, 0, stream>>>(f3, part, 256, 64, 16);
    k_finalize2<<<256, 256, 0, stream>>>(part, 32, 512 * 64, g3_2, b3_2, st32);

    // ---- FC (bn3_2 inline) ----
    k_fc2<<<512, 256, 0, stream>>>(f3, st32, fcw, fcb, out);
}

// Round 14
// 239.448 us; speedup vs baseline: 1.5483x; 1.1328x over previous
//
#include <hip/hip_runtime.h>

typedef unsigned int u32;

// ---------------------------------------------------------------------------
// LiBNet forward, bit-packed ternary arithmetic + integer intermediates.
// dot over taps = popc(nzA & nzW) - 2*popc((sA ^ sW) & nzA & nzW)
// conv1: thread = 2x2 pooled window x 8 oc, fmaf chains, float2 row loads
// (xpad rows padded to 36 floats for 8B alignment).
// Pack->conv stages fused per image; stats+finalize merged where standalone.
// ---------------------------------------------------------------------------

static __device__ __forceinline__ float fsign(float x) {
    return (x > 0.f) ? 1.f : ((x < 0.f) ? -1.f : 0.f);
}
static __device__ __forceinline__ u32 pack4(int a, int b, int c, int d) {
    return (a & 0xff) | ((b & 0xff) << 8) | ((c & 0xff) << 16) | ((u32)(d & 0xff) << 24);
}
// DPP on float (VALU pipe). 0xB1 = quad lane^1, 0x4E = quad lane^2,
// 0x124 = row_ror:4, 0x128 = row_ror:8 (16-lane row rotations).
template <int CTRL>
static __device__ __forceinline__ float dppf(float x) {
    int i = __builtin_amdgcn_mov_dpp(__float_as_int(x), CTRL, 0xF, 0xF, true);
    return __int_as_float(i);
}

// --- weight prep + input padding (one launch) ---
// conv1 weights TAP-MAJOR: swt[k*64+oc] = sign(w1[oc*48+k]).
// xpad layout: [512*3][35 rows][36 cols] (col 35 = align pad, zeroed).
__global__ __launch_bounds__(256) void k_wprep(const float* __restrict__ w1, float* __restrict__ swt,
                                               const float* __restrict__ w2_1, u32* __restrict__ wpk21,
                                               const float* __restrict__ w3_1, u32* __restrict__ wpk31,
                                               const float* __restrict__ w2_2, u32* __restrict__ wp22,
                                               const float* __restrict__ w3_2, u32* __restrict__ wp32,
                                               const float* __restrict__ x, float* __restrict__ xpad)
{
    int blk = blockIdx.x, tid = threadIdx.x;
    if (blk >= 14) {                    // pad x -> xpad
        int i = (blk - 14) * 256 + tid;
        if (i < 1935360) {
            int bic = i / 1260;
            int rem = i - bic * 1260;
            int r = rem / 36, c = rem - r * 36;
            float v = 0.f;
            if (r >= 1 && r <= 32 && c >= 1 && c <= 32)
                v = x[bic * 1024 + (r - 1) * 32 + (c - 1)];
            xpad[i] = v;
        }
        return;
    }
    if (blk < 12) {
        int i = blk * 256 + tid;
        if (i < 3072) {
            int k = i >> 6, oc = i & 63;
            swt[i] = fsign(w1[oc * 48 + k]);
        }
        return;
    }
    if (blk == 12) {
        if (tid < 64) {   // grouped 4x4 weights, C=64
            const float* p = w2_1 + tid * 32;
            for (int r = 0; r < 8; ++r) {
                u32 sn = 0, nz = 0;
                for (int kw = 0; kw < 4; ++kw) {
                    float v = p[r * 4 + kw];
                    sn |= (u32)(v > 0.f) << kw;
                    nz |= (u32)(v != 0.f) << kw;
                }
                wpk21[tid * 8 + r] = sn | (nz << 8);
            }
        }
        {                 // 1x1 weights 256x64
            const float* p = w2_2 + (size_t)tid * 64;
            for (int j = 0; j < 2; ++j) {
                u32 sv = 0, nv = 0;
                for (int k = 0; k < 32; ++k) {
                    float v = p[j * 32 + k];
                    sv |= (u32)(v > 0.f) << k;
                    nv |= (u32)(v != 0.f) << k;
                }
                wp22[tid * 4 + j] = sv;
                wp22[tid * 4 + 2 + j] = nv;
            }
        }
        return;
    }
    {                     // blk == 13
        {                 // grouped 4x4 weights, C=256
            const float* p = w3_1 + tid * 32;
            for (int r = 0; r < 8; ++r) {
                u32 sn = 0, nz = 0;
                for (int kw = 0; kw < 4; ++kw) {
                    float v = p[r * 4 + kw];
                    sn |= (u32)(v > 0.f) << kw;
                    nz |= (u32)(v != 0.f) << kw;
                }
                wpk31[tid * 8 + r] = sn | (nz << 8);
            }
        }
        {                 // 1x1 weights 256x256
            const float* p = w3_2 + (size_t)tid * 256;
            for (int j = 0; j < 8; ++j) {
                u32 sv = 0, nv = 0;
                for (int k = 0; k < 32; ++k) {
                    float v = p[j * 32 + k];
                    sv |= (u32)(v > 0.f) << k;
                    nv |= (u32)(v != 0.f) << k;
                }
                wp32[tid * 16 + j] = sv;
                wp32[tid * 16 + 8 + j] = nv;
            }
        }
    }
}

// --- conv1 fused: block = (image, oc-group of 8); thread = 2x2 pool window ---
__global__ __launch_bounds__(256) void k_conv1f(const float* __restrict__ xpad,
                                                const float* __restrict__ swt,
                                                const float* __restrict__ g1,
                                                float* __restrict__ ppool,
                                                double* __restrict__ part)
{
    __shared__ float sacc_s[8 * 17];    // [j][16 s16-partials], pad 17
    __shared__ float sacc_q[8 * 17];
    int b = blockIdx.x >> 3, ocg = blockIdx.x & 7;
    int t = threadIdx.x;
    int lane = t & 63, wv = t >> 6;
    int oh = t >> 4, ow = t & 15;       // pooled position
    const float* xb = xpad + (size_t)b * 3780 + (2 * oh) * 36 + 2 * ow;
    float acc0[8], acc1[8], acc2[8], acc3[8];   // [pos(r,c)][oc j]
#pragma unroll
    for (int j = 0; j < 8; ++j) { acc0[j] = 0.f; acc1[j] = 0.f; acc2[j] = 0.f; acc3[j] = 0.f; }
#pragma unroll 1
    for (int ic = 0; ic < 3; ++ic) {
        const float* xr = xb + ic * 1260;
        const float* wic = swt + ic * 1024 + ocg * 8;
#pragma unroll 1
        for (int rr = 0; rr < 5; ++rr) {
            float2 a01 = *(const float2*)xr;
            float2 a23 = *(const float2*)(xr + 2);
            float x0 = a01.x, x1 = a01.y, x2 = a23.x, x3 = a23.y, x4 = xr[4];
            if (rr <= 3) {              // contributes to out-row 2oh via kh=rr
                const float* wA = wic + rr * 256;
#pragma unroll
                for (int j = 0; j < 8; ++j) {
                    float w0 = wA[j], w1 = wA[64 + j], w2 = wA[128 + j], w3 = wA[192 + j];
                    acc0[j] = __builtin_fmaf(x0, w0, acc0[j]);
                    acc0[j] = __builtin_fmaf(x1, w1, acc0[j]);
                    acc0[j] = __builtin_fmaf(x2, w2, acc0[j]);
                    acc0[j] = __builtin_fmaf(x3, w3, acc0[j]);
                    acc1[j] = __builtin_fmaf(x1, w0, acc1[j]);
                    acc1[j] = __builtin_fmaf(x2, w1, acc1[j]);
                    acc1[j] = __builtin_fmaf(x3, w2, acc1[j]);
                    acc1[j] = __builtin_fmaf(x4, w3, acc1[j]);
                }
            }
            if (rr >= 1) {              // contributes to out-row 2oh+1 via kh=rr-1
                const float* wB = wic + (rr - 1) * 256;
#pragma unroll
                for (int j = 0; j < 8; ++j) {
                    float w0 = wB[j], w1 = wB[64 + j], w2 = wB[128 + j], w3 = wB[192 + j];
                    acc2[j] = __builtin_fmaf(x0, w0, acc2[j]);
                    acc2[j] = __builtin_fmaf(x1, w1, acc2[j]);
                    acc2[j] = __builtin_fmaf(x2, w2, acc2[j]);
                    acc2[j] = __builtin_fmaf(x3, w3, acc2[j]);
                    acc3[j] = __builtin_fmaf(x1, w0, acc3[j]);
                    acc3[j] = __builtin_fmaf(x2, w1, acc3[j]);
                    acc3[j] = __builtin_fmaf(x3, w2, acc3[j]);
                    acc3[j] = __builtin_fmaf(x4, w3, acc3[j]);
                }
            }
            xr += 36;
        }
    }
    bool owner16 = ((lane & 15) == 0);
    float* ppb = ppool + ((size_t)(b * 64 + ocg * 8)) * 256 + t;
#pragma unroll
    for (int j = 0; j < 8; ++j) {
        float a0 = acc0[j], a1 = acc1[j], a2 = acc2[j], a3 = acc3[j];
        bool posi = (g1[ocg * 8 + j] > 0.f);    // == sign(bn scale), uniform
        float pooled = posi ? fmaxf(fmaxf(a0, a1), fmaxf(a2, a3))
                            : fminf(fminf(a0, a1), fminf(a2, a3));
        float s = (a0 + a1) + (a2 + a3);
        float sq = a0 * a0 + a1 * a1 + a2 * a2 + a3 * a3;
        s += dppf<0xB1>(s);   sq += dppf<0xB1>(sq);
        s += dppf<0x4E>(s);   sq += dppf<0x4E>(sq);
        s += dppf<0x124>(s);  sq += dppf<0x124>(sq);
        s += dppf<0x128>(s);  sq += dppf<0x128>(sq);
        if (owner16) {
            int idx = j * 17 + wv * 4 + (lane >> 4);
            sacc_s[idx] = s;
            sacc_q[idx] = sq;
        }
        ppb[j * 256] = pooled;
    }
    __syncthreads();
    if (t < 16) {
        int j = t >> 1, half = t & 1;
        const float* sp = (half ? sacc_q : sacc_s) + j * 17;
        double acc = 0.0;
        for (int i = 0; i < 16; ++i) acc += (double)sp[i];
        part[(((size_t)(ocg * 8 + j)) * 512 + b) * 2 + half] = acc;
    }
}

// --- finalize: block per channel; mean/var -> power-of-two shift scale ---
__global__ __launch_bounds__(256) void k_finalize2(const double* __restrict__ part,
                                                   int nch, int N,
                                                   const float* __restrict__ gamma,
                                                   const float* __restrict__ beta,
                                                   float4* __restrict__ st)
{
    int c = blockIdx.x;
    double s = 0.0, sq = 0.0;
    for (int i = threadIdx.x; i < nch; i += 256) {
        s  += part[((size_t)c * nch + i) * 2];
        sq += part[((size_t)c * nch + i) * 2 + 1];
    }
    __shared__ double ss[256];
    __shared__ double sb[256];
    ss[threadIdx.x] = s; sb[threadIdx.x] = sq;
    __syncthreads();
    for (int stp = 128; stp > 0; stp >>= 1) {
        if (threadIdx.x < stp) {
            ss[threadIdx.x] += ss[threadIdx.x + stp];
            sb[threadIdx.x] += sb[threadIdx.x + stp];
        }
        __syncthreads();
    }
    if (threadIdx.x == 0) {
        double mean = ss[0] / (double)N;
        double var = sb[0] / (double)N - mean * mean;
        float inv = gamma[c] / sqrtf((float)var + 1e-5f);
        float sh = rintf(log2f(fabsf(inv) + 1e-12f));
        sh = fminf(fmaxf(sh, -4.f), 4.f);
        float scale = copysignf(exp2f(sh), inv);
        st[c] = make_float4((float)mean, scale, beta[c], 0.f);
    }
}

// --- merged stats+finalize, int8 tensor [512][256][256] per channel ---
__global__ __launch_bounds__(256) void k_statsfin8(const signed char* __restrict__ in,
                                                   const float* __restrict__ gamma,
                                                   const float* __restrict__ beta,
                                                   float4* __restrict__ st)
{
    int c = blockIdx.x;
    int s = 0, sq = 0;
    for (int i = threadIdx.x; i < 32768; i += 256) {   // 512 b x 64 words
        int b = i >> 6, w = i & 63;
        u32 v = ((const u32*)in)[((size_t)(b * 256 + c) << 6) + w];
        int x0 = (int)(v << 24) >> 24, x1 = (int)(v << 16) >> 24;
        int x2 = (int)(v << 8) >> 24,  x3 = (int)v >> 24;
        s += x0 + x1 + x2 + x3;
        sq += x0 * x0 + x1 * x1 + x2 * x2 + x3 * x3;
    }
    __shared__ int ss[256];
    __shared__ int sb[256];
    ss[threadIdx.x] = s; sb[threadIdx.x] = sq;
    __syncthreads();
    for (int stp = 128; stp > 0; stp >>= 1) {
        if (threadIdx.x < stp) {
            ss[threadIdx.x] += ss[threadIdx.x + stp];
            sb[threadIdx.x] += sb[threadIdx.x + stp];
        }
        __syncthreads();
    }
    if (threadIdx.x == 0) {
        double mean = (double)ss[0] / 131072.0;
        double var = (double)sb[0] / 131072.0 - mean * mean;
        float inv = gamma[c] / sqrtf((float)var + 1e-5f);
        float sh = rintf(log2f(fabsf(inv) + 1e-12f));
        sh = fminf(fmaxf(sh, -4.f), 4.f);
        float scale = copysignf(exp2f(sh), inv);
        st[c] = make_float4((float)mean, scale, beta[c], 0.f);
    }
}

// --- merged stats+finalize, int16 tensor [512][256][64] per channel ---
__global__ __launch_bounds__(256) void k_statsfin16(const short* __restrict__ in,
                                                    const float* __restrict__ gamma,
                                                    const float* __restrict__ beta,
                                                    float4* __restrict__ st)
{
    int c = blockIdx.x;
    int s = 0, sq = 0;
    for (int i = threadIdx.x; i < 16384; i += 256) {   // 512 b x 32 words
        int b = i >> 5, w = i & 31;
        u32 v = ((const u32*)in)[((size_t)(b * 256 + c) << 5) + w];
        int x0 = (int)(v << 16) >> 16, x1 = (int)v >> 16;
        s += x0 + x1;
        sq += x0 * x0 + x1 * x1;
    }
    __shared__ double ss[256];
    __shared__ double sb[256];
    ss[threadIdx.x] = (double)s; sb[threadIdx.x] = (double)sq;
    __syncthreads();
    for (int stp = 128; stp > 0; stp >>= 1) {
        if (threadIdx.x < stp) {
            ss[threadIdx.x] += ss[threadIdx.x + stp];
            sb[threadIdx.x] += sb[threadIdx.x + stp];
        }
        __syncthreads();
    }
    if (threadIdx.x == 0) {
        double mean = ss[0] / 32768.0;
        double var = sb[0] / 32768.0 - mean * mean;
        float inv = gamma[c] / sqrtf((float)var + 1e-5f);
        float sh = rintf(log2f(fabsf(inv) + 1e-12f));
        sh = fminf(fmaxf(sh, -4.f), 4.f);
        float scale = copysignf(exp2f(sh), inv);
        st[c] = make_float4((float)mean, scale, beta[c], 0.f);
    }
}

// --- FUSED layer-2 head: bnpick(ppool) -> LDS packed rows -> grouped conv ---
__global__ __launch_bounds__(512) void k_fuse2(const float* __restrict__ ppool,
                                               const float4* __restrict__ st,
                                               const u32* __restrict__ wpk,
                                               signed char* __restrict__ out,
                                               double* __restrict__ part)
{
    __shared__ u32 lspk[64 * 20];
    __shared__ u32 lnpk[64 * 20];
    int b = blockIdx.x, t = threadIdx.x;
#pragma unroll
    for (int k = 0; k < 2; ++k) {
        int e = t + k * 512;
        int c = e >> 4, oh = e & 15;
        float4 s = st[c];
        const float4* p = (const float4*)(ppool + ((size_t)(b * 64 + c)) * 256 + oh * 16);
        u32 sb = 0, nb = 0;
#pragma unroll
        for (int j = 0; j < 4; ++j) {
            float4 v4 = p[j];
            float vs[4] = {v4.x, v4.y, v4.z, v4.w};
#pragma unroll
            for (int kk = 0; kk < 4; ++kk) {
                float v = (vs[kk] - s.x) * s.y + s.z;
                int ow = j * 4 + kk;
                sb |= (u32)(v > 0.f) << (ow + 1);
                nb |= (u32)(v != 0.f) << (ow + 1);
            }
        }
        lspk[c * 20 + 1 + oh] = sb;
        lnpk[c * 20 + 1 + oh] = nb;
        if (oh < 4) {
            int zs = (oh == 0) ? 0 : (16 + oh);
            lspk[c * 20 + zs] = 0; lnpk[c * 20 + zs] = 0;
        }
    }
    __syncthreads();
    int g = t >> 4, h = t & 15;
    const u32* sp = lspk + (2 * g) * 20 + h;
    const u32* np = lnpk + (2 * g) * 20 + h;
    u32 S[8], N[8];
#pragma unroll
    for (int jc = 0; jc < 2; ++jc)
#pragma unroll
        for (int jj = 0; jj < 4; ++jj) {
            S[jc * 4 + jj] = sp[jc * 20 + jj];
            N[jc * 4 + jj] = np[jc * 20 + jj];
        }
    const u32* wq = wpk + (size_t)(2 * g) * 8;
    u32 Ws0[8], Wn0[8], Ws1[8], Wn1[8];
#pragma unroll
    for (int r = 0; r < 8; ++r) {
        u32 a = wq[r];      Ws0[r] = a & 15u;  Wn0[r] = (a >> 8) & 15u;
        u32 bb = wq[8 + r]; Ws1[r] = bb & 15u; Wn1[r] = (bb >> 8) & 15u;
    }
    int v0[16], v1[16];
    int s0 = 0, q0 = 0, s1 = 0, q1 = 0;
#pragma unroll
    for (int w = 0; w < 16; ++w) {
        int snz0 = 0, smis0 = 0, snz1 = 0, smis1 = 0;
#pragma unroll
        for (int r = 0; r < 8; ++r) {
            u32 ss = (S[r] >> w) & 15u;
            u32 nn = (N[r] >> w) & 15u;
            u32 nz0 = nn & Wn0[r]; u32 m0 = (ss ^ Ws0[r]) & nz0;
            snz0 += __popc(nz0); smis0 += __popc(m0);
            u32 nz1 = nn & Wn1[r]; u32 m1 = (ss ^ Ws1[r]) & nz1;
            snz1 += __popc(nz1); smis1 += __popc(m1);
        }
        v0[w] = snz0 - 2 * smis0;
        v1[w] = snz1 - 2 * smis1;
        s0 += v0[w]; q0 += v0[w] * v0[w];
        s1 += v1[w]; q1 += v1[w] * v1[w];
    }
#pragma unroll
    for (int m = 1; m < 16; m <<= 1) {
        s0 += __shfl_xor(s0, m); q0 += __shfl_xor(q0, m);
        s1 += __shfl_xor(s1, m); q1 += __shfl_xor(q1, m);
    }
    if (h == 0) {
        part[((size_t)(2 * g) * 512 + b) * 2]         = (double)s0;
        part[((size_t)(2 * g) * 512 + b) * 2 + 1]     = (double)q0;
        part[((size_t)(2 * g + 1) * 512 + b) * 2]     = (double)s1;
        part[((size_t)(2 * g + 1) * 512 + b) * 2 + 1] = (double)q1;
    }
    signed char* o0 = out + ((size_t)((b * 64 + 2 * g) * 16 + h)) * 16;
    signed char* o1 = o0 + 256;
    u32 wb0[4], wb1[4];
#pragma unroll
    for (int j = 0; j < 4; ++j) {
        wb0[j] = pack4(v0[4*j], v0[4*j+1], v0[4*j+2], v0[4*j+3]);
        wb1[j] = pack4(v1[4*j], v1[4*j+1], v1[4*j+2], v1[4*j+3]);
    }
    *(uint4*)o0 = make_uint4(wb0[0], wb0[1], wb0[2], wb0[3]);
    *(uint4*)o1 = make_uint4(wb1[0], wb1[1], wb1[2], wb1[3]);
}

// --- 1x1 conv Cin=64->Cout=256, HW=256, int8 out, FUSED bn2_1 binarize+pack ---
__global__ __launch_bounds__(256) void k_conv1x1_bp2(const signed char* __restrict__ q8,
                                                     const float4* __restrict__ st,
                                                     const u32* __restrict__ wp,
                                                     signed char* __restrict__ out)
{
    int t = blockIdx.x * 256 + threadIdx.x;   // t = b*256 + hw
    int hw = t & 255; int b = t >> 8;
    const signed char* qp = q8 + (size_t)b * 64 * 256 + hw;
    u32 as0 = 0, as1 = 0, an0 = 0, an1 = 0;
#pragma unroll
    for (int k = 0; k < 32; ++k) {
        float4 s = st[k];                       // uniform -> s_load
        float v = ((float)qp[k * 256] - s.x) * s.y + s.z;   // coalesced byte load
        as0 |= (u32)(v > 0.f) << k;
        an0 |= (u32)(v != 0.f) << k;
    }
#pragma unroll
    for (int k = 0; k < 32; ++k) {
        float4 s = st[32 + k];
        float v = ((float)qp[(32 + k) * 256] - s.x) * s.y + s.z;
        as1 |= (u32)(v > 0.f) << k;
        an1 |= (u32)(v != 0.f) << k;
    }
    signed char* op = out + (size_t)b * 256 * 256 + hw;
#pragma unroll 8
    for (int oc = 0; oc < 256; ++oc) {
        uint4 wv = ((const uint4*)wp)[oc];      // wave-uniform -> scalar loads
        u32 nz0 = an0 & wv.z, nz1 = an1 & wv.w;
        u32 m0 = (as0 ^ wv.x) & nz0, m1 = (as1 ^ wv.y) & nz1;
        int dot = __popc(nz0) + __popc(nz1) - 2 * (__popc(m0) + __popc(m1));
        op[(size_t)oc << 8] = (signed char)dot;
    }
}

// --- FUSED layer-3 head: pool+pack(c22) -> LDS rows -> grouped conv ---
__global__ __launch_bounds__(512) void k_fuse3(const signed char* __restrict__ c22,
                                               const float4* __restrict__ st,
                                               const u32* __restrict__ wpk,
                                               signed char* __restrict__ out,
                                               double* __restrict__ part)
{
    __shared__ u32 lspk[256 * 12];
    __shared__ u32 lnpk[256 * 12];
    int b = blockIdx.x, t = threadIdx.x;
#pragma unroll
    for (int k = 0; k < 4; ++k) {
        int e = t + k * 512;
        int c = e >> 3, oh = e & 7;
        float4 s = st[c];
        const uint4* p = (const uint4*)(c22 + ((size_t)(b * 256 + c)) * 256 + (size_t)(2 * oh) * 16);
        uint4 r0 = p[0], r1 = p[1];
        bool pos = (s.y > 0.f);
        u32 rows0[4] = {r0.x, r0.y, r0.z, r0.w};
        u32 rows1[4] = {r1.x, r1.y, r1.z, r1.w};
        u32 sb = 0, nb = 0;
#pragma unroll
        for (int j = 0; j < 4; ++j) {
            u32 a = rows0[j], bw = rows1[j];
#pragma unroll
            for (int kk = 0; kk < 2; ++kk) {
                int sh0 = 24 - 16 * kk, sh1 = 16 - 16 * kk;
                int a0 = (int)(a  << sh0) >> 24, a1 = (int)(a  << sh1) >> 24;
                int a2 = (int)(bw << sh0) >> 24, a3 = (int)(bw << sh1) >> 24;
                int raw = pos ? max(max(a0, a1), max(a2, a3))
                              : min(min(a0, a1), min(a2, a3));
                float v = ((float)raw - s.x) * s.y + s.z;
                int ow = j * 2 + kk;
                sb |= (u32)(v > 0.f) << (ow + 1);
                nb |= (u32)(v != 0.f) << (ow + 1);
            }
        }
        lspk[c * 12 + 1 + oh] = sb;
        lnpk[c * 12 + 1 + oh] = nb;
        if (oh < 4) {
            int zs = (oh == 0) ? 0 : (8 + oh);
            lspk[c * 12 + zs] = 0; lnpk[c * 12 + zs] = 0;
        }
    }
    __syncthreads();
#pragma unroll
    for (int k = 0; k < 2; ++k) {
        int e = t + k * 512;
        int g = e >> 3, h = e & 7;
        const u32* sp = lspk + (2 * g) * 12 + h;
        const u32* np = lnpk + (2 * g) * 12 + h;
        u32 S[8], N[8];
#pragma unroll
        for (int jc = 0; jc < 2; ++jc)
#pragma unroll
            for (int jj = 0; jj < 4; ++jj) {
                S[jc * 4 + jj] = sp[jc * 12 + jj];
                N[jc * 4 + jj] = np[jc * 12 + jj];
            }
        const u32* wq = wpk + (size_t)(2 * g) * 8;
        u32 Ws0[8], Wn0[8], Ws1[8], Wn1[8];
#pragma unroll
        for (int r = 0; r < 8; ++r) {
            u32 a = wq[r];      Ws0[r] = a & 15u;  Wn0[r] = (a >> 8) & 15u;
            u32 bb = wq[8 + r]; Ws1[r] = bb & 15u; Wn1[r] = (bb >> 8) & 15u;
        }
        int v0[8], v1[8];
        int s0 = 0, q0 = 0, s1 = 0, q1 = 0;
#pragma unroll
        for (int w = 0; w < 8; ++w) {
            int snz0 = 0, smis0 = 0, snz1 = 0, smis1 = 0;
#pragma unroll
            for (int r = 0; r < 8; ++r) {
                u32 ss = (S[r] >> w) & 15u;
                u32 nn = (N[r] >> w) & 15u;
                u32 nz0 = nn & Wn0[r]; u32 m0 = (ss ^ Ws0[r]) & nz0;
                snz0 += __popc(nz0); smis0 += __popc(m0);
                u32 nz1 = nn & Wn1[r]; u32 m1 = (ss ^ Ws1[r]) & nz1;
                snz1 += __popc(nz1); smis1 += __popc(m1);
            }
            v0[w] = snz0 - 2 * smis0;
            v1[w] = snz1 - 2 * smis1;
            s0 += v0[w]; q0 += v0[w] * v0[w];
            s1 += v1[w]; q1 += v1[w] * v1[w];
        }
#pragma unroll
        for (int m = 1; m < 8; m <<= 1) {
            s0 += __shfl_xor(s0, m); q0 += __shfl_xor(q0, m);
            s1 += __shfl_xor(s1, m); q1 += __shfl_xor(q1, m);
        }
        if (h == 0) {
            part[((size_t)(2 * g) * 512 + b) * 2]         = (double)s0;
            part[((size_t)(2 * g) * 512 + b) * 2 + 1]     = (double)q0;
            part[((size_t)(2 * g + 1) * 512 + b) * 2]     = (double)s1;
            part[((size_t)(2 * g + 1) * 512 + b) * 2 + 1] = (double)q1;
        }
        signed char* o0 = out + ((size_t)((b * 256 + 2 * g) * 8 + h)) * 8;
        signed char* o1 = o0 + 64;
        *(uint2*)o0 = make_uint2(pack4(v0[0], v0[1], v0[2], v0[3]),
                                 pack4(v0[4], v0[5], v0[6], v0[7]));
        *(uint2*)o1 = make_uint2(pack4(v1[0], v1[1], v1[2], v1[3]),
                                 pack4(v1[4], v1[5], v1[6], v1[7]));
    }
}

// --- FUSED: bn+binarize+channel-pack (LDS) -> 1x1 conv Cin=256, int16 out ---
__global__ __launch_bounds__(256) void k_fuse4(const signed char* __restrict__ q8,
                                               const float4* __restrict__ st,
                                               const u32* __restrict__ wp,
                                               short* __restrict__ out)
{
    __shared__ u32 sq[4096];       // one image: 256ch x 64hw bytes
    __shared__ u32 act[64 * 17];   // [hw][16 words], pad 17
    int b = blockIdx.x, t = threadIdx.x;
    const u32* qb = (const u32*)(q8 + (size_t)b * 16384);
    for (int i = t; i < 4096; i += 256) sq[i] = qb[i];
    __syncthreads();
    {
        const signed char* s8p = (const signed char*)sq;
        int hw = t & 63, qd = t >> 6;
        u32 sv0 = 0, nv0 = 0, sv1 = 0, nv1 = 0;
#pragma unroll
        for (int k = 0; k < 32; ++k) {
            int c = qd * 64 + k;
            float4 s = st[c];
            float v = ((float)s8p[c * 64 + hw] - s.x) * s.y + s.z;
            sv0 |= (u32)(v > 0.f) << k;
            nv0 |= (u32)(v != 0.f) << k;
        }
#pragma unroll
        for (int k = 0; k < 32; ++k) {
            int c = qd * 64 + 32 + k;
            float4 s = st[c];
            float v = ((float)s8p[c * 64 + hw] - s.x) * s.y + s.z;
            sv1 |= (u32)(v > 0.f) << k;
            nv1 |= (u32)(v != 0.f) << k;
        }
        u32* ap = act + hw * 17;
        ap[qd * 2]     = sv0;
        ap[qd * 2 + 1] = sv1;
        ap[8 + qd * 2]     = nv0;
        ap[8 + qd * 2 + 1] = nv1;
    }
    __syncthreads();
    int hw = t & 63, ch = t >> 6;
    const u32* ap = act + hw * 17;
    u32 as[8], an[8];
#pragma unroll
    for (int j = 0; j < 8; ++j) { as[j] = ap[j]; an[j] = ap[8 + j]; }
    short* op = out + (size_t)b * 256 * 64 + hw;
#pragma unroll 4
    for (int oc = ch * 64; oc < ch * 64 + 64; ++oc) {
        const u32* wq = wp + oc * 16;
        int snz = 0, smis = 0;
#pragma unroll
        for (int j = 0; j < 8; ++j) {
            u32 nz = an[j] & wq[8 + j];
            u32 m = (as[j] ^ wq[j]) & nz;
            snz += __popc(nz); smis += __popc(m);
        }
        op[(size_t)oc * 64] = (short)(snz - 2 * smis);
    }
}

// --- FC: block per image, bn3_2 applied inline, features read once ---
__global__ __launch_bounds__(256) void k_fc2(const short* __restrict__ f,
                                             const float4* __restrict__ st,
                                             const float* __restrict__ fcw,
                                             const float* __restrict__ fcb,
                                             float* __restrict__ out)
{
    int b = blockIdx.x, t = threadIdx.x;
    int lane = t & 63, wv = t >> 6;
    const u32* fp = (const u32*)(f + (size_t)b * 16384);
    float acc[10];
#pragma unroll
    for (int n = 0; n < 10; ++n) acc[n] = 0.f;
    for (int i = 0; i < 32; ++i) {
        int j = i * 256 + t;                 // u32 index; features 2j, 2j+1
        u32 v = fp[j];
        float4 s = st[j >> 5];               // channel = (2j)>>6 = j>>5
        float f0 = ((float)((int)(v << 16) >> 16) - s.x) * s.y + s.z;
        float f1 = ((float)((int)v >> 16) - s.x) * s.y + s.z;
#pragma unroll
        for (int n = 0; n < 10; ++n) {
            float2 wv2 = *(const float2*)(fcw + (size_t)n * 16384 + 2 * j);
            acc[n] += f0 * wv2.x + f1 * wv2.y;
        }
    }
#pragma unroll
    for (int n = 0; n < 10; ++n)
#pragma unroll
        for (int m = 1; m < 64; m <<= 1) acc[n] += __shfl_xor(acc[n], m);
    __shared__ float sred[4][10];
    if (lane == 0)
#pragma unroll
        for (int n = 0; n < 10; ++n) sred[wv][n] = acc[n];
    __syncthreads();
    if (t < 10)
        out[b * 10 + t] = sred[0][t] + sred[1][t] + sred[2][t] + sred[3][t] + fcb[t];
}

extern "C" void kernel_launch(void* const* d_in, const int* in_sizes, int n_in,
                              void* d_out, int out_size, void* d_ws, size_t ws_size,
                              hipStream_t stream)
{
    const float* x    = (const float*)d_in[0];
    const float* w1   = (const float*)d_in[1];
    const float* g1   = (const float*)d_in[2];
    const float* b1   = (const float*)d_in[3];
    const float* w2_1 = (const float*)d_in[4];
    const float* g2_1 = (const float*)d_in[5];
    const float* b2_1 = (const float*)d_in[6];
    const float* w2_2 = (const float*)d_in[7];
    const float* g2_2 = (const float*)d_in[8];
    const float* b2_2 = (const float*)d_in[9];
    const float* w3_1 = (const float*)d_in[10];
    const float* g3_1 = (const float*)d_in[11];
    const float* b3_1 = (const float*)d_in[12];
    const float* w3_2 = (const float*)d_in[13];
    const float* g3_2 = (const float*)d_in[14];
    const float* b3_2 = (const float*)d_in[15];
    const float* fcw  = (const float*)d_in[16];
    const float* fcb  = (const float*)d_in[17];
    float* out = (float*)d_out;

    // workspace layout (bytes). ppool aliases later c22 (write-after-consume
    // ordering per launch sequence).
    const size_t OFF_PPOOL= 0;          // 33,554,432  (-> c22 later)
    const size_t OFF_F3   = 33554432;   // 16,777,216  conv3_2 int16 out
    const size_t OFF_Q    = 50331648;   //  8,388,608  convg int8 outs
    const size_t OFF_WPK21= 67108864;   //  2,048
    const size_t OFF_WPK31= 67110912;   //  8,192
    const size_t OFF_WP22 = 67119104;   //  4,096
    const size_t OFF_WP32 = 67123200;   //  16,384
    const size_t OFF_PART = 67139584;   //  2,097,152
    const size_t OFF_ST   = 69236736;   //  20,480     5 x 256 float4
    const size_t OFF_SWT  = 69257216;   //  12,288     conv1 signed weights, tap-major f32
    const size_t OFF_XPAD = 69269504;   //  7,741,440  padded input [512*3][35][36]
    const size_t NEED     = OFF_XPAD + 7741440;
    if (ws_size < NEED) return;

    char* ws = (char*)d_ws;
    float* ppool = (float*)(ws + OFF_PPOOL);
    signed char* c22 = (signed char*)(ws + OFF_PPOOL); // after k_fuse2 consumes ppool
    short* f3  = (short*)(ws + OFF_F3);
    signed char* q8 = (signed char*)(ws + OFF_Q);
    u32* wpk21 = (u32*)(ws + OFF_WPK21);
    u32* wpk31 = (u32*)(ws + OFF_WPK31);
    u32* wp22  = (u32*)(ws + OFF_WP22);
    u32* wp32  = (u32*)(ws + OFF_WP32);
    double* part = (double*)(ws + OFF_PART);
    float4* st1  = (float4*)(ws + OFF_ST);
    float4* st21 = st1 + 256;
    float4* st22 = st21 + 256;
    float4* st31 = st22 + 256;
    float4* st32 = st31 + 256;
    float* swt   = (float*)(ws + OFF_SWT);
    float* xpad  = (float*)(ws + OFF_XPAD);

    // ---- weight prep + input pad (one launch) ----
    k_wprep<<<7574, 256, 0, stream>>>(w1, swt, w2_1, wpk21, w3_1, wpk31,
                                      w2_2, wp22, w3_2, wp32, x, xpad);

    // ---- layer 1 ----
    k_conv1f<<<4096, 256, 0, stream>>>(xpad, swt, g1, ppool, part);
    k_finalize2<<<64, 256, 0, stream>>>(part, 512, 512 * 1024, g1, b1, st1);

    // ---- layer 2 (pack+gconv fused) ----
    k_fuse2<<<512, 512, 0, stream>>>(ppool, st1, wpk21, q8, part);
    k_finalize2<<<64, 256, 0, stream>>>(part, 512, 512 * 256, g2_1, b2_1, st21);
    k_conv1x1_bp2<<<512, 256, 0, stream>>>(q8, st21, wp22, c22);
    k_statsfin8<<<256, 256, 0, stream>>>(c22, g2_2, b2_2, st22);

    // ---- layer 3 (pool+pack+gconv fused; pack+1x1 fused) ----
    k_fuse3<<<512, 512, 0, stream>>>(c22, st22, wpk31, q8, part);
    k_finalize2<<<256, 256, 0, stream>>>(part, 512, 512 * 64, g3_1, b3_1, st31);
    k_fuse4<<<512, 256, 0, stream>>>(q8, st31, wp32, f3);
    k_statsfin16<<<256, 256, 0, stream>>>(f3, g3_2, b3_2, st32);

    // ---- FC (bn3_2 inline) ----
    k_fc2<<<512, 256, 0, stream>>>(f3, st32, fcw, fcb, out);
}